// Round 1
// baseline (3898.326 us; speedup 1.0000x reference)
//
#include <hip/hip_runtime.h>

// ---------------------------------------------------------------------------
// Problem constants
// ---------------------------------------------------------------------------
constexpr int cB    = 2;
constexpr int cH    = 96;
constexpr int cW    = 320;
constexpr int cC    = 128;   // CV
constexpr int cCIN  = 256;
constexpr int cHID  = 512;
constexpr int cNPIX = cH * cW;          // 30720
constexpr int cNTOK = cB * cNPIX;       // 61440
constexpr int cWH   = 12;               // window height (H/NS)
constexpr int cWW   = 40;               // window width  (W/NS)

// ---------------------------------------------------------------------------
// Transpose (B, C, HW) -> (B, HW, C)   (for input x, C=256)
// ---------------------------------------------------------------------------
__global__ __launch_bounds__(256) void k_chw2hwc(const float* __restrict__ in,
                                                 float* __restrict__ out, int Cc)
{
    __shared__ float tile[32][33];
    int s0 = blockIdx.x * 32;
    int c0 = blockIdx.y * 32;
    int b  = blockIdx.z;
    const float* ip = in  + (size_t)b * Cc * cNPIX;
    float*       op = out + (size_t)b * cNPIX * Cc;
    int tx = threadIdx.x, ty = threadIdx.y;   // (32, 8)
#pragma unroll
    for (int i = 0; i < 32; i += 8)
        tile[ty + i][tx] = ip[(size_t)(c0 + ty + i) * cNPIX + s0 + tx];
    __syncthreads();
#pragma unroll
    for (int i = 0; i < 32; i += 8)
        op[(size_t)(s0 + ty + i) * Cc + c0 + tx] = tile[tx][ty + i];
}

// (B, HW, C=128) -> (B, C, HW)  (final output)
__global__ __launch_bounds__(256) void k_hwc2chw(const float* __restrict__ in,
                                                 float* __restrict__ out)
{
    __shared__ float tile[32][33];
    int s0 = blockIdx.x * 32;
    int c0 = blockIdx.y * 32;
    int b  = blockIdx.z;
    const float* ip = in  + (size_t)b * cNPIX * cC;
    float*       op = out + (size_t)b * cC * cNPIX;
    int tx = threadIdx.x, ty = threadIdx.y;
#pragma unroll
    for (int i = 0; i < 32; i += 8)
        tile[ty + i][tx] = ip[(size_t)(s0 + ty + i) * cC + c0 + tx];
    __syncthreads();
#pragma unroll
    for (int i = 0; i < 32; i += 8)
        op[(size_t)(c0 + ty + i) * cNPIX + s0 + tx] = tile[tx][ty + i];
}

// ---------------------------------------------------------------------------
// Generic fp32 tiled GEMM: out[n][m] = act(A[n][:K] * Wm[:K][m] + bias[m]) (+res)
// A is (NTOK, K) row-major contiguous; Wm row stride is ldw (>= M).
// BM=BN=64, BK=16, 256 threads, 4x4 accum per thread.
// ---------------------------------------------------------------------------
template<bool RELU, bool RES>
__global__ __launch_bounds__(256) void k_gemm(const float* __restrict__ A,
                                              const float* __restrict__ Wm,
                                              const float* __restrict__ bias,
                                              const float* __restrict__ res,
                                              float* __restrict__ out,
                                              int K, int M, int ldw)
{
    __shared__ float As[16][64];
    __shared__ float Bs[16][68];
    const int bm = blockIdx.y * 64;
    const int bn = blockIdx.x * 64;
    const int t  = threadIdx.x;
    const int ty = t >> 4, tx = t & 15;
    const int ar = t >> 2, acq = (t & 3) * 4;   // A tile load: row, col-quad
    const int wr = t >> 4, wc  = (t & 15) * 4;  // W tile load

    float acc[4][4] = {};

    for (int k0 = 0; k0 < K; k0 += 16) {
        float4 a = *(const float4*)(A + (size_t)(bm + ar) * K + k0 + acq);
        As[acq + 0][ar] = a.x;
        As[acq + 1][ar] = a.y;
        As[acq + 2][ar] = a.z;
        As[acq + 3][ar] = a.w;
#pragma unroll
        for (int j = 0; j < 4; ++j) {
            int m = bn + wc + j;
            Bs[wr][wc + j] = (m < M) ? Wm[(size_t)(k0 + wr) * ldw + m] : 0.f;
        }
        __syncthreads();
#pragma unroll
        for (int kk = 0; kk < 16; ++kk) {
            const float4 av = *(const float4*)&As[kk][ty * 4];
            const float4 bv = *(const float4*)&Bs[kk][tx * 4];
            acc[0][0] = fmaf(av.x, bv.x, acc[0][0]);
            acc[0][1] = fmaf(av.x, bv.y, acc[0][1]);
            acc[0][2] = fmaf(av.x, bv.z, acc[0][2]);
            acc[0][3] = fmaf(av.x, bv.w, acc[0][3]);
            acc[1][0] = fmaf(av.y, bv.x, acc[1][0]);
            acc[1][1] = fmaf(av.y, bv.y, acc[1][1]);
            acc[1][2] = fmaf(av.y, bv.z, acc[1][2]);
            acc[1][3] = fmaf(av.y, bv.w, acc[1][3]);
            acc[2][0] = fmaf(av.z, bv.x, acc[2][0]);
            acc[2][1] = fmaf(av.z, bv.y, acc[2][1]);
            acc[2][2] = fmaf(av.z, bv.z, acc[2][2]);
            acc[2][3] = fmaf(av.z, bv.w, acc[2][3]);
            acc[3][0] = fmaf(av.w, bv.x, acc[3][0]);
            acc[3][1] = fmaf(av.w, bv.y, acc[3][1]);
            acc[3][2] = fmaf(av.w, bv.z, acc[3][2]);
            acc[3][3] = fmaf(av.w, bv.w, acc[3][3]);
        }
        __syncthreads();
    }

#pragma unroll
    for (int i = 0; i < 4; ++i) {
        int n = bm + ty * 4 + i;
#pragma unroll
        for (int j = 0; j < 4; ++j) {
            int m = bn + tx * 4 + j;
            if (m >= M) continue;
            float v = acc[i][j];
            if (bias) v += bias[m];
            if (RELU) v = fmaxf(v, 0.f);
            if (RES)  v += res[(size_t)n * M + m];
            out[(size_t)n * M + m] = v;
        }
    }
}

// ---------------------------------------------------------------------------
// LayerNorm over C=128: one wave per token, 2 channels per lane.
// ---------------------------------------------------------------------------
__global__ __launch_bounds__(256) void k_ln(const float* __restrict__ x,
                                            const float* __restrict__ g,
                                            const float* __restrict__ b,
                                            float* __restrict__ out)
{
    int tok  = blockIdx.x * 4 + (threadIdx.x >> 6);
    int lane = threadIdx.x & 63;
    float2 v = *(const float2*)(x + (size_t)tok * cC + lane * 2);
    float s = v.x + v.y;
#pragma unroll
    for (int o = 1; o < 64; o <<= 1) s += __shfl_xor(s, o);
    float mu = s * (1.f / cC);
    float dx = v.x - mu, dy = v.y - mu;
    float sq = dx * dx + dy * dy;
#pragma unroll
    for (int o = 1; o < 64; o <<= 1) sq += __shfl_xor(sq, o);
    float rs = rsqrtf(sq * (1.f / cC) + 1e-5f);
    float2 gv = *(const float2*)(g + lane * 2);
    float2 bv = *(const float2*)(b + lane * 2);
    float2 ov;
    ov.x = dx * rs * gv.x + bv.x;
    ov.y = dy * rs * gv.y + bv.y;
    *(float2*)(out + (size_t)tok * cC + lane * 2) = ov;
}

// ---------------------------------------------------------------------------
// Outlook: sink softmax over groups of 9 (attn buffer is (NTOK, 81) = rows of 9)
// ---------------------------------------------------------------------------
__global__ __launch_bounds__(256) void k_sink_softmax9(float* __restrict__ a, int nrows)
{
    int idx = blockIdx.x * blockDim.x + threadIdx.x;
    if (idx >= nrows) return;
    float* p = a + (size_t)idx * 9;
    float v[9];
    float m = 0.f;
#pragma unroll
    for (int i = 0; i < 9; ++i) { v[i] = p[i]; m = fmaxf(m, v[i]); }
    float se = 0.f;
#pragma unroll
    for (int i = 0; i < 9; ++i) { v[i] = expf(v[i] - m); se += v[i]; }
    float inv = 1.f / (se + expf(-m));
#pragma unroll
    for (int i = 0; i < 9; ++i) p[i] = v[i] * inv;
}

// ---------------------------------------------------------------------------
// Outlook fused gather:
// y[b,h,w,c] = sum_{p=(pi,pj)} [h'=h+1-pi, w'=w+1-pj valid]
//              sum_{q=(qi,qj)} attn[b,h',w',p,q] * v[b, h'+qi-1, w'+qj-1, c]
// ---------------------------------------------------------------------------
__global__ __launch_bounds__(128) void k_olk_gather(const float* __restrict__ v,
                                                    const float* __restrict__ attn,
                                                    float* __restrict__ y)
{
    int pix = blockIdx.x;
    int c   = threadIdx.x;
    int b   = pix / cNPIX;
    int hw  = pix % cNPIX;
    int h = hw / cW, w = hw % cW;
    float acc = 0.f;
#pragma unroll
    for (int p = 0; p < 9; ++p) {
        int pi = p / 3, pj = p % 3;
        int hh = h + 1 - pi, ww = w + 1 - pj;
        if ((unsigned)hh >= (unsigned)cH || (unsigned)ww >= (unsigned)cW) continue;
        const float* arow = attn + (size_t)(b * cNPIX + hh * cW + ww) * 81 + p * 9;
#pragma unroll
        for (int q = 0; q < 9; ++q) {
            int qi = q / 3, qj = q % 3;
            int sh = hh + qi - 1, sw = ww + qj - 1;
            if ((unsigned)sh >= (unsigned)cH || (unsigned)sw >= (unsigned)cW) continue;
            acc = fmaf(arow[q], v[(size_t)(b * cNPIX + sh * cW + sw) * cC + c], acc);
        }
    }
    y[(size_t)pix * cC + c] = acc;
}

// ---------------------------------------------------------------------------
// Depthwise 3x3 conv (SAME, zero pad) + bias + exact GELU, NHWC, 256 channels
// (FFN is processed in two 256-channel chunks). 128 threads, 2 ch each.
// ---------------------------------------------------------------------------
__global__ __launch_bounds__(128) void k_dwconv_gelu(const float* __restrict__ h1,
                                                     const float* __restrict__ dw,
                                                     const float* __restrict__ bdw,
                                                     float* __restrict__ h2)
{
    int pix = blockIdx.x;
    int c2  = threadIdx.x * 2;
    int b   = pix / cNPIX;
    int hw  = pix % cNPIX;
    int h = hw / cW, w = hw % cW;
    float a0 = 0.f, a1 = 0.f;
#pragma unroll
    for (int ky = 0; ky < 3; ++ky) {
        int sh = h + ky - 1;
        if ((unsigned)sh >= (unsigned)cH) continue;
#pragma unroll
        for (int kx = 0; kx < 3; ++kx) {
            int sw = w + kx - 1;
            if ((unsigned)sw >= (unsigned)cW) continue;
            float2 hv = *(const float2*)(h1 + (size_t)(b * cNPIX + sh * cW + sw) * 256 + c2);
            float w0 = dw[(size_t)c2 * 9 + ky * 3 + kx];
            float w1 = dw[(size_t)(c2 + 1) * 9 + ky * 3 + kx];
            a0 = fmaf(hv.x, w0, a0);
            a1 = fmaf(hv.y, w1, a1);
        }
    }
    a0 += bdw[c2];
    a1 += bdw[c2 + 1];
    a0 = 0.5f * a0 * (1.f + erff(a0 * 0.70710678118654752f));
    a1 = 0.5f * a1 * (1.f + erff(a1 * 0.70710678118654752f));
    float2 ov; ov.x = a0; ov.y = a1;
    *(float2*)(h2 + (size_t)pix * 256 + c2) = ov;
}

// ---------------------------------------------------------------------------
// Sinusoidal positional embedding, added in place to f (B,H,W,128).
// c<64: y-embedding of (h+1); c>=64: x-embedding of (w+1).
// emb[2k] = sin(p / 10000^(k/32)), emb[2k+1] = cos(p / 10000^(k/32))
// ---------------------------------------------------------------------------
__global__ __launch_bounds__(256) void k_pos_add(float* __restrict__ f)
{
    int idx = blockIdx.x * blockDim.x + threadIdx.x;
    if (idx >= cNTOK * cC) return;
    int c  = idx & (cC - 1);
    int n  = idx >> 7;
    int hw = n % cNPIX;
    int h = hw / cW, w = hw % cW;
    const float TWO_PI = 6.283185307179586f;
    float p;
    int cc;
    if (c < 64) { p = (float)(h + 1) * (TWO_PI / ((float)cH + 1e-6f)); cc = c; }
    else        { p = (float)(w + 1) * (TWO_PI / ((float)cW + 1e-6f)); cc = c - 64; }
    int k = cc >> 1;
    float val = p * expf((float)k * (-9.210340371976184f / 32.f)); // p / 10000^(k/32)
    float e = (cc & 1) ? cosf(val) : sinf(val);
    f[idx] += e;
}

// ---------------------------------------------------------------------------
// Cyclic roll: dst[b,h,w,:] = src[b,(h+sh)%H,(w+sw)%W,:]  (sh,sw >= 0)
// ---------------------------------------------------------------------------
__global__ __launch_bounds__(256) void k_roll(const float* __restrict__ src,
                                              float* __restrict__ dst, int sh, int sw)
{
    int idx = blockIdx.x * blockDim.x + threadIdx.x;
    if (idx >= cNTOK * 32) return;
    int q = idx & 31;
    int n = idx >> 5;
    int b  = n / cNPIX;
    int hw = n % cNPIX;
    int h = hw / cW, w = hw % cW;
    int s = b * cNPIX + ((h + sh) % cH) * cW + ((w + sw) % cW);
    ((float4*)dst)[(size_t)n * 32 + q] = ((const float4*)src)[(size_t)s * 32 + q];
}

// ---------------------------------------------------------------------------
// Window attention (flash-style, sink softmax). Window = 12x40 = 480 tokens.
// Grid: (30 q-tiles of 16, 64 windows, B). Block: 256 threads.
// Sink: m0 = 0, l0 = 1 (virtual key with logit 0, value 0).
// SHIFT: add Swin mask (-100 when region labels differ).
// ---------------------------------------------------------------------------
template<bool SHIFT>
__global__ __launch_bounds__(256) void k_win_attn(const float* __restrict__ q,
                                                  const float* __restrict__ k,
                                                  const float* __restrict__ v,
                                                  float* __restrict__ out)
{
    __shared__ float qs[16][132];
    __shared__ float ks[16][132];
    __shared__ float vs[16][132];
    __shared__ float sc[16][17];
    __shared__ float rowm[16], rowl[16], rowsc[16];

    const int qt = blockIdx.x;
    const int nh = blockIdx.y >> 3, nw = blockIdx.y & 7;
    const int b  = blockIdx.z;
    const int t  = threadIdx.x;
    const int rr = t >> 4;   // 0..15
    const int cg = t & 15;   // 0..15

    const float SCALE = 0.088388347648318447f;  // 1/sqrt(128)

    int qp = qt * 16 + rr;
    int qh = nh * cWH + qp / cWW;
    int qw = nw * cWW + qp % cWW;
    size_t qpix = (size_t)(b * cNPIX + qh * cW + qw);
    {
        float4 a  = *(const float4*)(q + qpix * cC + cg * 8);
        float4 bq = *(const float4*)(q + qpix * cC + cg * 8 + 4);
        qs[rr][cg*8+0] = a.x * SCALE;  qs[rr][cg*8+1] = a.y * SCALE;
        qs[rr][cg*8+2] = a.z * SCALE;  qs[rr][cg*8+3] = a.w * SCALE;
        qs[rr][cg*8+4] = bq.x * SCALE; qs[rr][cg*8+5] = bq.y * SCALE;
        qs[rr][cg*8+6] = bq.z * SCALE; qs[rr][cg*8+7] = bq.w * SCALE;
    }
    int lq = 0;
    if (SHIFT) {
        int rh = qh < (cH - cWH) ? 0 : (qh < (cH - cWH / 2) ? 1 : 2);
        int rc = qw < (cW - cWW) ? 0 : (qw < (cW - cWW / 2) ? 1 : 2);
        lq = rh * 3 + rc;
    }
    if (t < 16) { rowm[t] = 0.f; rowl[t] = 1.f; }
    float4 o0 = {0.f, 0.f, 0.f, 0.f}, o1 = {0.f, 0.f, 0.f, 0.f};
    __syncthreads();

    for (int kt = 0; kt < 30; ++kt) {
        int kp = kt * 16 + rr;
        int kh = nh * cWH + kp / cWW;
        int kw = nw * cWW + kp % cWW;
        size_t kpix = (size_t)(b * cNPIX + kh * cW + kw);
        {
            float4 a  = *(const float4*)(k + kpix * cC + cg * 8);
            float4 b2 = *(const float4*)(k + kpix * cC + cg * 8 + 4);
            ks[rr][cg*8+0] = a.x;  ks[rr][cg*8+1] = a.y;
            ks[rr][cg*8+2] = a.z;  ks[rr][cg*8+3] = a.w;
            ks[rr][cg*8+4] = b2.x; ks[rr][cg*8+5] = b2.y;
            ks[rr][cg*8+6] = b2.z; ks[rr][cg*8+7] = b2.w;
            float4 c1 = *(const float4*)(v + kpix * cC + cg * 8);
            float4 c2 = *(const float4*)(v + kpix * cC + cg * 8 + 4);
            vs[rr][cg*8+0] = c1.x; vs[rr][cg*8+1] = c1.y;
            vs[rr][cg*8+2] = c1.z; vs[rr][cg*8+3] = c1.w;
            vs[rr][cg*8+4] = c2.x; vs[rr][cg*8+5] = c2.y;
            vs[rr][cg*8+6] = c2.z; vs[rr][cg*8+7] = c2.w;
        }
        __syncthreads();

        // score s[rr][cg] = q_rr . k_cg
        float s = 0.f;
#pragma unroll
        for (int i = 0; i < 128; i += 4) {
            const float4 a  = *(const float4*)&qs[rr][i];
            const float4 bk = *(const float4*)&ks[cg][i];
            s = fmaf(a.x, bk.x, s);
            s = fmaf(a.y, bk.y, s);
            s = fmaf(a.z, bk.z, s);
            s = fmaf(a.w, bk.w, s);
        }
        if (SHIFT) {
            int kp2 = kt * 16 + cg;
            int kh2 = nh * cWH + kp2 / cWW;
            int kw2 = nw * cWW + kp2 % cWW;
            int rh = kh2 < (cH - cWH) ? 0 : (kh2 < (cH - cWH / 2) ? 1 : 2);
            int rc = kw2 < (cW - cWW) ? 0 : (kw2 < (cW - cWW / 2) ? 1 : 2);
            if (lq != rh * 3 + rc) s -= 100.f;
        }
        sc[rr][cg] = s;
        __syncthreads();

        if (t < 16) {
            float m = rowm[t], l = rowl[t];
            float mc = sc[t][0];
#pragma unroll
            for (int j = 1; j < 16; ++j) mc = fmaxf(mc, sc[t][j]);
            float nm  = fmaxf(m, mc);
            float scl = expf(m - nm);
            float ss  = 0.f;
#pragma unroll
            for (int j = 0; j < 16; ++j) {
                float pp = expf(sc[t][j] - nm);
                sc[t][j] = pp;
                ss += pp;
            }
            rowm[t]  = nm;
            rowl[t]  = l * scl + ss;
            rowsc[t] = scl;
        }
        __syncthreads();

        float scl = rowsc[rr];
        o0.x *= scl; o0.y *= scl; o0.z *= scl; o0.w *= scl;
        o1.x *= scl; o1.y *= scl; o1.z *= scl; o1.w *= scl;
#pragma unroll
        for (int j = 0; j < 16; ++j) {
            float pp = sc[rr][j];
            const float4 va = *(const float4*)&vs[j][cg * 8];
            const float4 vb = *(const float4*)&vs[j][cg * 8 + 4];
            o0.x = fmaf(pp, va.x, o0.x); o0.y = fmaf(pp, va.y, o0.y);
            o0.z = fmaf(pp, va.z, o0.z); o0.w = fmaf(pp, va.w, o0.w);
            o1.x = fmaf(pp, vb.x, o1.x); o1.y = fmaf(pp, vb.y, o1.y);
            o1.z = fmaf(pp, vb.z, o1.z); o1.w = fmaf(pp, vb.w, o1.w);
        }
        __syncthreads();
    }

    float inv = 1.f / rowl[rr];
    float* op = out + qpix * cC + cg * 8;
    float4 w0, w1;
    w0.x = o0.x * inv; w0.y = o0.y * inv; w0.z = o0.z * inv; w0.w = o0.w * inv;
    w1.x = o1.x * inv; w1.y = o1.y * inv; w1.z = o1.z * inv; w1.w = o1.w * inv;
    *(float4*)(op)     = w0;
    *(float4*)(op + 4) = w1;
}

// ---------------------------------------------------------------------------
// Host launcher
// ---------------------------------------------------------------------------
extern "C" void kernel_launch(void* const* d_in, const int* in_sizes, int n_in,
                              void* d_out, int out_size, void* d_ws, size_t ws_size,
                              hipStream_t stream)
{
    (void)in_sizes; (void)n_in; (void)out_size; (void)ws_size;

    const float* X      = (const float*)d_in[0];
    const float* agg_w1 = (const float*)d_in[1];
    const float* agg_b1 = (const float*)d_in[2];
    const float* agg_w2 = (const float*)d_in[3];
    const float* agg_b2 = (const float*)d_in[4];
    const float* ol_g   = (const float*)d_in[5];
    const float* ol_b   = (const float*)d_in[6];
    const float* ol_wv  = (const float*)d_in[7];
    const float* ol_wa  = (const float*)d_in[8];
    const float* ol_ba  = (const float*)d_in[9];
    const float* ol_wo  = (const float*)d_in[10];
    const float* ol_bo  = (const float*)d_in[11];
    // f1: 12..19 (g,b,w1,b1,dw,bdw,w2,b2); w: 20..26 (g,b,wq,wk,wv,wo,bo)
    // f2: 27..34; s: 35..41; f3: 42..49

    // Workspace layout (floats):
    //   f    : NTOK*128   residual stream
    //   xn   : NTOK*128   LN output / scratch
    //   bufA : NTOK*256   (x^T staging / h1 chunk / q,k)
    //   bufB : NTOK*256   (agg hidden / h2 chunk / v,attn_out / roll scratch)
    float* f    = (float*)d_ws;
    float* xn   = f    + (size_t)cNTOK * cC;
    float* bufA = xn   + (size_t)cNTOK * cC;
    float* bufB = bufA + (size_t)cNTOK * 256;
    float* A0  = bufA;
    float* A1  = bufA + (size_t)cNTOK * cC;
    float* Bf0 = bufB;
    float* Bf1 = bufB + (size_t)cNTOK * cC;

    const dim3 g2(2, cNTOK / 64), g4(4, cNTOK / 64);

    // ---- input transpose + aggregation MLP ----
    k_chw2hwc<<<dim3(cNPIX / 32, cCIN / 32, cB), dim3(32, 8), 0, stream>>>(X, bufA, cCIN);
    k_gemm<true,  false><<<g2, 256, 0, stream>>>(bufA, agg_w1, agg_b1, nullptr, Bf0, 256, 128, 128);
    k_gemm<false, false><<<g2, 256, 0, stream>>>(Bf0,  agg_w2, agg_b2, nullptr, f,   128, 128, 128);

    // ---- outlook attention ----
    k_ln<<<cNTOK / 4, 256, 0, stream>>>(f, ol_g, ol_b, xn);
    k_gemm<false, false><<<g2, 256, 0, stream>>>(xn, ol_wv, nullptr, nullptr, A0, 128, 128, 128);
    k_gemm<false, false><<<g2, 256, 0, stream>>>(xn, ol_wa, ol_ba,  nullptr, A1, 128,  81,  81);
    k_sink_softmax9<<<(cNTOK * 9 + 255) / 256, 256, 0, stream>>>(A1, cNTOK * 9);
    k_olk_gather<<<cNTOK, 128, 0, stream>>>(A0, A1, Bf0);
    k_gemm<false, true><<<g2, 256, 0, stream>>>(Bf0, ol_wo, ol_bo, f, f, 128, 128, 128);

    // ---- conv FFN (two 256-channel chunks to bound workspace) ----
    auto run_ffn = [&](int base) {
        const float* g   = (const float*)d_in[base + 0];
        const float* bln = (const float*)d_in[base + 1];
        const float* w1  = (const float*)d_in[base + 2];
        const float* b1  = (const float*)d_in[base + 3];
        const float* dw  = (const float*)d_in[base + 4];
        const float* bdw = (const float*)d_in[base + 5];
        const float* w2  = (const float*)d_in[base + 6];
        const float* b2  = (const float*)d_in[base + 7];
        k_ln<<<cNTOK / 4, 256, 0, stream>>>(f, g, bln, xn);
        for (int ch = 0; ch < 2; ++ch) {
            k_gemm<false, false><<<g4, 256, 0, stream>>>(
                xn, w1 + ch * 256, b1 + ch * 256, nullptr, bufA, 128, 256, 512);
            k_dwconv_gelu<<<cNTOK, 128, 0, stream>>>(
                bufA, dw + (size_t)ch * 256 * 9, bdw + ch * 256, bufB);
            k_gemm<false, true><<<g2, 256, 0, stream>>>(
                bufB, w2 + (size_t)ch * 256 * 128, (ch == 0) ? b2 : nullptr, f, f, 256, 128, 128);
        }
    };

    // ---- window attention ----
    auto run_win = [&](int base, bool shift) {
        const float* g  = (const float*)d_in[base + 0];
        const float* bl = (const float*)d_in[base + 1];
        const float* wq = (const float*)d_in[base + 2];
        const float* wk = (const float*)d_in[base + 3];
        const float* wv = (const float*)d_in[base + 4];
        const float* wo = (const float*)d_in[base + 5];
        const float* bo = (const float*)d_in[base + 6];
        k_ln<<<cNTOK / 4, 256, 0, stream>>>(f, g, bl, xn);
        const float* src = xn;
        if (shift) {
            k_roll<<<(cNTOK * 32) / 256, 256, 0, stream>>>(xn, Bf0, 6, 20);
            src = Bf0;
        }
        float* qb = A0;
        float* kb = A1;
        float* vb = shift ? Bf1 : Bf0;
        k_gemm<false, false><<<g2, 256, 0, stream>>>(src, wq, nullptr, nullptr, qb, 128, 128, 128);
        k_gemm<false, false><<<g2, 256, 0, stream>>>(src, wk, nullptr, nullptr, kb, 128, 128, 128);
        k_gemm<false, false><<<g2, 256, 0, stream>>>(src, wv, nullptr, nullptr, vb, 128, 128, 128);
        float* ao = shift ? Bf0 : Bf1;  // shift: src (Bf0) is dead after the 3 GEMMs
        if (shift) k_win_attn<true ><<<dim3(30, 64, cB), 256, 0, stream>>>(qb, kb, vb, ao);
        else       k_win_attn<false><<<dim3(30, 64, cB), 256, 0, stream>>>(qb, kb, vb, ao);
        const float* gin = ao;
        if (shift) {
            k_roll<<<(cNTOK * 32) / 256, 256, 0, stream>>>(ao, xn, cH - 6, cW - 20);
            gin = xn;
        }
        k_gemm<false, true><<<g2, 256, 0, stream>>>(gin, wo, bo, f, f, 128, 128, 128);
    };

    run_ffn(12);                                                    // f1
    k_pos_add<<<(cNTOK * cC) / 256, 256, 0, stream>>>(f);           // pos embed
    run_win(20, false);                                             // w
    run_ffn(27);                                                    // f2
    run_win(35, true);                                              // s (shifted)
    run_ffn(42);                                                    // f3

    // ---- output transpose (B,H,W,C) -> (B,C,H,W) ----
    k_hwc2chw<<<dim3(cNPIX / 32, cC / 32, cB), dim3(32, 8), 0, stream>>>(f, (float*)d_out);
}

// Round 2
// 1715.353 us; speedup vs baseline: 2.2726x; 2.2726x over previous
//
#include <hip/hip_runtime.h>

typedef __bf16 bf16;
typedef __bf16 bf16x8 __attribute__((ext_vector_type(8)));
typedef float  f32x4  __attribute__((ext_vector_type(4)));

#define MFMA_BF16(a, b, c) __builtin_amdgcn_mfma_f32_16x16x32_bf16(a, b, c, 0, 0, 0)

// ---------------------------------------------------------------------------
// Problem constants
// ---------------------------------------------------------------------------
constexpr int cB    = 2;
constexpr int cH    = 96;
constexpr int cW    = 320;
constexpr int cC    = 128;   // CV
constexpr int cNPIX = cH * cW;          // 30720
constexpr int cNTOK = cB * cNPIX;       // 61440

// ---------------------------------------------------------------------------
// Weight transpose+convert: fp32 W (K x M) -> bf16 Wt (M x K)
// ---------------------------------------------------------------------------
struct WJob  { const float* src; bf16* dst; int K; int M; };
struct WJobs { WJob j[19]; };

__global__ __launch_bounds__(256) void k_wt(WJobs jobs)
{
    __shared__ float tile[32][33];
    const WJob jb = jobs.j[blockIdx.z];
    int k0 = blockIdx.y * 32, m0 = blockIdx.x * 32;
    if (k0 >= jb.K || m0 >= jb.M) return;
    int tx = threadIdx.x, ty = threadIdx.y;   // (32, 8)
#pragma unroll
    for (int i = 0; i < 32; i += 8) {
        int kk = k0 + ty + i, mm = m0 + tx;
        tile[ty + i][tx] = (kk < jb.K && mm < jb.M) ? jb.src[(size_t)kk * jb.M + mm] : 0.f;
    }
    __syncthreads();
#pragma unroll
    for (int i = 0; i < 32; i += 8) {
        int mm = m0 + ty + i, kk = k0 + tx;
        if (mm < jb.M && kk < jb.K)
            jb.dst[(size_t)mm * jb.K + kk] = (bf16)tile[tx][ty + i];
    }
}

// ---------------------------------------------------------------------------
// Transpose (B, C=256, HW) -> (B, HW, C) bf16   (input x)
// ---------------------------------------------------------------------------
__global__ __launch_bounds__(256) void k_chw2hwc(const float* __restrict__ in,
                                                 bf16* __restrict__ out)
{
    __shared__ float tile[32][33];
    const int Cc = 256;
    int s0 = blockIdx.x * 32;
    int c0 = blockIdx.y * 32;
    int b  = blockIdx.z;
    const float* ip = in  + (size_t)b * Cc * cNPIX;
    bf16*        op = out + (size_t)b * cNPIX * Cc;
    int tx = threadIdx.x, ty = threadIdx.y;
#pragma unroll
    for (int i = 0; i < 32; i += 8)
        tile[ty + i][tx] = ip[(size_t)(c0 + ty + i) * cNPIX + s0 + tx];
    __syncthreads();
#pragma unroll
    for (int i = 0; i < 32; i += 8)
        op[(size_t)(s0 + ty + i) * Cc + c0 + tx] = (bf16)tile[tx][ty + i];
}

// (B, HW, C=128) fp32 -> (B, C, HW) fp32  (final output)
__global__ __launch_bounds__(256) void k_hwc2chw(const float* __restrict__ in,
                                                 float* __restrict__ out)
{
    __shared__ float tile[32][33];
    int s0 = blockIdx.x * 32;
    int c0 = blockIdx.y * 32;
    int b  = blockIdx.z;
    const float* ip = in  + (size_t)b * cNPIX * cC;
    float*       op = out + (size_t)b * cC * cNPIX;
    int tx = threadIdx.x, ty = threadIdx.y;
#pragma unroll
    for (int i = 0; i < 32; i += 8)
        tile[ty + i][tx] = ip[(size_t)(s0 + ty + i) * cC + c0 + tx];
    __syncthreads();
#pragma unroll
    for (int i = 0; i < 32; i += 8)
        op[(size_t)(c0 + ty + i) * cNPIX + s0 + tx] = tile[tx][ty + i];
}

// ---------------------------------------------------------------------------
// bf16 MFMA GEMM: out[n][m] = act(A[n][:K] . Wt[m][:K] + bias[m]) (+res)
// A: (NTOK x K) bf16 row-major. Wt: (M x K) bf16 row-major (i.e. B^T).
// Tile 128x128, BK=32, 4 waves (2x2), each wave 64x64 = 4x4 MFMA frags.
// ---------------------------------------------------------------------------
template<bool RELU, bool RES, bool OUTBF>
__global__ __launch_bounds__(256) void k_gemm_bf(const bf16* __restrict__ A,
                                                 const bf16* __restrict__ Wt,
                                                 const float* __restrict__ bias,
                                                 const float* __restrict__ res,
                                                 float* __restrict__ outF,
                                                 bf16* __restrict__ outB,
                                                 int K, int M)
{
    __shared__ bf16 As[128][40];   // +8 pad (16B) keeps b128 alignment, 2-way banks
    __shared__ bf16 Bs[128][40];
    const int bm = blockIdx.y * 128;
    const int bn = blockIdx.x * 128;
    const int t    = threadIdx.x;
    const int lane = t & 63;
    const int wid  = t >> 6;
    const int wm = (wid >> 1) * 64, wn = (wid & 1) * 64;
    const int lr = lane & 15, lg = lane >> 4;

    const f32x4 zero4 = {0.f, 0.f, 0.f, 0.f};
    f32x4 acc[4][4];
#pragma unroll
    for (int i = 0; i < 4; ++i)
#pragma unroll
        for (int j = 0; j < 4; ++j) acc[i][j] = zero4;

    bf16x8 zrow;
#pragma unroll
    for (int j = 0; j < 8; ++j) zrow[j] = (bf16)0.f;

    for (int k0 = 0; k0 < K; k0 += 32) {
#pragma unroll
        for (int i = 0; i < 2; ++i) {
            int idx = t + i * 256;
            int row = idx >> 2, kg = (idx & 3) * 8;
            *(bf16x8*)&As[row][kg] =
                *(const bf16x8*)(A + (size_t)(bm + row) * K + k0 + kg);
            int m = bn + row;
            bf16x8 wv = zrow;
            if (m < M) wv = *(const bf16x8*)(Wt + (size_t)m * K + k0 + kg);
            *(bf16x8*)&Bs[row][kg] = wv;
        }
        __syncthreads();
        bf16x8 af[4], bf[4];
#pragma unroll
        for (int mf = 0; mf < 4; ++mf)
            af[mf] = *(const bf16x8*)&As[wm + mf * 16 + lr][lg * 8];
#pragma unroll
        for (int nf = 0; nf < 4; ++nf)
            bf[nf] = *(const bf16x8*)&Bs[wn + nf * 16 + lr][lg * 8];
#pragma unroll
        for (int mf = 0; mf < 4; ++mf)
#pragma unroll
            for (int nf = 0; nf < 4; ++nf)
                acc[mf][nf] = MFMA_BF16(af[mf], bf[nf], acc[mf][nf]);
        __syncthreads();
    }

#pragma unroll
    for (int nf = 0; nf < 4; ++nf) {
        int col = bn + wn + nf * 16 + lr;
        if (col >= M) continue;
        float bv = bias ? bias[col] : 0.f;
#pragma unroll
        for (int mf = 0; mf < 4; ++mf) {
#pragma unroll
            for (int r = 0; r < 4; ++r) {
                int row = bm + wm + mf * 16 + lg * 4 + r;
                float vv = acc[mf][nf][r] + bv;
                if (RELU) vv = fmaxf(vv, 0.f);
                if (RES)  vv += res[(size_t)row * M + col];
                if (OUTBF) outB[(size_t)row * M + col] = (bf16)vv;
                else       outF[(size_t)row * M + col] = vv;
            }
        }
    }
}

// ---------------------------------------------------------------------------
// LayerNorm over C=128 (fp32 in, bf16 out): one wave per token.
// ---------------------------------------------------------------------------
__global__ __launch_bounds__(256) void k_ln(const float* __restrict__ x,
                                            const float* __restrict__ g,
                                            const float* __restrict__ b,
                                            bf16* __restrict__ out)
{
    int tok  = blockIdx.x * 4 + (threadIdx.x >> 6);
    int lane = threadIdx.x & 63;
    float2 v = *(const float2*)(x + (size_t)tok * cC + lane * 2);
    float s = v.x + v.y;
#pragma unroll
    for (int o = 1; o < 64; o <<= 1) s += __shfl_xor(s, o);
    float mu = s * (1.f / cC);
    float dx = v.x - mu, dy = v.y - mu;
    float sq = dx * dx + dy * dy;
#pragma unroll
    for (int o = 1; o < 64; o <<= 1) sq += __shfl_xor(sq, o);
    float rs = rsqrtf(sq * (1.f / cC) + 1e-5f);
    float2 gv = *(const float2*)(g + lane * 2);
    float2 bv = *(const float2*)(b + lane * 2);
    union { bf16 h[2]; unsigned int u; } o2;
    o2.h[0] = (bf16)(dx * rs * gv.x + bv.x);
    o2.h[1] = (bf16)(dy * rs * gv.y + bv.y);
    *(unsigned int*)(out + (size_t)tok * cC + lane * 2) = o2.u;
}

// ---------------------------------------------------------------------------
// Outlook: sink softmax over groups of 9 (attn is (NTOK, 81) fp32)
// ---------------------------------------------------------------------------
__global__ __launch_bounds__(256) void k_sink_softmax9(float* __restrict__ a, int nrows)
{
    int idx = blockIdx.x * blockDim.x + threadIdx.x;
    if (idx >= nrows) return;
    float* p = a + (size_t)idx * 9;
    float v[9];
    float m = 0.f;
#pragma unroll
    for (int i = 0; i < 9; ++i) { v[i] = p[i]; m = fmaxf(m, v[i]); }
    float se = 0.f;
#pragma unroll
    for (int i = 0; i < 9; ++i) { v[i] = expf(v[i] - m); se += v[i]; }
    float inv = 1.f / (se + expf(-m));
#pragma unroll
    for (int i = 0; i < 9; ++i) p[i] = v[i] * inv;
}

// ---------------------------------------------------------------------------
// Outlook fused gather (v bf16, attn fp32 -> y bf16)
// ---------------------------------------------------------------------------
__global__ __launch_bounds__(128) void k_olk_gather(const bf16* __restrict__ v,
                                                    const float* __restrict__ attn,
                                                    bf16* __restrict__ y)
{
    int pix = blockIdx.x;
    int c   = threadIdx.x;
    int b   = pix / cNPIX;
    int hw  = pix % cNPIX;
    int h = hw / cW, w = hw % cW;
    float acc = 0.f;
#pragma unroll
    for (int p = 0; p < 9; ++p) {
        int pi = p / 3, pj = p % 3;
        int hh = h + 1 - pi, ww = w + 1 - pj;
        if ((unsigned)hh >= (unsigned)cH || (unsigned)ww >= (unsigned)cW) continue;
        const float* arow = attn + (size_t)(b * cNPIX + hh * cW + ww) * 81 + p * 9;
#pragma unroll
        for (int q = 0; q < 9; ++q) {
            int qi = q / 3, qj = q % 3;
            int sh = hh + qi - 1, sw = ww + qj - 1;
            if ((unsigned)sh >= (unsigned)cH || (unsigned)sw >= (unsigned)cW) continue;
            acc = fmaf(arow[q], (float)v[(size_t)(b * cNPIX + sh * cW + sw) * cC + c], acc);
        }
    }
    y[(size_t)pix * cC + c] = (bf16)acc;
}

// ---------------------------------------------------------------------------
// Depthwise 3x3 + bias + exact GELU, NHWC, 512 channels, bf16 in/out.
// ---------------------------------------------------------------------------
__global__ __launch_bounds__(256) void k_dwconv_gelu(const bf16* __restrict__ h1,
                                                     const float* __restrict__ dw,
                                                     const float* __restrict__ bdw,
                                                     bf16* __restrict__ h2)
{
    int pix = blockIdx.x;
    int c2  = threadIdx.x * 2;
    int b   = pix / cNPIX;
    int hw  = pix % cNPIX;
    int h = hw / cW, w = hw % cW;
    float a0 = 0.f, a1 = 0.f;
#pragma unroll
    for (int ky = 0; ky < 3; ++ky) {
        int sh = h + ky - 1;
        if ((unsigned)sh >= (unsigned)cH) continue;
#pragma unroll
        for (int kx = 0; kx < 3; ++kx) {
            int sw = w + kx - 1;
            if ((unsigned)sw >= (unsigned)cW) continue;
            unsigned int hv = *(const unsigned int*)(h1 + (size_t)(b * cNPIX + sh * cW + sw) * 512 + c2);
            float x0 = __uint_as_float(hv << 16);
            float x1 = __uint_as_float(hv & 0xffff0000u);
            a0 = fmaf(x0, dw[(size_t)c2 * 9 + ky * 3 + kx], a0);
            a1 = fmaf(x1, dw[(size_t)(c2 + 1) * 9 + ky * 3 + kx], a1);
        }
    }
    a0 += bdw[c2];
    a1 += bdw[c2 + 1];
    a0 = 0.5f * a0 * (1.f + erff(a0 * 0.70710678118654752f));
    a1 = 0.5f * a1 * (1.f + erff(a1 * 0.70710678118654752f));
    union { bf16 h[2]; unsigned int u; } o2;
    o2.h[0] = (bf16)a0;
    o2.h[1] = (bf16)a1;
    *(unsigned int*)(h2 + (size_t)pix * 512 + c2) = o2.u;
}

// ---------------------------------------------------------------------------
// Sinusoidal positional embedding, added in place to f (fp32).
// ---------------------------------------------------------------------------
__global__ __launch_bounds__(256) void k_pos_add(float* __restrict__ f)
{
    int idx = blockIdx.x * blockDim.x + threadIdx.x;
    if (idx >= cNTOK * cC) return;
    int c  = idx & (cC - 1);
    int n  = idx >> 7;
    int hw = n % cNPIX;
    int h = hw / cW, w = hw % cW;
    const float TWO_PI = 6.283185307179586f;
    float p;
    int cc;
    if (c < 64) { p = (float)(h + 1) * (TWO_PI / ((float)cH + 1e-6f)); cc = c; }
    else        { p = (float)(w + 1) * (TWO_PI / ((float)cW + 1e-6f)); cc = c - 64; }
    int k = cc >> 1;
    float val = p * expf((float)k * (-9.210340371976184f / 32.f));
    float e = (cc & 1) ? cosf(val) : sinf(val);
    f[idx] += e;
}

// ---------------------------------------------------------------------------
// Cyclic roll on bf16 (C=128 -> 16 uint4 per token)
// ---------------------------------------------------------------------------
__global__ __launch_bounds__(256) void k_roll(const uint4* __restrict__ src,
                                              uint4* __restrict__ dst, int sh, int sw)
{
    int idx = blockIdx.x * blockDim.x + threadIdx.x;
    if (idx >= cNTOK * 16) return;
    int q = idx & 15;
    int n = idx >> 4;
    int b  = n / cNPIX;
    int hw = n % cNPIX;
    int h = hw / cW, w = hw % cW;
    int s = b * cNPIX + ((h + sh) % cH) * cW + ((w + sw) % cW);
    dst[(size_t)n * 16 + q] = src[(size_t)s * 16 + q];
}

// ---------------------------------------------------------------------------
// Window attention, MFMA flash-style with online sink softmax.
// Window = 12x40 = 480 tokens, 64 windows per image, B=2.
// Grid (8 q-blocks of 64, 64 windows, B). Block 256 = 4 waves x 16 q-rows.
// ---------------------------------------------------------------------------
template<bool SHIFT>
__global__ __launch_bounds__(256) void k_win_attn(const bf16* __restrict__ q,
                                                  const bf16* __restrict__ k,
                                                  const bf16* __restrict__ v,
                                                  bf16* __restrict__ out)
{
    __shared__ bf16 Ks[32][136];     // [key][ch]  (+8 pad)
    __shared__ bf16 Vs[128][40];     // [ch][key]  (+8 pad)
    __shared__ bf16 Ps[4][16][40];   // per-wave P tile [q][key] (+8 pad)

    const int t = threadIdx.x, lane = t & 63, wid = t >> 6;
    const int lr = lane & 15, lg = lane >> 4;
    const int nh = blockIdx.y >> 3, nw = blockIdx.y & 7;
    const int b  = blockIdx.z;
    const int qbase = blockIdx.x * 64 + wid * 16;

    auto tokOf = [&](int p) {
        int ph = p / 40, pw = p - ph * 40;
        return b * cNPIX + (nh * 12 + ph) * cW + nw * 40 + pw;
    };
    auto labOf = [&](int p) {
        int ph = nh * 12 + p / 40;
        int pw = nw * 40 + (p % 40);
        int rh = ph < 84 ? 0 : (ph < 90 ? 1 : 2);
        int rc = pw < 280 ? 0 : (pw < 300 ? 1 : 2);
        return rh * 3 + rc;
    };

    // Q fragments (A operand), 4 ch-chunks of 32
    int qp = min(qbase + lr, 479);
    size_t qoff = (size_t)tokOf(qp) * 128;
    bf16x8 qf[4];
#pragma unroll
    for (int c = 0; c < 4; ++c)
        qf[c] = *(const bf16x8*)(q + qoff + c * 32 + lg * 8);

    int labq[4];
    if (SHIFT) {
#pragma unroll
        for (int r = 0; r < 4; ++r) labq[r] = labOf(min(qbase + lg * 4 + r, 479));
    }

    const f32x4 zero4 = {0.f, 0.f, 0.f, 0.f};
    float m_run[4] = {0.f, 0.f, 0.f, 0.f};   // sink: m0 = 0
    float l_run[4] = {1.f, 1.f, 1.f, 1.f};   // sink: l0 = 1
    f32x4 o[8];
#pragma unroll
    for (int nf = 0; nf < 8; ++nf) o[nf] = zero4;

    const float SCALE = 0.088388347648318447f;  // 1/sqrt(128)

    for (int kt = 0; kt < 15; ++kt) {
        // stage K tile [key][ch]
#pragma unroll
        for (int i = 0; i < 2; ++i) {
            int idx = t + i * 256;
            int key = idx >> 4, cg = (idx & 15) * 8;
            *(bf16x8*)&Ks[key][cg] =
                *(const bf16x8*)(k + (size_t)tokOf(kt * 32 + key) * 128 + cg);
        }
        // stage V tile transposed [ch][key]
#pragma unroll
        for (int i = 0; i < 2; ++i) {
            int idx = t + i * 256;
            int key = idx & 31, cg = (idx >> 5) * 8;
            bf16x8 vv = *(const bf16x8*)(v + (size_t)tokOf(kt * 32 + key) * 128 + cg);
#pragma unroll
            for (int j = 0; j < 8; ++j) Vs[cg + j][key] = vv[j];
        }
        __syncthreads();

        // QK^T: 16q x 32keys
        f32x4 s0 = zero4, s1 = zero4;
#pragma unroll
        for (int c = 0; c < 4; ++c) {
            bf16x8 kf0 = *(const bf16x8*)&Ks[lr][c * 32 + lg * 8];
            bf16x8 kf1 = *(const bf16x8*)&Ks[16 + lr][c * 32 + lg * 8];
            s0 = MFMA_BF16(qf[c], kf0, s0);
            s1 = MFMA_BF16(qf[c], kf1, s1);
        }
#pragma unroll
        for (int r = 0; r < 4; ++r) { s0[r] *= SCALE; s1[r] *= SCALE; }
        if (SHIFT) {
            int lab0 = labOf(kt * 32 + lr);
            int lab1 = labOf(kt * 32 + 16 + lr);
#pragma unroll
            for (int r = 0; r < 4; ++r) {
                if (labq[r] != lab0) s0[r] -= 100.f;
                if (labq[r] != lab1) s1[r] -= 100.f;
            }
        }

        // online sink softmax per q-row; write P (bf16) to per-wave LDS
#pragma unroll
        for (int r = 0; r < 4; ++r) {
            float mx = fmaxf(s0[r], s1[r]);
#pragma unroll
            for (int off = 1; off < 16; off <<= 1) mx = fmaxf(mx, __shfl_xor(mx, off));
            float nm = fmaxf(m_run[r], mx);
            float sc = expf(m_run[r] - nm);
            m_run[r] = nm;
            float p0 = expf(s0[r] - nm);
            float p1 = expf(s1[r] - nm);
            float rs = p0 + p1;
#pragma unroll
            for (int off = 1; off < 16; off <<= 1) rs += __shfl_xor(rs, off);
            l_run[r] = l_run[r] * sc + rs;
#pragma unroll
            for (int nf = 0; nf < 8; ++nf) o[nf][r] *= sc;
            Ps[wid][lg * 4 + r][lr]      = (bf16)p0;
            Ps[wid][lg * 4 + r][16 + lr] = (bf16)p1;
        }
        __syncthreads();

        // PV: O(16q x 128ch) += P(16x32) * V(32x128)
        bf16x8 pa = *(const bf16x8*)&Ps[wid][lr][lg * 8];
#pragma unroll
        for (int nf = 0; nf < 8; ++nf) {
            bf16x8 bv = *(const bf16x8*)&Vs[nf * 16 + lr][lg * 8];
            o[nf] = MFMA_BF16(pa, bv, o[nf]);
        }
        __syncthreads();
    }

#pragma unroll
    for (int r = 0; r < 4; ++r) {
        int qrow = qbase + lg * 4 + r;
        if (qrow >= 480) continue;
        float inv = 1.f / l_run[r];
        size_t ooff = (size_t)tokOf(qrow) * 128;
#pragma unroll
        for (int nf = 0; nf < 8; ++nf)
            out[ooff + nf * 16 + lr] = (bf16)(o[nf][r] * inv);
    }
}

// ---------------------------------------------------------------------------
// Host launcher
// ---------------------------------------------------------------------------
extern "C" void kernel_launch(void* const* d_in, const int* in_sizes, int n_in,
                              void* d_out, int out_size, void* d_ws, size_t ws_size,
                              hipStream_t stream)
{
    (void)in_sizes; (void)n_in; (void)out_size; (void)ws_size;

    const float* X = (const float*)d_in[0];

    // ---- workspace layout ----
    char* ws = (char*)d_ws;
    float* f    = (float*)ws;                                 ws += (size_t)cNTOK * 128 * 4;
    bf16*  xnb  = (bf16*)ws;                                  ws += (size_t)cNTOK * 128 * 2;
    bf16*  bufA = (bf16*)ws;                                  ws += (size_t)cNTOK * 512 * 2;
    bf16*  bufB = (bf16*)ws;                                  ws += (size_t)cNTOK * 512 * 2;
    bf16*  wts  = (bf16*)ws;

    // ---- transposed bf16 weights ----
    size_t wo_off = 0;
    auto nextw = [&](int K, int M) { bf16* p = wts + wo_off; wo_off += (size_t)K * M; return p; };
    bf16* agg_w1t = nextw(256, 128);
    bf16* agg_w2t = nextw(128, 128);
    bf16* ol_wvt  = nextw(128, 128);
    bf16* ol_wat  = nextw(128, 81);
    bf16* ol_wot  = nextw(128, 128);
    bf16* f1_w1t  = nextw(128, 512);
    bf16* f1_w2t  = nextw(512, 128);
    bf16* w_wqt   = nextw(128, 128);
    bf16* w_wkt   = nextw(128, 128);
    bf16* w_wvt   = nextw(128, 128);
    bf16* w_wot   = nextw(128, 128);
    bf16* f2_w1t  = nextw(128, 512);
    bf16* f2_w2t  = nextw(512, 128);
    bf16* s_wqt   = nextw(128, 128);
    bf16* s_wkt   = nextw(128, 128);
    bf16* s_wvt   = nextw(128, 128);
    bf16* s_wot   = nextw(128, 128);
    bf16* f3_w1t  = nextw(128, 512);
    bf16* f3_w2t  = nextw(512, 128);

    WJobs jobs;
    int ji = 0;
    auto addj = [&](int src_idx, bf16* dst, int K, int M) {
        jobs.j[ji++] = WJob{(const float*)d_in[src_idx], dst, K, M};
    };
    addj(1,  agg_w1t, 256, 128);
    addj(3,  agg_w2t, 128, 128);
    addj(7,  ol_wvt,  128, 128);
    addj(8,  ol_wat,  128, 81);
    addj(10, ol_wot,  128, 128);
    addj(14, f1_w1t,  128, 512);
    addj(18, f1_w2t,  512, 128);
    addj(22, w_wqt,   128, 128);
    addj(23, w_wkt,   128, 128);
    addj(24, w_wvt,   128, 128);
    addj(25, w_wot,   128, 128);
    addj(29, f2_w1t,  128, 512);
    addj(33, f2_w2t,  512, 128);
    addj(37, s_wqt,   128, 128);
    addj(38, s_wkt,   128, 128);
    addj(39, s_wvt,   128, 128);
    addj(40, s_wot,   128, 128);
    addj(44, f3_w1t,  128, 512);
    addj(48, f3_w2t,  512, 128);
    k_wt<<<dim3(16, 16, 19), dim3(32, 8), 0, stream>>>(jobs);

    const dim3 gB1(1, cNTOK / 128), gB4(4, cNTOK / 128);

    // ---- input transpose + aggregation MLP ----
    k_chw2hwc<<<dim3(cNPIX / 32, 256 / 32, cB), dim3(32, 8), 0, stream>>>(X, bufA);
    k_gemm_bf<true,  false, true ><<<gB1, 256, 0, stream>>>(
        bufA, agg_w1t, (const float*)d_in[2], nullptr, nullptr, bufB, 256, 128);
    k_gemm_bf<false, false, false><<<gB1, 256, 0, stream>>>(
        bufB, agg_w2t, (const float*)d_in[4], nullptr, f, nullptr, 128, 128);

    // ---- outlook attention ----
    {
        bf16* vb   = bufA;
        bf16* gout = bufA + (size_t)cNTOK * 128;
        float* atn = (float*)bufB;
        k_ln<<<cNTOK / 4, 256, 0, stream>>>(f, (const float*)d_in[5], (const float*)d_in[6], xnb);
        k_gemm_bf<false, false, true ><<<gB1, 256, 0, stream>>>(
            xnb, ol_wvt, nullptr, nullptr, nullptr, vb, 128, 128);
        k_gemm_bf<false, false, false><<<gB1, 256, 0, stream>>>(
            xnb, ol_wat, (const float*)d_in[9], nullptr, atn, nullptr, 128, 81);
        k_sink_softmax9<<<(cNTOK * 9 + 255) / 256, 256, 0, stream>>>(atn, cNTOK * 9);
        k_olk_gather<<<cNTOK, 128, 0, stream>>>(vb, atn, gout);
        k_gemm_bf<false, true, false><<<gB1, 256, 0, stream>>>(
            gout, ol_wot, (const float*)d_in[11], f, f, nullptr, 128, 128);
    }

    // ---- conv FFN ----
    auto run_ffn = [&](int base, bf16* w1t, bf16* w2t) {
        k_ln<<<cNTOK / 4, 256, 0, stream>>>(f, (const float*)d_in[base], (const float*)d_in[base + 1], xnb);
        k_gemm_bf<false, false, true ><<<gB4, 256, 0, stream>>>(
            xnb, w1t, (const float*)d_in[base + 3], nullptr, nullptr, bufA, 128, 512);
        k_dwconv_gelu<<<cNTOK, 256, 0, stream>>>(
            bufA, (const float*)d_in[base + 4], (const float*)d_in[base + 5], bufB);
        k_gemm_bf<false, true, false><<<gB1, 256, 0, stream>>>(
            bufB, w2t, (const float*)d_in[base + 7], f, f, nullptr, 512, 128);
    };

    // ---- window attention ----
    auto run_win = [&](int base, bf16* wqt, bf16* wkt, bf16* wvt, bf16* wot, bool shift) {
        k_ln<<<cNTOK / 4, 256, 0, stream>>>(f, (const float*)d_in[base], (const float*)d_in[base + 1], xnb);
        bf16* qb = bufA;
        bf16* kb = bufA + (size_t)cNTOK * 128;
        bf16* vb = bufA + (size_t)cNTOK * 256;
        bf16* ao = bufA + (size_t)cNTOK * 384;
        const bf16* src = xnb;
        if (shift) {
            k_roll<<<(cNTOK * 16 + 255) / 256, 256, 0, stream>>>(
                (const uint4*)xnb, (uint4*)bufB, 6, 20);
            src = bufB;
        }
        k_gemm_bf<false, false, true><<<gB1, 256, 0, stream>>>(src, wqt, nullptr, nullptr, nullptr, qb, 128, 128);
        k_gemm_bf<false, false, true><<<gB1, 256, 0, stream>>>(src, wkt, nullptr, nullptr, nullptr, kb, 128, 128);
        k_gemm_bf<false, false, true><<<gB1, 256, 0, stream>>>(src, wvt, nullptr, nullptr, nullptr, vb, 128, 128);
        if (shift) k_win_attn<true ><<<dim3(8, 64, cB), 256, 0, stream>>>(qb, kb, vb, ao);
        else       k_win_attn<false><<<dim3(8, 64, cB), 256, 0, stream>>>(qb, kb, vb, ao);
        const bf16* gin = ao;
        if (shift) {
            k_roll<<<(cNTOK * 16 + 255) / 256, 256, 0, stream>>>(
                (const uint4*)ao, (uint4*)bufB, cH - 6, cW - 20);
            gin = bufB;
        }
        k_gemm_bf<false, true, false><<<gB1, 256, 0, stream>>>(
            gin, wot, (const float*)d_in[base + 6], f, f, nullptr, 128, 128);
    };

    run_ffn(12, f1_w1t, f1_w2t);                               // f1
    k_pos_add<<<(cNTOK * cC) / 256, 256, 0, stream>>>(f);      // pos embed
    run_win(20, w_wqt, w_wkt, w_wvt, w_wot, false);            // w
    run_ffn(27, f2_w1t, f2_w2t);                               // f2
    run_win(35, s_wqt, s_wkt, s_wvt, s_wot, true);             // s (shifted)
    run_ffn(42, f3_w1t, f3_w2t);                               // f3

    // ---- output transpose ----
    k_hwc2chw<<<dim3(cNPIX / 32, cC / 32, cB), dim3(32, 8), 0, stream>>>(f, (float*)d_out);
}

// Round 3
// 1059.125 us; speedup vs baseline: 3.6807x; 1.6196x over previous
//
#include <hip/hip_runtime.h>

typedef __bf16 bf16;
typedef __bf16 bf16x8 __attribute__((ext_vector_type(8)));
typedef float  f32x4  __attribute__((ext_vector_type(4)));

#define MFMA_BF16(a, b, c) __builtin_amdgcn_mfma_f32_16x16x32_bf16(a, b, c, 0, 0, 0)

// ---------------------------------------------------------------------------
// Problem constants
// ---------------------------------------------------------------------------
constexpr int cB    = 2;
constexpr int cH    = 96;
constexpr int cW    = 320;
constexpr int cC    = 128;   // CV
constexpr int cNPIX = cH * cW;          // 30720
constexpr int cNTOK = cB * cNPIX;       // 61440

// ---------------------------------------------------------------------------
// Weight transpose+convert: fp32 W (K x M) -> bf16 Wt (M x K)
// ---------------------------------------------------------------------------
struct WJob  { const float* src; bf16* dst; int K; int M; };
struct WJobs { WJob j[19]; };

__global__ __launch_bounds__(256) void k_wt(WJobs jobs)
{
    __shared__ float tile[32][33];
    const WJob jb = jobs.j[blockIdx.z];
    int k0 = blockIdx.y * 32, m0 = blockIdx.x * 32;
    if (k0 >= jb.K || m0 >= jb.M) return;
    int tx = threadIdx.x, ty = threadIdx.y;   // (32, 8)
#pragma unroll
    for (int i = 0; i < 32; i += 8) {
        int kk = k0 + ty + i, mm = m0 + tx;
        tile[ty + i][tx] = (kk < jb.K && mm < jb.M) ? jb.src[(size_t)kk * jb.M + mm] : 0.f;
    }
    __syncthreads();
#pragma unroll
    for (int i = 0; i < 32; i += 8) {
        int mm = m0 + ty + i, kk = k0 + tx;
        if (mm < jb.M && kk < jb.K)
            jb.dst[(size_t)mm * jb.K + kk] = (bf16)tile[tx][ty + i];
    }
}

// Depthwise weight transpose: [512][9] -> [9][512] fp32, 3 layers
__global__ __launch_bounds__(256) void k_dwt(const float* s0, const float* s1, const float* s2,
                                             float* d0, float* d1, float* d2)
{
    const float* s = blockIdx.x == 0 ? s0 : (blockIdx.x == 1 ? s1 : s2);
    float*       d = blockIdx.x == 0 ? d0 : (blockIdx.x == 1 ? d1 : d2);
    for (int i = threadIdx.x; i < 512 * 9; i += 256) {
        int c = i / 9, tap = i - c * 9;
        d[tap * 512 + c] = s[i];
    }
}

// ---------------------------------------------------------------------------
// Transpose (B, C=256, HW) -> (B, HW, C) bf16   (input x)
// ---------------------------------------------------------------------------
__global__ __launch_bounds__(256) void k_chw2hwc(const float* __restrict__ in,
                                                 bf16* __restrict__ out)
{
    __shared__ float tile[32][33];
    const int Cc = 256;
    int s0 = blockIdx.x * 32;
    int c0 = blockIdx.y * 32;
    int b  = blockIdx.z;
    const float* ip = in  + (size_t)b * Cc * cNPIX;
    bf16*        op = out + (size_t)b * cNPIX * Cc;
    int tx = threadIdx.x, ty = threadIdx.y;
#pragma unroll
    for (int i = 0; i < 32; i += 8)
        tile[ty + i][tx] = ip[(size_t)(c0 + ty + i) * cNPIX + s0 + tx];
    __syncthreads();
#pragma unroll
    for (int i = 0; i < 32; i += 8)
        op[(size_t)(s0 + ty + i) * Cc + c0 + tx] = (bf16)tile[tx][ty + i];
}

// (B, HW, C=128) fp32 -> (B, C, HW) fp32  (final output)
__global__ __launch_bounds__(256) void k_hwc2chw(const float* __restrict__ in,
                                                 float* __restrict__ out)
{
    __shared__ float tile[32][33];
    int s0 = blockIdx.x * 32;
    int c0 = blockIdx.y * 32;
    int b  = blockIdx.z;
    const float* ip = in  + (size_t)b * cNPIX * cC;
    float*       op = out + (size_t)b * cC * cNPIX;
    int tx = threadIdx.x, ty = threadIdx.y;
#pragma unroll
    for (int i = 0; i < 32; i += 8)
        tile[ty + i][tx] = ip[(size_t)(s0 + ty + i) * cC + c0 + tx];
    __syncthreads();
#pragma unroll
    for (int i = 0; i < 32; i += 8)
        op[(size_t)(c0 + ty + i) * cNPIX + s0 + tx] = tile[tx][ty + i];
}

// ---------------------------------------------------------------------------
// bf16 MFMA GEMM (128x128 tile, BK=32, 4 waves)
// ---------------------------------------------------------------------------
template<bool RELU, bool RES, bool OUTBF>
__global__ __launch_bounds__(256) void k_gemm_bf(const bf16* __restrict__ A,
                                                 const bf16* __restrict__ Wt,
                                                 const float* __restrict__ bias,
                                                 const float* __restrict__ res,
                                                 float* __restrict__ outF,
                                                 bf16* __restrict__ outB,
                                                 int K, int M)
{
    __shared__ bf16 As[128][40];
    __shared__ bf16 Bs[128][40];
    const int bm = blockIdx.y * 128;
    const int bn = blockIdx.x * 128;
    const int t    = threadIdx.x;
    const int lane = t & 63;
    const int wid  = t >> 6;
    const int wm = (wid >> 1) * 64, wn = (wid & 1) * 64;
    const int lr = lane & 15, lg = lane >> 4;

    const f32x4 zero4 = {0.f, 0.f, 0.f, 0.f};
    f32x4 acc[4][4];
#pragma unroll
    for (int i = 0; i < 4; ++i)
#pragma unroll
        for (int j = 0; j < 4; ++j) acc[i][j] = zero4;

    bf16x8 zrow;
#pragma unroll
    for (int j = 0; j < 8; ++j) zrow[j] = (bf16)0.f;

    for (int k0 = 0; k0 < K; k0 += 32) {
#pragma unroll
        for (int i = 0; i < 2; ++i) {
            int idx = t + i * 256;
            int row = idx >> 2, kg = (idx & 3) * 8;
            *(bf16x8*)&As[row][kg] =
                *(const bf16x8*)(A + (size_t)(bm + row) * K + k0 + kg);
            int m = bn + row;
            bf16x8 wv = zrow;
            if (m < M) wv = *(const bf16x8*)(Wt + (size_t)m * K + k0 + kg);
            *(bf16x8*)&Bs[row][kg] = wv;
        }
        __syncthreads();
        bf16x8 af[4], bf[4];
#pragma unroll
        for (int mf = 0; mf < 4; ++mf)
            af[mf] = *(const bf16x8*)&As[wm + mf * 16 + lr][lg * 8];
#pragma unroll
        for (int nf = 0; nf < 4; ++nf)
            bf[nf] = *(const bf16x8*)&Bs[wn + nf * 16 + lr][lg * 8];
#pragma unroll
        for (int mf = 0; mf < 4; ++mf)
#pragma unroll
            for (int nf = 0; nf < 4; ++nf)
                acc[mf][nf] = MFMA_BF16(af[mf], bf[nf], acc[mf][nf]);
        __syncthreads();
    }

#pragma unroll
    for (int nf = 0; nf < 4; ++nf) {
        int col = bn + wn + nf * 16 + lr;
        if (col >= M) continue;
        float bv = bias ? bias[col] : 0.f;
#pragma unroll
        for (int mf = 0; mf < 4; ++mf) {
#pragma unroll
            for (int r = 0; r < 4; ++r) {
                int row = bm + wm + mf * 16 + lg * 4 + r;
                float vv = acc[mf][nf][r] + bv;
                if (RELU) vv = fmaxf(vv, 0.f);
                if (RES)  vv += res[(size_t)row * M + col];
                if (OUTBF) outB[(size_t)row * M + col] = (bf16)vv;
                else       outF[(size_t)row * M + col] = vv;
            }
        }
    }
}

// ---------------------------------------------------------------------------
// LayerNorm over C=128 (fp32 in, bf16 out)
// ---------------------------------------------------------------------------
__global__ __launch_bounds__(256) void k_ln(const float* __restrict__ x,
                                            const float* __restrict__ g,
                                            const float* __restrict__ b,
                                            bf16* __restrict__ out)
{
    int tok  = blockIdx.x * 4 + (threadIdx.x >> 6);
    int lane = threadIdx.x & 63;
    float2 v = *(const float2*)(x + (size_t)tok * cC + lane * 2);
    float s = v.x + v.y;
#pragma unroll
    for (int o = 1; o < 64; o <<= 1) s += __shfl_xor(s, o);
    float mu = s * (1.f / cC);
    float dx = v.x - mu, dy = v.y - mu;
    float sq = dx * dx + dy * dy;
#pragma unroll
    for (int o = 1; o < 64; o <<= 1) sq += __shfl_xor(sq, o);
    float rs = rsqrtf(sq * (1.f / cC) + 1e-5f);
    float2 gv = *(const float2*)(g + lane * 2);
    float2 bv = *(const float2*)(b + lane * 2);
    union { bf16 h[2]; unsigned int u; } o2;
    o2.h[0] = (bf16)(dx * rs * gv.x + bv.x);
    o2.h[1] = (bf16)(dy * rs * gv.y + bv.y);
    *(unsigned int*)(out + (size_t)tok * cC + lane * 2) = o2.u;
}

// ---------------------------------------------------------------------------
// Sink-softmax stats per 9-row: st = (m, 1/(sum exp(v-m) + exp(-m)))
// Coalesced via per-wave LDS transpose. 256 rows / block.
// ---------------------------------------------------------------------------
__global__ __launch_bounds__(256) void k_sm9_stats(const float* __restrict__ a,
                                                   float2* __restrict__ st)
{
    __shared__ float buf[4][576];
    int wid = threadIdx.x >> 6, lane = threadIdx.x & 63;
    int rowbase = blockIdx.x * 256 + wid * 64;
    const float* src = a + (size_t)rowbase * 9;
#pragma unroll
    for (int i = 0; i < 9; ++i)
        buf[wid][lane + i * 64] = src[lane + i * 64];
    __syncthreads();
    float v[9];
#pragma unroll
    for (int i = 0; i < 9; ++i) v[i] = buf[wid][lane * 9 + i];
    float m = 0.f;
#pragma unroll
    for (int i = 0; i < 9; ++i) m = fmaxf(m, v[i]);
    float se = 0.f;
#pragma unroll
    for (int i = 0; i < 9; ++i) se += expf(v[i] - m);
    float2 o; o.x = m; o.y = 1.f / (se + expf(-m));
    st[rowbase + lane] = o;
}

// ---------------------------------------------------------------------------
// Outlook fused gather with on-the-fly softmax probabilities
// ---------------------------------------------------------------------------
__global__ __launch_bounds__(128) void k_olk_gather(const bf16* __restrict__ v,
                                                    const float* __restrict__ attn,
                                                    const float2* __restrict__ st,
                                                    bf16* __restrict__ y)
{
    __shared__ float pr[81];
    int pix = blockIdx.x;
    int t   = threadIdx.x;
    int b   = pix / cNPIX;
    int hw  = pix % cNPIX;
    int h = hw / cW, w = hw % cW;
    if (t < 81) {
        int p = t / 9, q = t - p * 9;
        int pi = p / 3, pj = p - pi * 3;
        int hh = h + 1 - pi, ww = w + 1 - pj;
        float val = 0.f;
        if ((unsigned)hh < (unsigned)cH && (unsigned)ww < (unsigned)cW) {
            size_t row = (size_t)(b * cNPIX + hh * cW + ww);
            float lg = attn[row * 81 + p * 9 + q];
            float2 s = st[row * 9 + p];
            val = expf(lg - s.x) * s.y;
        }
        pr[t] = val;
    }
    __syncthreads();
    float acc = 0.f;
#pragma unroll
    for (int p = 0; p < 9; ++p) {
        int pi = p / 3, pj = p - pi * 3;
        int hh = h + 1 - pi, ww = w + 1 - pj;
        if ((unsigned)hh >= (unsigned)cH || (unsigned)ww >= (unsigned)cW) continue;
#pragma unroll
        for (int q = 0; q < 9; ++q) {
            int qi = q / 3, qj = q - qi * 3;
            int sh = hh + qi - 1, sw = ww + qj - 1;
            if ((unsigned)sh >= (unsigned)cH || (unsigned)sw >= (unsigned)cW) continue;
            acc = fmaf(pr[p * 9 + q], (float)v[(size_t)(b * cNPIX + sh * cW + sw) * cC + t], acc);
        }
    }
    y[(size_t)pix * cC + t] = (bf16)acc;
}

// ---------------------------------------------------------------------------
// Depthwise 3x3 + bias + exact GELU, row-sliding, NHWC 512 ch.
// Block: 256 threads = 512 ch (2 per thread), one 40-px row segment.
// dwt layout [9][512] -> coalesced float2 weight loads, once per block.
// ---------------------------------------------------------------------------
__global__ __launch_bounds__(256) void k_dwconv_gelu(const bf16* __restrict__ h1,
                                                     const float* __restrict__ dwt,
                                                     const float* __restrict__ bdw,
                                                     bf16* __restrict__ h2)
{
    const int t   = threadIdx.x;
    const int c2  = t * 2;
    const int blk = blockIdx.x;
    const int row = blk >> 3;          // b*96 + h
    const int seg = blk & 7;
    const int bb  = row / cH, h = row % cH;
    const int w0  = seg * 40;

    float2 wgt[9];
#pragma unroll
    for (int k = 0; k < 9; ++k)
        wgt[k] = *(const float2*)(dwt + k * 512 + c2);
    const float2 bias = *(const float2*)(bdw + c2);

    const size_t base = (size_t)bb * cNPIX;

    auto ld = [&](int hh, int ww) -> float2 {
        float2 r; r.x = 0.f; r.y = 0.f;
        if ((unsigned)hh < (unsigned)cH && (unsigned)ww < (unsigned)cW) {
            unsigned u = *(const unsigned*)(h1 + ((base + (size_t)hh * cW + ww) * 512 + c2));
            r.x = __uint_as_float(u << 16);
            r.y = __uint_as_float(u & 0xffff0000u);
        }
        return r;
    };

    float2 cm[3], c0[3], cp[3];
#pragma unroll
    for (int r = 0; r < 3; ++r) {
        cm[r] = ld(h + r - 1, w0 - 1);
        c0[r] = ld(h + r - 1, w0);
    }

    for (int j = 0; j < 40; ++j) {
#pragma unroll
        for (int r = 0; r < 3; ++r) cp[r] = ld(h + r - 1, w0 + j + 1);
        float a0 = bias.x, a1 = bias.y;
#pragma unroll
        for (int r = 0; r < 3; ++r) {
            a0 = fmaf(cm[r].x, wgt[r * 3 + 0].x, a0);
            a1 = fmaf(cm[r].y, wgt[r * 3 + 0].y, a1);
            a0 = fmaf(c0[r].x, wgt[r * 3 + 1].x, a0);
            a1 = fmaf(c0[r].y, wgt[r * 3 + 1].y, a1);
            a0 = fmaf(cp[r].x, wgt[r * 3 + 2].x, a0);
            a1 = fmaf(cp[r].y, wgt[r * 3 + 2].y, a1);
        }
        a0 = 0.5f * a0 * (1.f + erff(a0 * 0.70710678118654752f));
        a1 = 0.5f * a1 * (1.f + erff(a1 * 0.70710678118654752f));
        union { bf16 hh[2]; unsigned int u; } o2;
        o2.hh[0] = (bf16)a0;
        o2.hh[1] = (bf16)a1;
        *(unsigned int*)(h2 + (base + (size_t)h * cW + w0 + j) * 512 + c2) = o2.u;
#pragma unroll
        for (int r = 0; r < 3; ++r) { cm[r] = c0[r]; c0[r] = cp[r]; }
    }
}

// ---------------------------------------------------------------------------
// Sinusoidal positional embedding, added in place to f (fp32).
// ---------------------------------------------------------------------------
__global__ __launch_bounds__(256) void k_pos_add(float* __restrict__ f)
{
    int idx = blockIdx.x * blockDim.x + threadIdx.x;
    if (idx >= cNTOK * cC) return;
    int c  = idx & (cC - 1);
    int n  = idx >> 7;
    int hw = n % cNPIX;
    int h = hw / cW, w = hw % cW;
    const float TWO_PI = 6.283185307179586f;
    float p;
    int cc;
    if (c < 64) { p = (float)(h + 1) * (TWO_PI / ((float)cH + 1e-6f)); cc = c; }
    else        { p = (float)(w + 1) * (TWO_PI / ((float)cW + 1e-6f)); cc = c - 64; }
    int k = cc >> 1;
    float val = p * expf((float)k * (-9.210340371976184f / 32.f));
    float e = (cc & 1) ? cosf(val) : sinf(val);
    f[idx] += e;
}

// ---------------------------------------------------------------------------
// Window attention, MFMA flash-style with online sink softmax.
// qkv interleaved [tok][384] = {q,k,v}. SHIFT folds the cyclic roll into
// token indexing (QKV projection is pointwise, so it commutes with roll).
// ---------------------------------------------------------------------------
template<bool SHIFT>
__global__ __launch_bounds__(256) void k_win_attn(const bf16* __restrict__ qkv,
                                                  bf16* __restrict__ out)
{
    __shared__ bf16 Ks[32][136];     // [key][ch]
    __shared__ bf16 Vs[128][40];     // [ch][key]
    __shared__ bf16 Ps[4][16][40];   // per-wave P tile [q][key]

    const int t = threadIdx.x, lane = t & 63, wid = t >> 6;
    const int lr = lane & 15, lg = lane >> 4;
    const int nh = blockIdx.y >> 3, nw = blockIdx.y & 7;
    const int b  = blockIdx.z;
    const int qbase = blockIdx.x * 64 + wid * 16;

    auto tokOf = [&](int p) {
        int ph = nh * 12 + p / 40;
        int pw = nw * 40 + (p % 40);
        if (SHIFT) {
            ph += 6;  if (ph >= cH) ph -= cH;
            pw += 20; if (pw >= cW) pw -= cW;
        }
        return b * cNPIX + ph * cW + pw;
    };
    auto labOf = [&](int p) {
        int ph = nh * 12 + p / 40;
        int pw = nw * 40 + (p % 40);
        int rh = ph < 84 ? 0 : (ph < 90 ? 1 : 2);
        int rc = pw < 280 ? 0 : (pw < 300 ? 1 : 2);
        return rh * 3 + rc;
    };

    int qp = min(qbase + lr, 479);
    size_t qoff = (size_t)tokOf(qp) * 384;
    bf16x8 qf[4];
#pragma unroll
    for (int c = 0; c < 4; ++c)
        qf[c] = *(const bf16x8*)(qkv + qoff + c * 32 + lg * 8);

    int labq[4];
    if (SHIFT) {
#pragma unroll
        for (int r = 0; r < 4; ++r) labq[r] = labOf(min(qbase + lg * 4 + r, 479));
    }

    const f32x4 zero4 = {0.f, 0.f, 0.f, 0.f};
    float m_run[4] = {0.f, 0.f, 0.f, 0.f};
    float l_run[4] = {1.f, 1.f, 1.f, 1.f};
    f32x4 o[8];
#pragma unroll
    for (int nf = 0; nf < 8; ++nf) o[nf] = zero4;

    const float SCALE = 0.088388347648318447f;

    for (int kt = 0; kt < 15; ++kt) {
#pragma unroll
        for (int i = 0; i < 2; ++i) {
            int idx = t + i * 256;
            int key = idx >> 4, cg = (idx & 15) * 8;
            *(bf16x8*)&Ks[key][cg] =
                *(const bf16x8*)(qkv + (size_t)tokOf(kt * 32 + key) * 384 + 128 + cg);
        }
#pragma unroll
        for (int i = 0; i < 2; ++i) {
            int idx = t + i * 256;
            int key = idx & 31, cg = (idx >> 5) * 8;
            bf16x8 vv = *(const bf16x8*)(qkv + (size_t)tokOf(kt * 32 + key) * 384 + 256 + cg);
#pragma unroll
            for (int j = 0; j < 8; ++j) Vs[cg + j][key] = vv[j];
        }
        __syncthreads();

        f32x4 s0 = zero4, s1 = zero4;
#pragma unroll
        for (int c = 0; c < 4; ++c) {
            bf16x8 kf0 = *(const bf16x8*)&Ks[lr][c * 32 + lg * 8];
            bf16x8 kf1 = *(const bf16x8*)&Ks[16 + lr][c * 32 + lg * 8];
            s0 = MFMA_BF16(qf[c], kf0, s0);
            s1 = MFMA_BF16(qf[c], kf1, s1);
        }
#pragma unroll
        for (int r = 0; r < 4; ++r) { s0[r] *= SCALE; s1[r] *= SCALE; }
        if (SHIFT) {
            int lab0 = labOf(kt * 32 + lr);
            int lab1 = labOf(kt * 32 + 16 + lr);
#pragma unroll
            for (int r = 0; r < 4; ++r) {
                if (labq[r] != lab0) s0[r] -= 100.f;
                if (labq[r] != lab1) s1[r] -= 100.f;
            }
        }

#pragma unroll
        for (int r = 0; r < 4; ++r) {
            float mx = fmaxf(s0[r], s1[r]);
#pragma unroll
            for (int off = 1; off < 16; off <<= 1) mx = fmaxf(mx, __shfl_xor(mx, off));
            float nm = fmaxf(m_run[r], mx);
            float sc = expf(m_run[r] - nm);
            m_run[r] = nm;
            float p0 = expf(s0[r] - nm);
            float p1 = expf(s1[r] - nm);
            float rs = p0 + p1;
#pragma unroll
            for (int off = 1; off < 16; off <<= 1) rs += __shfl_xor(rs, off);
            l_run[r] = l_run[r] * sc + rs;
#pragma unroll
            for (int nf = 0; nf < 8; ++nf) o[nf][r] *= sc;
            Ps[wid][lg * 4 + r][lr]      = (bf16)p0;
            Ps[wid][lg * 4 + r][16 + lr] = (bf16)p1;
        }
        __syncthreads();

        bf16x8 pa = *(const bf16x8*)&Ps[wid][lr][lg * 8];
#pragma unroll
        for (int nf = 0; nf < 8; ++nf) {
            bf16x8 bv = *(const bf16x8*)&Vs[nf * 16 + lr][lg * 8];
            o[nf] = MFMA_BF16(pa, bv, o[nf]);
        }
        __syncthreads();
    }

#pragma unroll
    for (int r = 0; r < 4; ++r) {
        int qrow = qbase + lg * 4 + r;
        if (qrow >= 480) continue;
        float inv = 1.f / l_run[r];
        size_t ooff = (size_t)tokOf(qrow) * 128;
#pragma unroll
        for (int nf = 0; nf < 8; ++nf)
            out[ooff + nf * 16 + lr] = (bf16)(o[nf][r] * inv);
    }
}

// ---------------------------------------------------------------------------
// Host launcher
// ---------------------------------------------------------------------------
extern "C" void kernel_launch(void* const* d_in, const int* in_sizes, int n_in,
                              void* d_out, int out_size, void* d_ws, size_t ws_size,
                              hipStream_t stream)
{
    (void)in_sizes; (void)n_in; (void)out_size; (void)ws_size;

    const float* X = (const float*)d_in[0];

    // ---- workspace layout ----
    char* ws = (char*)d_ws;
    float* f    = (float*)ws;                                 ws += (size_t)cNTOK * 128 * 4;
    bf16*  xnb  = (bf16*)ws;                                  ws += (size_t)cNTOK * 128 * 2;
    bf16*  bufA = (bf16*)ws;                                  ws += (size_t)cNTOK * 512 * 2;
    bf16*  bufB = (bf16*)ws;                                  ws += (size_t)cNTOK * 512 * 2;
    bf16*  wts  = (bf16*)ws;

    size_t wo_off = 0;
    auto nextw = [&](int K, int M) { bf16* p = wts + wo_off; wo_off += (size_t)K * M; return p; };
    bf16* agg_w1t = nextw(256, 128);
    bf16* agg_w2t = nextw(128, 128);
    bf16* ol_wvt  = nextw(128, 128);
    bf16* ol_wat  = nextw(128, 81);
    bf16* ol_wot  = nextw(128, 128);
    bf16* f1_w1t  = nextw(128, 512);
    bf16* f1_w2t  = nextw(512, 128);
    bf16* w_qkvt  = nextw(128, 384);
    bf16* w_wot   = nextw(128, 128);
    bf16* f2_w1t  = nextw(128, 512);
    bf16* f2_w2t  = nextw(512, 128);
    bf16* s_qkvt  = nextw(128, 384);
    bf16* s_wot   = nextw(128, 128);
    bf16* f3_w1t  = nextw(128, 512);
    bf16* f3_w2t  = nextw(512, 128);
    float* dwt1 = (float*)(wts + wo_off);
    float* dwt2 = dwt1 + 512 * 9;
    float* dwt3 = dwt2 + 512 * 9;

    WJobs jobs;
    int ji = 0;
    auto addj = [&](int src_idx, bf16* dst, int K, int M) {
        jobs.j[ji++] = WJob{(const float*)d_in[src_idx], dst, K, M};
    };
    addj(1,  agg_w1t, 256, 128);
    addj(3,  agg_w2t, 128, 128);
    addj(7,  ol_wvt,  128, 128);
    addj(8,  ol_wat,  128, 81);
    addj(10, ol_wot,  128, 128);
    addj(14, f1_w1t,  128, 512);
    addj(18, f1_w2t,  512, 128);
    addj(22, w_qkvt,           128, 128);   // wq
    addj(23, w_qkvt + 128*128, 128, 128);   // wk
    addj(24, w_qkvt + 256*128, 128, 128);   // wv
    addj(25, w_wot,   128, 128);
    addj(29, f2_w1t,  128, 512);
    addj(33, f2_w2t,  512, 128);
    addj(37, s_qkvt,           128, 128);
    addj(38, s_qkvt + 128*128, 128, 128);
    addj(39, s_qkvt + 256*128, 128, 128);
    addj(40, s_wot,   128, 128);
    addj(44, f3_w1t,  128, 512);
    addj(48, f3_w2t,  512, 128);
    k_wt<<<dim3(16, 16, 19), dim3(32, 8), 0, stream>>>(jobs);
    k_dwt<<<3, 256, 0, stream>>>((const float*)d_in[16], (const float*)d_in[31],
                                 (const float*)d_in[46], dwt1, dwt2, dwt3);

    const dim3 gB1(1, cNTOK / 128), gB3(3, cNTOK / 128), gB4(4, cNTOK / 128);

    // ---- input transpose + aggregation MLP ----
    k_chw2hwc<<<dim3(cNPIX / 32, 256 / 32, cB), dim3(32, 8), 0, stream>>>(X, bufA);
    k_gemm_bf<true,  false, true ><<<gB1, 256, 0, stream>>>(
        bufA, agg_w1t, (const float*)d_in[2], nullptr, nullptr, bufB, 256, 128);
    k_gemm_bf<false, false, false><<<gB1, 256, 0, stream>>>(
        bufB, agg_w2t, (const float*)d_in[4], nullptr, f, nullptr, 128, 128);

    // ---- outlook attention ----
    {
        bf16*  vb   = bufA;
        bf16*  gout = bufA + (size_t)cNTOK * 128;
        float* atn  = (float*)bufB;
        float2* st  = (float2*)((float*)bufB + (size_t)cNTOK * 81);
        k_ln<<<cNTOK / 4, 256, 0, stream>>>(f, (const float*)d_in[5], (const float*)d_in[6], xnb);
        k_gemm_bf<false, false, true ><<<gB1, 256, 0, stream>>>(
            xnb, ol_wvt, nullptr, nullptr, nullptr, vb, 128, 128);
        k_gemm_bf<false, false, false><<<gB1, 256, 0, stream>>>(
            xnb, ol_wat, (const float*)d_in[9], nullptr, atn, nullptr, 128, 81);
        k_sm9_stats<<<cNTOK * 9 / 256, 256, 0, stream>>>(atn, st);
        k_olk_gather<<<cNTOK, 128, 0, stream>>>(vb, atn, st, gout);
        k_gemm_bf<false, true, false><<<gB1, 256, 0, stream>>>(
            gout, ol_wot, (const float*)d_in[11], f, f, nullptr, 128, 128);
    }

    // ---- conv FFN ----
    auto run_ffn = [&](int base, bf16* w1t, bf16* w2t, float* dwt) {
        k_ln<<<cNTOK / 4, 256, 0, stream>>>(f, (const float*)d_in[base], (const float*)d_in[base + 1], xnb);
        k_gemm_bf<false, false, true ><<<gB4, 256, 0, stream>>>(
            xnb, w1t, (const float*)d_in[base + 3], nullptr, nullptr, bufA, 128, 512);
        k_dwconv_gelu<<<cB * cH * 8, 256, 0, stream>>>(
            bufA, dwt, (const float*)d_in[base + 5], bufB);
        k_gemm_bf<false, true, false><<<gB1, 256, 0, stream>>>(
            bufB, w2t, (const float*)d_in[base + 7], f, f, nullptr, 512, 128);
    };

    // ---- window attention ----
    auto run_win = [&](int base, bf16* qkvt, bf16* wot, bool shift) {
        k_ln<<<cNTOK / 4, 256, 0, stream>>>(f, (const float*)d_in[base], (const float*)d_in[base + 1], xnb);
        bf16* qkv = bufA;
        bf16* ao  = bufA + (size_t)cNTOK * 384;
        k_gemm_bf<false, false, true><<<gB3, 256, 0, stream>>>(
            xnb, qkvt, nullptr, nullptr, nullptr, qkv, 128, 384);
        if (shift) k_win_attn<true ><<<dim3(8, 64, cB), 256, 0, stream>>>(qkv, ao);
        else       k_win_attn<false><<<dim3(8, 64, cB), 256, 0, stream>>>(qkv, ao);
        k_gemm_bf<false, true, false><<<gB1, 256, 0, stream>>>(
            ao, wot, (const float*)d_in[base + 6], f, f, nullptr, 128, 128);
    };

    run_ffn(12, f1_w1t, f1_w2t, dwt1);                         // f1
    k_pos_add<<<(cNTOK * cC) / 256, 256, 0, stream>>>(f);      // pos embed
    run_win(20, w_qkvt, w_wot, false);                         // w
    run_ffn(27, f2_w1t, f2_w2t, dwt2);                         // f2
    run_win(35, s_qkvt, s_wot, true);                          // s (shifted)
    run_ffn(42, f3_w1t, f3_w2t, dwt3);                         // f3

    // ---- output transpose ----
    k_hwc2chw<<<dim3(cNPIX / 32, cC / 32, cB), dim3(32, 8), 0, stream>>>(f, (float*)d_out);
}

// Round 4
// 810.519 us; speedup vs baseline: 4.8097x; 1.3067x over previous
//
#include <hip/hip_runtime.h>

typedef __bf16 bf16;
typedef __bf16 bf16x8 __attribute__((ext_vector_type(8)));
typedef float  f32x4  __attribute__((ext_vector_type(4)));

#define MFMA_BF16(a, b, c) __builtin_amdgcn_mfma_f32_16x16x32_bf16(a, b, c, 0, 0, 0)

// ---------------------------------------------------------------------------
// Problem constants
// ---------------------------------------------------------------------------
constexpr int cB    = 2;
constexpr int cH    = 96;
constexpr int cW    = 320;
constexpr int cC    = 128;   // CV
constexpr int cNPIX = cH * cW;          // 30720
constexpr int cNTOK = cB * cNPIX;       // 61440

// ---------------------------------------------------------------------------
// Weight transpose+convert: fp32 W (K x M) -> bf16 Wt (M x K)
// ---------------------------------------------------------------------------
struct WJob  { const float* src; bf16* dst; int K; int M; };
struct WJobs { WJob j[19]; };

__global__ __launch_bounds__(256) void k_wt(WJobs jobs)
{
    __shared__ float tile[32][33];
    const WJob jb = jobs.j[blockIdx.z];
    int k0 = blockIdx.y * 32, m0 = blockIdx.x * 32;
    if (k0 >= jb.K || m0 >= jb.M) return;
    int tx = threadIdx.x, ty = threadIdx.y;   // (32, 8)
#pragma unroll
    for (int i = 0; i < 32; i += 8) {
        int kk = k0 + ty + i, mm = m0 + tx;
        tile[ty + i][tx] = (kk < jb.K && mm < jb.M) ? jb.src[(size_t)kk * jb.M + mm] : 0.f;
    }
    __syncthreads();
#pragma unroll
    for (int i = 0; i < 32; i += 8) {
        int mm = m0 + ty + i, kk = k0 + tx;
        if (mm < jb.M && kk < jb.K)
            jb.dst[(size_t)mm * jb.K + kk] = (bf16)tile[tx][ty + i];
    }
}

// Depthwise weight transpose: [512][9] -> [9][512] fp32, 3 layers
__global__ __launch_bounds__(256) void k_dwt(const float* s0, const float* s1, const float* s2,
                                             float* d0, float* d1, float* d2)
{
    const float* s = blockIdx.x == 0 ? s0 : (blockIdx.x == 1 ? s1 : s2);
    float*       d = blockIdx.x == 0 ? d0 : (blockIdx.x == 1 ? d1 : d2);
    for (int i = threadIdx.x; i < 512 * 9; i += 256) {
        int c = i / 9, tap = i - c * 9;
        d[tap * 512 + c] = s[i];
    }
}

// ---------------------------------------------------------------------------
// Transpose (B, C=256, HW) -> (B, HW, C) bf16   (input x)
// ---------------------------------------------------------------------------
__global__ __launch_bounds__(256) void k_chw2hwc(const float* __restrict__ in,
                                                 bf16* __restrict__ out)
{
    __shared__ float tile[32][33];
    const int Cc = 256;
    int s0 = blockIdx.x * 32;
    int c0 = blockIdx.y * 32;
    int b  = blockIdx.z;
    const float* ip = in  + (size_t)b * Cc * cNPIX;
    bf16*        op = out + (size_t)b * cNPIX * Cc;
    int tx = threadIdx.x, ty = threadIdx.y;
#pragma unroll
    for (int i = 0; i < 32; i += 8)
        tile[ty + i][tx] = ip[(size_t)(c0 + ty + i) * cNPIX + s0 + tx];
    __syncthreads();
#pragma unroll
    for (int i = 0; i < 32; i += 8)
        op[(size_t)(s0 + ty + i) * Cc + c0 + tx] = (bf16)tile[tx][ty + i];
}

// (B, HW, C=128) fp32 -> (B, C, HW) fp32  (final output)
__global__ __launch_bounds__(256) void k_hwc2chw(const float* __restrict__ in,
                                                 float* __restrict__ out)
{
    __shared__ float tile[32][33];
    int s0 = blockIdx.x * 32;
    int c0 = blockIdx.y * 32;
    int b  = blockIdx.z;
    const float* ip = in  + (size_t)b * cNPIX * cC;
    float*       op = out + (size_t)b * cC * cNPIX;
    int tx = threadIdx.x, ty = threadIdx.y;
#pragma unroll
    for (int i = 0; i < 32; i += 8)
        tile[ty + i][tx] = ip[(size_t)(s0 + ty + i) * cC + c0 + tx];
    __syncthreads();
#pragma unroll
    for (int i = 0; i < 32; i += 8)
        op[(size_t)(c0 + ty + i) * cNPIX + s0 + tx] = tile[tx][ty + i];
}

// ---------------------------------------------------------------------------
// bf16 MFMA GEMM (128x128 tile, BK=32, 4 waves)
// ---------------------------------------------------------------------------
template<bool RELU, bool RES, bool OUTBF>
__global__ __launch_bounds__(256) void k_gemm_bf(const bf16* __restrict__ A,
                                                 const bf16* __restrict__ Wt,
                                                 const float* __restrict__ bias,
                                                 const float* __restrict__ res,
                                                 float* __restrict__ outF,
                                                 bf16* __restrict__ outB,
                                                 int K, int M)
{
    __shared__ bf16 As[128][40];
    __shared__ bf16 Bs[128][40];
    const int bm = blockIdx.y * 128;
    const int bn = blockIdx.x * 128;
    const int t    = threadIdx.x;
    const int lane = t & 63;
    const int wid  = t >> 6;
    const int wm = (wid >> 1) * 64, wn = (wid & 1) * 64;
    const int lr = lane & 15, lg = lane >> 4;

    const f32x4 zero4 = {0.f, 0.f, 0.f, 0.f};
    f32x4 acc[4][4];
#pragma unroll
    for (int i = 0; i < 4; ++i)
#pragma unroll
        for (int j = 0; j < 4; ++j) acc[i][j] = zero4;

    bf16x8 zrow;
#pragma unroll
    for (int j = 0; j < 8; ++j) zrow[j] = (bf16)0.f;

    for (int k0 = 0; k0 < K; k0 += 32) {
#pragma unroll
        for (int i = 0; i < 2; ++i) {
            int idx = t + i * 256;
            int row = idx >> 2, kg = (idx & 3) * 8;
            *(bf16x8*)&As[row][kg] =
                *(const bf16x8*)(A + (size_t)(bm + row) * K + k0 + kg);
            int m = bn + row;
            bf16x8 wv = zrow;
            if (m < M) wv = *(const bf16x8*)(Wt + (size_t)m * K + k0 + kg);
            *(bf16x8*)&Bs[row][kg] = wv;
        }
        __syncthreads();
        bf16x8 af[4], bf[4];
#pragma unroll
        for (int mf = 0; mf < 4; ++mf)
            af[mf] = *(const bf16x8*)&As[wm + mf * 16 + lr][lg * 8];
#pragma unroll
        for (int nf = 0; nf < 4; ++nf)
            bf[nf] = *(const bf16x8*)&Bs[wn + nf * 16 + lr][lg * 8];
#pragma unroll
        for (int mf = 0; mf < 4; ++mf)
#pragma unroll
            for (int nf = 0; nf < 4; ++nf)
                acc[mf][nf] = MFMA_BF16(af[mf], bf[nf], acc[mf][nf]);
        __syncthreads();
    }

#pragma unroll
    for (int nf = 0; nf < 4; ++nf) {
        int col = bn + wn + nf * 16 + lr;
        if (col >= M) continue;
        float bv = bias ? bias[col] : 0.f;
#pragma unroll
        for (int mf = 0; mf < 4; ++mf) {
#pragma unroll
            for (int r = 0; r < 4; ++r) {
                int row = bm + wm + mf * 16 + lg * 4 + r;
                float vv = acc[mf][nf][r] + bv;
                if (RELU) vv = fmaxf(vv, 0.f);
                if (RES)  vv += res[(size_t)row * M + col];
                if (OUTBF) outB[(size_t)row * M + col] = (bf16)vv;
                else       outF[(size_t)row * M + col] = vv;
            }
        }
    }
}

// ---------------------------------------------------------------------------
// LayerNorm over C=128 (fp32 in, bf16 out)
// ---------------------------------------------------------------------------
__global__ __launch_bounds__(256) void k_ln(const float* __restrict__ x,
                                            const float* __restrict__ g,
                                            const float* __restrict__ b,
                                            bf16* __restrict__ out)
{
    int tok  = blockIdx.x * 4 + (threadIdx.x >> 6);
    int lane = threadIdx.x & 63;
    float2 v = *(const float2*)(x + (size_t)tok * cC + lane * 2);
    float s = v.x + v.y;
#pragma unroll
    for (int o = 1; o < 64; o <<= 1) s += __shfl_xor(s, o);
    float mu = s * (1.f / cC);
    float dx = v.x - mu, dy = v.y - mu;
    float sq = dx * dx + dy * dy;
#pragma unroll
    for (int o = 1; o < 64; o <<= 1) sq += __shfl_xor(sq, o);
    float rs = rsqrtf(sq * (1.f / cC) + 1e-5f);
    float2 gv = *(const float2*)(g + lane * 2);
    float2 bv = *(const float2*)(b + lane * 2);
    union { bf16 h[2]; unsigned int u; } o2;
    o2.h[0] = (bf16)(dx * rs * gv.x + bv.x);
    o2.h[1] = (bf16)(dy * rs * gv.y + bv.y);
    *(unsigned int*)(out + (size_t)tok * cC + lane * 2) = o2.u;
}

// ---------------------------------------------------------------------------
// Sink-softmax stats per 9-row: st = (m, 1/(sum exp(v-m) + exp(-m)))
// ---------------------------------------------------------------------------
__global__ __launch_bounds__(256) void k_sm9_stats(const float* __restrict__ a,
                                                   float2* __restrict__ st)
{
    __shared__ float buf[4][576];
    int wid = threadIdx.x >> 6, lane = threadIdx.x & 63;
    int rowbase = blockIdx.x * 256 + wid * 64;
    const float* src = a + (size_t)rowbase * 9;
#pragma unroll
    for (int i = 0; i < 9; ++i)
        buf[wid][lane + i * 64] = src[lane + i * 64];
    __syncthreads();
    float v[9];
#pragma unroll
    for (int i = 0; i < 9; ++i) v[i] = buf[wid][lane * 9 + i];
    float m = 0.f;
#pragma unroll
    for (int i = 0; i < 9; ++i) m = fmaxf(m, v[i]);
    float se = 0.f;
#pragma unroll
    for (int i = 0; i < 9; ++i) se += expf(v[i] - m);
    float2 o; o.x = m; o.y = 1.f / (se + expf(-m));
    st[rowbase + lane] = o;
}

// ---------------------------------------------------------------------------
// Outlook fused gather, 25-offset form.
// y[h,w,:] = sum_{d in 5x5} coef[d] * v[h+dy, w+dx, :]
// coef[d]  = sum_{(p,q): q-p = d} exp(attn[h',w',p,q]-m_p)*inv_p
// Block: 256 thr = 16 pixels x 16 lanes (8 ch each, bf16x8 loads).
// ---------------------------------------------------------------------------
__global__ __launch_bounds__(256) void k_olk_gather(const bf16* __restrict__ v,
                                                    const float* __restrict__ attn,
                                                    const float2* __restrict__ st,
                                                    bf16* __restrict__ y)
{
    __shared__ float pr[16][84];     // 81 used (+3 pad)
    __shared__ float coef[16][26];   // 25 used (+1 pad)

    const int t  = threadIdx.x;
    const int px = t >> 4;           // local pixel 0..15
    const int j  = t & 15;           // lane-in-pixel 0..15
    const int pix = blockIdx.x * 16 + px;
    const int b  = pix / cNPIX;
    const int hw = pix % cNPIX;
    const int h = hw / cW, w = hw % cW;

    // ---- phase 1: pr[p][q] for p = j (9 active lanes per pixel) ----
    if (j < 9) {
        const int p  = j;
        const int pi = p / 3, pj = p - pi * 3;
        const int hh = h + 1 - pi, ww = w + 1 - pj;
        float prv[9];
        if ((unsigned)hh < (unsigned)cH && (unsigned)ww < (unsigned)cW) {
            const size_t row = (size_t)(b * cNPIX + hh * cW + ww);
            const float* arow = attn + row * 81 + p * 9;
            const float2 s = st[row * 9 + p];
#pragma unroll
            for (int q = 0; q < 9; ++q) prv[q] = expf(arow[q] - s.x) * s.y;
        } else {
#pragma unroll
            for (int q = 0; q < 9; ++q) prv[q] = 0.f;
        }
#pragma unroll
        for (int q = 0; q < 9; ++q) pr[px][p * 9 + q] = prv[q];
    }
    __syncthreads();

    // ---- phase 2: fold 81 pr values into 25 offset coefficients ----
    for (int d = j; d < 25; d += 16) {
        const int a  = d / 5, bb = d - a * 5;   // a = qi-pi+2, bb = qj-pj+2
        float s = 0.f;
#pragma unroll
        for (int pi = 0; pi < 3; ++pi) {
            const int qi = pi + a - 2;
            if ((unsigned)qi >= 3u) continue;
#pragma unroll
            for (int pj = 0; pj < 3; ++pj) {
                const int qj = pj + bb - 2;
                if ((unsigned)qj >= 3u) continue;
                s += pr[px][(pi * 3 + pj) * 9 + qi * 3 + qj];
            }
        }
        coef[px][d] = s;
    }
    __syncthreads();

    // ---- phase 3: 25-tap gather, 8 channels per lane ----
    float acc[8] = {};
    const size_t bbase = (size_t)b * cNPIX;
#pragma unroll
    for (int a = 0; a < 5; ++a) {
        const int sh = h + a - 2;
        if ((unsigned)sh >= (unsigned)cH) continue;
#pragma unroll
        for (int bb = 0; bb < 5; ++bb) {
            const int sw = w + bb - 2;
            if ((unsigned)sw >= (unsigned)cW) continue;
            const float cf = coef[px][a * 5 + bb];
            const bf16x8 v8 = *(const bf16x8*)(v + ((bbase + (size_t)sh * cW + sw) * 128 + j * 8));
#pragma unroll
            for (int e = 0; e < 8; ++e) acc[e] = fmaf(cf, (float)v8[e], acc[e]);
        }
    }
    bf16x8 o8;
#pragma unroll
    for (int e = 0; e < 8; ++e) o8[e] = (bf16)acc[e];
    *(bf16x8*)(y + (size_t)pix * 128 + j * 8) = o8;
}

// ---------------------------------------------------------------------------
// Depthwise 3x3 + bias + exact GELU, row-sliding, NHWC 512 ch.
// ---------------------------------------------------------------------------
__global__ __launch_bounds__(256) void k_dwconv_gelu(const bf16* __restrict__ h1,
                                                     const float* __restrict__ dwt,
                                                     const float* __restrict__ bdw,
                                                     bf16* __restrict__ h2)
{
    const int t   = threadIdx.x;
    const int c2  = t * 2;
    const int blk = blockIdx.x;
    const int row = blk >> 3;          // b*96 + h
    const int seg = blk & 7;
    const int bb  = row / cH, h = row % cH;
    const int w0  = seg * 40;

    float2 wgt[9];
#pragma unroll
    for (int k = 0; k < 9; ++k)
        wgt[k] = *(const float2*)(dwt + k * 512 + c2);
    const float2 bias = *(const float2*)(bdw + c2);

    const size_t base = (size_t)bb * cNPIX;

    auto ld = [&](int hh, int ww) -> float2 {
        float2 r; r.x = 0.f; r.y = 0.f;
        if ((unsigned)hh < (unsigned)cH && (unsigned)ww < (unsigned)cW) {
            unsigned u = *(const unsigned*)(h1 + ((base + (size_t)hh * cW + ww) * 512 + c2));
            r.x = __uint_as_float(u << 16);
            r.y = __uint_as_float(u & 0xffff0000u);
        }
        return r;
    };

    float2 cm[3], c0[3], cp[3];
#pragma unroll
    for (int r = 0; r < 3; ++r) {
        cm[r] = ld(h + r - 1, w0 - 1);
        c0[r] = ld(h + r - 1, w0);
    }

    for (int j = 0; j < 40; ++j) {
#pragma unroll
        for (int r = 0; r < 3; ++r) cp[r] = ld(h + r - 1, w0 + j + 1);
        float a0 = bias.x, a1 = bias.y;
#pragma unroll
        for (int r = 0; r < 3; ++r) {
            a0 = fmaf(cm[r].x, wgt[r * 3 + 0].x, a0);
            a1 = fmaf(cm[r].y, wgt[r * 3 + 0].y, a1);
            a0 = fmaf(c0[r].x, wgt[r * 3 + 1].x, a0);
            a1 = fmaf(c0[r].y, wgt[r * 3 + 1].y, a1);
            a0 = fmaf(cp[r].x, wgt[r * 3 + 2].x, a0);
            a1 = fmaf(cp[r].y, wgt[r * 3 + 2].y, a1);
        }
        a0 = 0.5f * a0 * (1.f + erff(a0 * 0.70710678118654752f));
        a1 = 0.5f * a1 * (1.f + erff(a1 * 0.70710678118654752f));
        union { bf16 hh[2]; unsigned int u; } o2;
        o2.hh[0] = (bf16)a0;
        o2.hh[1] = (bf16)a1;
        *(unsigned int*)(h2 + (base + (size_t)h * cW + w0 + j) * 512 + c2) = o2.u;
#pragma unroll
        for (int r = 0; r < 3; ++r) { cm[r] = c0[r]; c0[r] = cp[r]; }
    }
}

// ---------------------------------------------------------------------------
// Sinusoidal positional embedding, added in place to f (fp32).
// ---------------------------------------------------------------------------
__global__ __launch_bounds__(256) void k_pos_add(float* __restrict__ f)
{
    int idx = blockIdx.x * blockDim.x + threadIdx.x;
    if (idx >= cNTOK * cC) return;
    int c  = idx & (cC - 1);
    int n  = idx >> 7;
    int hw = n % cNPIX;
    int h = hw / cW, w = hw % cW;
    const float TWO_PI = 6.283185307179586f;
    float p;
    int cc;
    if (c < 64) { p = (float)(h + 1) * (TWO_PI / ((float)cH + 1e-6f)); cc = c; }
    else        { p = (float)(w + 1) * (TWO_PI / ((float)cW + 1e-6f)); cc = c - 64; }
    int k = cc >> 1;
    float val = p * expf((float)k * (-9.210340371976184f / 32.f));
    float e = (cc & 1) ? cosf(val) : sinf(val);
    f[idx] += e;
}

// ---------------------------------------------------------------------------
// Window attention, MFMA flash-style with online sink softmax.
// ---------------------------------------------------------------------------
template<bool SHIFT>
__global__ __launch_bounds__(256) void k_win_attn(const bf16* __restrict__ qkv,
                                                  bf16* __restrict__ out)
{
    __shared__ bf16 Ks[32][136];     // [key][ch]
    __shared__ bf16 Vs[128][40];     // [ch][key]
    __shared__ bf16 Ps[4][16][40];   // per-wave P tile [q][key]

    const int t = threadIdx.x, lane = t & 63, wid = t >> 6;
    const int lr = lane & 15, lg = lane >> 4;
    const int nh = blockIdx.y >> 3, nw = blockIdx.y & 7;
    const int b  = blockIdx.z;
    const int qbase = blockIdx.x * 64 + wid * 16;

    auto tokOf = [&](int p) {
        int ph = nh * 12 + p / 40;
        int pw = nw * 40 + (p % 40);
        if (SHIFT) {
            ph += 6;  if (ph >= cH) ph -= cH;
            pw += 20; if (pw >= cW) pw -= cW;
        }
        return b * cNPIX + ph * cW + pw;
    };
    auto labOf = [&](int p) {
        int ph = nh * 12 + p / 40;
        int pw = nw * 40 + (p % 40);
        int rh = ph < 84 ? 0 : (ph < 90 ? 1 : 2);
        int rc = pw < 280 ? 0 : (pw < 300 ? 1 : 2);
        return rh * 3 + rc;
    };

    int qp = min(qbase + lr, 479);
    size_t qoff = (size_t)tokOf(qp) * 384;
    bf16x8 qf[4];
#pragma unroll
    for (int c = 0; c < 4; ++c)
        qf[c] = *(const bf16x8*)(qkv + qoff + c * 32 + lg * 8);

    int labq[4];
    if (SHIFT) {
#pragma unroll
        for (int r = 0; r < 4; ++r) labq[r] = labOf(min(qbase + lg * 4 + r, 479));
    }

    const f32x4 zero4 = {0.f, 0.f, 0.f, 0.f};
    float m_run[4] = {0.f, 0.f, 0.f, 0.f};
    float l_run[4] = {1.f, 1.f, 1.f, 1.f};
    f32x4 o[8];
#pragma unroll
    for (int nf = 0; nf < 8; ++nf) o[nf] = zero4;

    const float SCALE = 0.088388347648318447f;

    for (int kt = 0; kt < 15; ++kt) {
#pragma unroll
        for (int i = 0; i < 2; ++i) {
            int idx = t + i * 256;
            int key = idx >> 4, cg = (idx & 15) * 8;
            *(bf16x8*)&Ks[key][cg] =
                *(const bf16x8*)(qkv + (size_t)tokOf(kt * 32 + key) * 384 + 128 + cg);
        }
#pragma unroll
        for (int i = 0; i < 2; ++i) {
            int idx = t + i * 256;
            int key = idx & 31, cg = (idx >> 5) * 8;
            bf16x8 vv = *(const bf16x8*)(qkv + (size_t)tokOf(kt * 32 + key) * 384 + 256 + cg);
#pragma unroll
            for (int j = 0; j < 8; ++j) Vs[cg + j][key] = vv[j];
        }
        __syncthreads();

        f32x4 s0 = zero4, s1 = zero4;
#pragma unroll
        for (int c = 0; c < 4; ++c) {
            bf16x8 kf0 = *(const bf16x8*)&Ks[lr][c * 32 + lg * 8];
            bf16x8 kf1 = *(const bf16x8*)&Ks[16 + lr][c * 32 + lg * 8];
            s0 = MFMA_BF16(qf[c], kf0, s0);
            s1 = MFMA_BF16(qf[c], kf1, s1);
        }
#pragma unroll
        for (int r = 0; r < 4; ++r) { s0[r] *= SCALE; s1[r] *= SCALE; }
        if (SHIFT) {
            int lab0 = labOf(kt * 32 + lr);
            int lab1 = labOf(kt * 32 + 16 + lr);
#pragma unroll
            for (int r = 0; r < 4; ++r) {
                if (labq[r] != lab0) s0[r] -= 100.f;
                if (labq[r] != lab1) s1[r] -= 100.f;
            }
        }

#pragma unroll
        for (int r = 0; r < 4; ++r) {
            float mx = fmaxf(s0[r], s1[r]);
#pragma unroll
            for (int off = 1; off < 16; off <<= 1) mx = fmaxf(mx, __shfl_xor(mx, off));
            float nm = fmaxf(m_run[r], mx);
            float sc = expf(m_run[r] - nm);
            m_run[r] = nm;
            float p0 = expf(s0[r] - nm);
            float p1 = expf(s1[r] - nm);
            float rs = p0 + p1;
#pragma unroll
            for (int off = 1; off < 16; off <<= 1) rs += __shfl_xor(rs, off);
            l_run[r] = l_run[r] * sc + rs;
#pragma unroll
            for (int nf = 0; nf < 8; ++nf) o[nf][r] *= sc;
            Ps[wid][lg * 4 + r][lr]      = (bf16)p0;
            Ps[wid][lg * 4 + r][16 + lr] = (bf16)p1;
        }
        __syncthreads();

        bf16x8 pa = *(const bf16x8*)&Ps[wid][lr][lg * 8];
#pragma unroll
        for (int nf = 0; nf < 8; ++nf) {
            bf16x8 bv = *(const bf16x8*)&Vs[nf * 16 + lr][lg * 8];
            o[nf] = MFMA_BF16(pa, bv, o[nf]);
        }
        __syncthreads();
    }

#pragma unroll
    for (int r = 0; r < 4; ++r) {
        int qrow = qbase + lg * 4 + r;
        if (qrow >= 480) continue;
        float inv = 1.f / l_run[r];
        size_t ooff = (size_t)tokOf(qrow) * 128;
#pragma unroll
        for (int nf = 0; nf < 8; ++nf)
            out[ooff + nf * 16 + lr] = (bf16)(o[nf][r] * inv);
    }
}

// ---------------------------------------------------------------------------
// Host launcher
// ---------------------------------------------------------------------------
extern "C" void kernel_launch(void* const* d_in, const int* in_sizes, int n_in,
                              void* d_out, int out_size, void* d_ws, size_t ws_size,
                              hipStream_t stream)
{
    (void)in_sizes; (void)n_in; (void)out_size; (void)ws_size;

    const float* X = (const float*)d_in[0];

    // ---- workspace layout ----
    char* ws = (char*)d_ws;
    float* f    = (float*)ws;                                 ws += (size_t)cNTOK * 128 * 4;
    bf16*  xnb  = (bf16*)ws;                                  ws += (size_t)cNTOK * 128 * 2;
    bf16*  bufA = (bf16*)ws;                                  ws += (size_t)cNTOK * 512 * 2;
    bf16*  bufB = (bf16*)ws;                                  ws += (size_t)cNTOK * 512 * 2;
    bf16*  wts  = (bf16*)ws;

    size_t wo_off = 0;
    auto nextw = [&](int K, int M) { bf16* p = wts + wo_off; wo_off += (size_t)K * M; return p; };
    bf16* agg_w1t = nextw(256, 128);
    bf16* agg_w2t = nextw(128, 128);
    bf16* ol_wvt  = nextw(128, 128);
    bf16* ol_wat  = nextw(128, 81);
    bf16* ol_wot  = nextw(128, 128);
    bf16* f1_w1t  = nextw(128, 512);
    bf16* f1_w2t  = nextw(512, 128);
    bf16* w_qkvt  = nextw(128, 384);
    bf16* w_wot   = nextw(128, 128);
    bf16* f2_w1t  = nextw(128, 512);
    bf16* f2_w2t  = nextw(512, 128);
    bf16* s_qkvt  = nextw(128, 384);
    bf16* s_wot   = nextw(128, 128);
    bf16* f3_w1t  = nextw(128, 512);
    bf16* f3_w2t  = nextw(512, 128);
    float* dwt1 = (float*)(wts + wo_off);
    float* dwt2 = dwt1 + 512 * 9;
    float* dwt3 = dwt2 + 512 * 9;

    WJobs jobs;
    int ji = 0;
    auto addj = [&](int src_idx, bf16* dst, int K, int M) {
        jobs.j[ji++] = WJob{(const float*)d_in[src_idx], dst, K, M};
    };
    addj(1,  agg_w1t, 256, 128);
    addj(3,  agg_w2t, 128, 128);
    addj(7,  ol_wvt,  128, 128);
    addj(8,  ol_wat,  128, 81);
    addj(10, ol_wot,  128, 128);
    addj(14, f1_w1t,  128, 512);
    addj(18, f1_w2t,  512, 128);
    addj(22, w_qkvt,           128, 128);   // wq
    addj(23, w_qkvt + 128*128, 128, 128);   // wk
    addj(24, w_qkvt + 256*128, 128, 128);   // wv
    addj(25, w_wot,   128, 128);
    addj(29, f2_w1t,  128, 512);
    addj(33, f2_w2t,  512, 128);
    addj(37, s_qkvt,           128, 128);
    addj(38, s_qkvt + 128*128, 128, 128);
    addj(39, s_qkvt + 256*128, 128, 128);
    addj(40, s_wot,   128, 128);
    addj(44, f3_w1t,  128, 512);
    addj(48, f3_w2t,  512, 128);
    k_wt<<<dim3(16, 16, 19), dim3(32, 8), 0, stream>>>(jobs);
    k_dwt<<<3, 256, 0, stream>>>((const float*)d_in[16], (const float*)d_in[31],
                                 (const float*)d_in[46], dwt1, dwt2, dwt3);

    const dim3 gB1(1, cNTOK / 128), gB3(3, cNTOK / 128), gB4(4, cNTOK / 128);

    // ---- input transpose + aggregation MLP ----
    k_chw2hwc<<<dim3(cNPIX / 32, 256 / 32, cB), dim3(32, 8), 0, stream>>>(X, bufA);
    k_gemm_bf<true,  false, true ><<<gB1, 256, 0, stream>>>(
        bufA, agg_w1t, (const float*)d_in[2], nullptr, nullptr, bufB, 256, 128);
    k_gemm_bf<false, false, false><<<gB1, 256, 0, stream>>>(
        bufB, agg_w2t, (const float*)d_in[4], nullptr, f, nullptr, 128, 128);

    // ---- outlook attention ----
    {
        bf16*  vb   = bufA;
        bf16*  gout = bufA + (size_t)cNTOK * 128;
        float* atn  = (float*)bufB;
        float2* st  = (float2*)((float*)bufB + (size_t)cNTOK * 81);
        k_ln<<<cNTOK / 4, 256, 0, stream>>>(f, (const float*)d_in[5], (const float*)d_in[6], xnb);
        k_gemm_bf<false, false, true ><<<gB1, 256, 0, stream>>>(
            xnb, ol_wvt, nullptr, nullptr, nullptr, vb, 128, 128);
        k_gemm_bf<false, false, false><<<gB1, 256, 0, stream>>>(
            xnb, ol_wat, (const float*)d_in[9], nullptr, atn, nullptr, 128, 81);
        k_sm9_stats<<<cNTOK * 9 / 256, 256, 0, stream>>>(atn, st);
        k_olk_gather<<<cNTOK / 16, 256, 0, stream>>>(vb, atn, st, gout);
        k_gemm_bf<false, true, false><<<gB1, 256, 0, stream>>>(
            gout, ol_wot, (const float*)d_in[11], f, f, nullptr, 128, 128);
    }

    // ---- conv FFN ----
    auto run_ffn = [&](int base, bf16* w1t, bf16* w2t, float* dwt) {
        k_ln<<<cNTOK / 4, 256, 0, stream>>>(f, (const float*)d_in[base], (const float*)d_in[base + 1], xnb);
        k_gemm_bf<false, false, true ><<<gB4, 256, 0, stream>>>(
            xnb, w1t, (const float*)d_in[base + 3], nullptr, nullptr, bufA, 128, 512);
        k_dwconv_gelu<<<cB * cH * 8, 256, 0, stream>>>(
            bufA, dwt, (const float*)d_in[base + 5], bufB);
        k_gemm_bf<false, true, false><<<gB1, 256, 0, stream>>>(
            bufB, w2t, (const float*)d_in[base + 7], f, f, nullptr, 512, 128);
    };

    // ---- window attention ----
    auto run_win = [&](int base, bf16* qkvt, bf16* wot, bool shift) {
        k_ln<<<cNTOK / 4, 256, 0, stream>>>(f, (const float*)d_in[base], (const float*)d_in[base + 1], xnb);
        bf16* qkv = bufA;
        bf16* ao  = bufA + (size_t)cNTOK * 384;
        k_gemm_bf<false, false, true><<<gB3, 256, 0, stream>>>(
            xnb, qkvt, nullptr, nullptr, nullptr, qkv, 128, 384);
        if (shift) k_win_attn<true ><<<dim3(8, 64, cB), 256, 0, stream>>>(qkv, ao);
        else       k_win_attn<false><<<dim3(8, 64, cB), 256, 0, stream>>>(qkv, ao);
        k_gemm_bf<false, true, false><<<gB1, 256, 0, stream>>>(
            ao, wot, (const float*)d_in[base + 6], f, f, nullptr, 128, 128);
    };

    run_ffn(12, f1_w1t, f1_w2t, dwt1);                         // f1
    k_pos_add<<<(cNTOK * cC) / 256, 256, 0, stream>>>(f);      // pos embed
    run_win(20, w_qkvt, w_wot, false);                         // w
    run_ffn(27, f2_w1t, f2_w2t, dwt2);                         // f2
    run_win(35, s_qkvt, s_wot, true);                          // s (shifted)
    run_ffn(42, f3_w1t, f3_w2t, dwt3);                         // f3

    // ---- output transpose ----
    k_hwc2chw<<<dim3(cNPIX / 32, cC / 32, cB), dim3(32, 8), 0, stream>>>(f, (float*)d_out);
}

// Round 5
// 786.913 us; speedup vs baseline: 4.9539x; 1.0300x over previous
//
#include <hip/hip_runtime.h>

typedef __bf16 bf16;
typedef __bf16 bf16x8 __attribute__((ext_vector_type(8)));
typedef float  f32x4  __attribute__((ext_vector_type(4)));

#define MFMA_BF16(a, b, c) __builtin_amdgcn_mfma_f32_16x16x32_bf16(a, b, c, 0, 0, 0)

// ---------------------------------------------------------------------------
// Problem constants
// ---------------------------------------------------------------------------
constexpr int cB    = 2;
constexpr int cH    = 96;
constexpr int cW    = 320;
constexpr int cC    = 128;   // CV
constexpr int cNPIX = cH * cW;          // 30720
constexpr int cNTOK = cB * cNPIX;       // 61440

// ---------------------------------------------------------------------------
// Weight transpose+convert: fp32 W (K x M) -> bf16 Wt (M x K)
// ---------------------------------------------------------------------------
struct WJob  { const float* src; bf16* dst; int K; int M; };
struct WJobs { WJob j[19]; };

__global__ __launch_bounds__(256) void k_wt(WJobs jobs)
{
    __shared__ float tile[32][33];
    const WJob jb = jobs.j[blockIdx.z];
    int k0 = blockIdx.y * 32, m0 = blockIdx.x * 32;
    if (k0 >= jb.K || m0 >= jb.M) return;
    int tx = threadIdx.x, ty = threadIdx.y;   // (32, 8)
#pragma unroll
    for (int i = 0; i < 32; i += 8) {
        int kk = k0 + ty + i, mm = m0 + tx;
        tile[ty + i][tx] = (kk < jb.K && mm < jb.M) ? jb.src[(size_t)kk * jb.M + mm] : 0.f;
    }
    __syncthreads();
#pragma unroll
    for (int i = 0; i < 32; i += 8) {
        int mm = m0 + ty + i, kk = k0 + tx;
        if (mm < jb.M && kk < jb.K)
            jb.dst[(size_t)mm * jb.K + kk] = (bf16)tile[tx][ty + i];
    }
}

// Depthwise weight transpose: [512][9] -> [9][512] fp32, 3 layers
__global__ __launch_bounds__(256) void k_dwt(const float* s0, const float* s1, const float* s2,
                                             float* d0, float* d1, float* d2)
{
    const float* s = blockIdx.x == 0 ? s0 : (blockIdx.x == 1 ? s1 : s2);
    float*       d = blockIdx.x == 0 ? d0 : (blockIdx.x == 1 ? d1 : d2);
    for (int i = threadIdx.x; i < 512 * 9; i += 256) {
        int c = i / 9, tap = i - c * 9;
        d[tap * 512 + c] = s[i];
    }
}

// Positional-embedding tables: ytab[96][64], xtab[320][64]
__global__ __launch_bounds__(256) void k_postab(float* __restrict__ yt, float* __restrict__ xt)
{
    int i = blockIdx.x * 256 + threadIdx.x;
    const float TWO_PI = 6.283185307179586f;
    const float KSC = -9.210340371976184f / 32.f;
    if (i < 96 * 64) {
        int h = i >> 6, c = i & 63;
        float p = (float)(h + 1) * (TWO_PI / (96.f + 1e-6f));
        float val = p * expf((float)(c >> 1) * KSC);
        yt[i] = (c & 1) ? cosf(val) : sinf(val);
    }
    if (i < 320 * 64) {
        int w = i >> 6, c = i & 63;
        float p = (float)(w + 1) * (TWO_PI / (320.f + 1e-6f));
        float val = p * expf((float)(c >> 1) * KSC);
        xt[i] = (c & 1) ? cosf(val) : sinf(val);
    }
}

// ---------------------------------------------------------------------------
// Transpose (B, C=256, HW) -> (B, HW, C) bf16   (input x)
// ---------------------------------------------------------------------------
__global__ __launch_bounds__(256) void k_chw2hwc(const float* __restrict__ in,
                                                 bf16* __restrict__ out)
{
    __shared__ float tile[32][33];
    const int Cc = 256;
    int s0 = blockIdx.x * 32;
    int c0 = blockIdx.y * 32;
    int b  = blockIdx.z;
    const float* ip = in  + (size_t)b * Cc * cNPIX;
    bf16*        op = out + (size_t)b * cNPIX * Cc;
    int tx = threadIdx.x, ty = threadIdx.y;
#pragma unroll
    for (int i = 0; i < 32; i += 8)
        tile[ty + i][tx] = ip[(size_t)(c0 + ty + i) * cNPIX + s0 + tx];
    __syncthreads();
#pragma unroll
    for (int i = 0; i < 32; i += 8)
        op[(size_t)(s0 + ty + i) * Cc + c0 + tx] = (bf16)tile[tx][ty + i];
}

// (B, HW, C=128) fp32 -> (B, C, HW) fp32  (final output)
__global__ __launch_bounds__(256) void k_hwc2chw(const float* __restrict__ in,
                                                 float* __restrict__ out)
{
    __shared__ float tile[32][33];
    int s0 = blockIdx.x * 32;
    int c0 = blockIdx.y * 32;
    int b  = blockIdx.z;
    const float* ip = in  + (size_t)b * cNPIX * cC;
    float*       op = out + (size_t)b * cC * cNPIX;
    int tx = threadIdx.x, ty = threadIdx.y;
#pragma unroll
    for (int i = 0; i < 32; i += 8)
        tile[ty + i][tx] = ip[(size_t)(s0 + ty + i) * cC + c0 + tx];
    __syncthreads();
#pragma unroll
    for (int i = 0; i < 32; i += 8)
        op[(size_t)(c0 + ty + i) * cNPIX + s0 + tx] = tile[tx][ty + i];
}

// ---------------------------------------------------------------------------
// bf16 MFMA GEMM (128x128 tile, BK=32, 4 waves)
// QKV mode: M=384; cols 0..255 -> qkb[tok][256]; cols 256..383 -> vt scatter
//           vt[((b*64+win)*128 + ch)*480 + key], window coords shifted by shH/shW.
// POS mode: adds table-based positional embedding in the epilogue.
// ---------------------------------------------------------------------------
template<bool RELU, bool RES, bool OUTBF, bool QKV, bool POS>
__global__ __launch_bounds__(256) void k_gemm_bf(const bf16* __restrict__ A,
                                                 const bf16* __restrict__ Wt,
                                                 const float* __restrict__ bias,
                                                 const float* __restrict__ res,
                                                 float* __restrict__ outF,
                                                 bf16* __restrict__ outB,
                                                 int K, int M,
                                                 bf16* __restrict__ vtb, int shH, int shW,
                                                 const float* __restrict__ ytab,
                                                 const float* __restrict__ xtab)
{
    __shared__ bf16 As[128][40];
    __shared__ bf16 Bs[128][40];
    const int bm = blockIdx.y * 128;
    const int bn = blockIdx.x * 128;
    const int t    = threadIdx.x;
    const int lane = t & 63;
    const int wid  = t >> 6;
    const int wm = (wid >> 1) * 64, wn = (wid & 1) * 64;
    const int lr = lane & 15, lg = lane >> 4;

    const f32x4 zero4 = {0.f, 0.f, 0.f, 0.f};
    f32x4 acc[4][4];
#pragma unroll
    for (int i = 0; i < 4; ++i)
#pragma unroll
        for (int j = 0; j < 4; ++j) acc[i][j] = zero4;

    bf16x8 zrow;
#pragma unroll
    for (int j = 0; j < 8; ++j) zrow[j] = (bf16)0.f;

    for (int k0 = 0; k0 < K; k0 += 32) {
#pragma unroll
        for (int i = 0; i < 2; ++i) {
            int idx = t + i * 256;
            int row = idx >> 2, kg = (idx & 3) * 8;
            *(bf16x8*)&As[row][kg] =
                *(const bf16x8*)(A + (size_t)(bm + row) * K + k0 + kg);
            int m = bn + row;
            bf16x8 wv = zrow;
            if (m < M) wv = *(const bf16x8*)(Wt + (size_t)m * K + k0 + kg);
            *(bf16x8*)&Bs[row][kg] = wv;
        }
        __syncthreads();
        bf16x8 af[4], bf[4];
#pragma unroll
        for (int mf = 0; mf < 4; ++mf)
            af[mf] = *(const bf16x8*)&As[wm + mf * 16 + lr][lg * 8];
#pragma unroll
        for (int nf = 0; nf < 4; ++nf)
            bf[nf] = *(const bf16x8*)&Bs[wn + nf * 16 + lr][lg * 8];
        __builtin_amdgcn_s_setprio(1);
#pragma unroll
        for (int mf = 0; mf < 4; ++mf)
#pragma unroll
            for (int nf = 0; nf < 4; ++nf)
                acc[mf][nf] = MFMA_BF16(af[mf], bf[nf], acc[mf][nf]);
        __builtin_amdgcn_s_setprio(0);
        __syncthreads();
    }

#pragma unroll
    for (int nf = 0; nf < 4; ++nf) {
        int col = bn + wn + nf * 16 + lr;
        if (col >= M) continue;
        float bv = bias ? bias[col] : 0.f;
#pragma unroll
        for (int mf = 0; mf < 4; ++mf) {
#pragma unroll
            for (int r = 0; r < 4; ++r) {
                int row = bm + wm + mf * 16 + lg * 4 + r;
                float vv = acc[mf][nf][r] + bv;
                if (RELU) vv = fmaxf(vv, 0.f);
                if (QKV) {
                    if (col < 256) {
                        outB[(size_t)row * 256 + col] = (bf16)vv;
                    } else {
                        int bb = row / cNPIX;
                        int hw = row - bb * cNPIX;
                        int h = hw / cW, w = hw - (hw / cW) * cW;
                        int h0 = h - shH; if (h0 < 0) h0 += cH;
                        int w0 = w - shW; if (w0 < 0) w0 += cW;
                        int nh = h0 / 12, kh = h0 - nh * 12;
                        int nw = w0 / 40, kw = w0 - nw * 40;
                        int win = nh * 8 + nw, key = kh * 40 + kw;
                        vtb[((size_t)(bb * 64 + win) * 128 + (col - 256)) * 480 + key] = (bf16)vv;
                    }
                } else {
                    if (POS) {
                        int hw = row % cNPIX;
                        int h = hw / cW, w = hw - (hw / cW) * cW;
                        vv += (col < 64) ? ytab[(h << 6) + col] : xtab[(w << 6) + col - 64];
                    }
                    if (RES)  vv += res[(size_t)row * M + col];
                    if (OUTBF) outB[(size_t)row * M + col] = (bf16)vv;
                    else       outF[(size_t)row * M + col] = vv;
                }
            }
        }
    }
}

// ---------------------------------------------------------------------------
// LayerNorm over C=128 (fp32 in, bf16 out)
// ---------------------------------------------------------------------------
__global__ __launch_bounds__(256) void k_ln(const float* __restrict__ x,
                                            const float* __restrict__ g,
                                            const float* __restrict__ b,
                                            bf16* __restrict__ out)
{
    int tok  = blockIdx.x * 4 + (threadIdx.x >> 6);
    int lane = threadIdx.x & 63;
    float2 v = *(const float2*)(x + (size_t)tok * cC + lane * 2);
    float s = v.x + v.y;
#pragma unroll
    for (int o = 1; o < 64; o <<= 1) s += __shfl_xor(s, o);
    float mu = s * (1.f / cC);
    float dx = v.x - mu, dy = v.y - mu;
    float sq = dx * dx + dy * dy;
#pragma unroll
    for (int o = 1; o < 64; o <<= 1) sq += __shfl_xor(sq, o);
    float rs = rsqrtf(sq * (1.f / cC) + 1e-5f);
    float2 gv = *(const float2*)(g + lane * 2);
    float2 bv = *(const float2*)(b + lane * 2);
    union { bf16 h[2]; unsigned int u; } o2;
    o2.h[0] = (bf16)(dx * rs * gv.x + bv.x);
    o2.h[1] = (bf16)(dy * rs * gv.y + bv.y);
    *(unsigned int*)(out + (size_t)tok * cC + lane * 2) = o2.u;
}

// ---------------------------------------------------------------------------
// Sink-softmax stats per 9-row: st = (m, 1/(sum exp(v-m) + exp(-m)))
// ---------------------------------------------------------------------------
__global__ __launch_bounds__(256) void k_sm9_stats(const float* __restrict__ a,
                                                   float2* __restrict__ st)
{
    __shared__ float buf[4][576];
    int wid = threadIdx.x >> 6, lane = threadIdx.x & 63;
    int rowbase = blockIdx.x * 256 + wid * 64;
    const float* src = a + (size_t)rowbase * 9;
#pragma unroll
    for (int i = 0; i < 9; ++i)
        buf[wid][lane + i * 64] = src[lane + i * 64];
    __syncthreads();
    float v[9];
#pragma unroll
    for (int i = 0; i < 9; ++i) v[i] = buf[wid][lane * 9 + i];
    float m = 0.f;
#pragma unroll
    for (int i = 0; i < 9; ++i) m = fmaxf(m, v[i]);
    float se = 0.f;
#pragma unroll
    for (int i = 0; i < 9; ++i) se += __expf(v[i] - m);
    float2 o; o.x = m; o.y = 1.f / (se + __expf(-m));
    st[rowbase + lane] = o;
}

// ---------------------------------------------------------------------------
// Outlook fused gather, 25-offset form.
// ---------------------------------------------------------------------------
__global__ __launch_bounds__(256) void k_olk_gather(const bf16* __restrict__ v,
                                                    const float* __restrict__ attn,
                                                    const float2* __restrict__ st,
                                                    bf16* __restrict__ y)
{
    __shared__ float pr[16][84];
    __shared__ float coef[16][26];

    const int t  = threadIdx.x;
    const int px = t >> 4;
    const int j  = t & 15;
    const int pix = blockIdx.x * 16 + px;
    const int b  = pix / cNPIX;
    const int hw = pix % cNPIX;
    const int h = hw / cW, w = hw % cW;

    if (j < 9) {
        const int p  = j;
        const int pi = p / 3, pj = p - pi * 3;
        const int hh = h + 1 - pi, ww = w + 1 - pj;
        float prv[9];
        if ((unsigned)hh < (unsigned)cH && (unsigned)ww < (unsigned)cW) {
            const size_t row = (size_t)(b * cNPIX + hh * cW + ww);
            const float* arow = attn + row * 81 + p * 9;
            const float2 s = st[row * 9 + p];
#pragma unroll
            for (int q = 0; q < 9; ++q) prv[q] = __expf(arow[q] - s.x) * s.y;
        } else {
#pragma unroll
            for (int q = 0; q < 9; ++q) prv[q] = 0.f;
        }
#pragma unroll
        for (int q = 0; q < 9; ++q) pr[px][p * 9 + q] = prv[q];
    }
    __syncthreads();

    for (int d = j; d < 25; d += 16) {
        const int a  = d / 5, bb = d - a * 5;
        float s = 0.f;
#pragma unroll
        for (int pi = 0; pi < 3; ++pi) {
            const int qi = pi + a - 2;
            if ((unsigned)qi >= 3u) continue;
#pragma unroll
            for (int pj = 0; pj < 3; ++pj) {
                const int qj = pj + bb - 2;
                if ((unsigned)qj >= 3u) continue;
                s += pr[px][(pi * 3 + pj) * 9 + qi * 3 + qj];
            }
        }
        coef[px][d] = s;
    }
    __syncthreads();

    float acc[8] = {};
    const size_t bbase = (size_t)b * cNPIX;
#pragma unroll
    for (int a = 0; a < 5; ++a) {
        const int sh = h + a - 2;
        if ((unsigned)sh >= (unsigned)cH) continue;
#pragma unroll
        for (int bb = 0; bb < 5; ++bb) {
            const int sw = w + bb - 2;
            if ((unsigned)sw >= (unsigned)cW) continue;
            const float cf = coef[px][a * 5 + bb];
            const bf16x8 v8 = *(const bf16x8*)(v + ((bbase + (size_t)sh * cW + sw) * 128 + j * 8));
#pragma unroll
            for (int e = 0; e < 8; ++e) acc[e] = fmaf(cf, (float)v8[e], acc[e]);
        }
    }
    bf16x8 o8;
#pragma unroll
    for (int e = 0; e < 8; ++e) o8[e] = (bf16)acc[e];
    *(bf16x8*)(y + (size_t)pix * 128 + j * 8) = o8;
}

// ---------------------------------------------------------------------------
// Depthwise 3x3 + bias + exact GELU, row-sliding, NHWC 512 ch.
// ---------------------------------------------------------------------------
__global__ __launch_bounds__(256) void k_dwconv_gelu(const bf16* __restrict__ h1,
                                                     const float* __restrict__ dwt,
                                                     const float* __restrict__ bdw,
                                                     bf16* __restrict__ h2)
{
    const int t   = threadIdx.x;
    const int c2  = t * 2;
    const int blk = blockIdx.x;
    const int row = blk >> 3;
    const int seg = blk & 7;
    const int bb  = row / cH, h = row % cH;
    const int w0  = seg * 40;

    float2 wgt[9];
#pragma unroll
    for (int k = 0; k < 9; ++k)
        wgt[k] = *(const float2*)(dwt + k * 512 + c2);
    const float2 bias = *(const float2*)(bdw + c2);

    const size_t base = (size_t)bb * cNPIX;

    auto ld = [&](int hh, int ww) -> float2 {
        float2 r; r.x = 0.f; r.y = 0.f;
        if ((unsigned)hh < (unsigned)cH && (unsigned)ww < (unsigned)cW) {
            unsigned u = *(const unsigned*)(h1 + ((base + (size_t)hh * cW + ww) * 512 + c2));
            r.x = __uint_as_float(u << 16);
            r.y = __uint_as_float(u & 0xffff0000u);
        }
        return r;
    };

    float2 cm[3], c0[3], cp[3];
#pragma unroll
    for (int r = 0; r < 3; ++r) {
        cm[r] = ld(h + r - 1, w0 - 1);
        c0[r] = ld(h + r - 1, w0);
    }

    for (int j = 0; j < 40; ++j) {
#pragma unroll
        for (int r = 0; r < 3; ++r) cp[r] = ld(h + r - 1, w0 + j + 1);
        float a0 = bias.x, a1 = bias.y;
#pragma unroll
        for (int r = 0; r < 3; ++r) {
            a0 = fmaf(cm[r].x, wgt[r * 3 + 0].x, a0);
            a1 = fmaf(cm[r].y, wgt[r * 3 + 0].y, a1);
            a0 = fmaf(c0[r].x, wgt[r * 3 + 1].x, a0);
            a1 = fmaf(c0[r].y, wgt[r * 3 + 1].y, a1);
            a0 = fmaf(cp[r].x, wgt[r * 3 + 2].x, a0);
            a1 = fmaf(cp[r].y, wgt[r * 3 + 2].y, a1);
        }
        a0 = 0.5f * a0 * (1.f + erff(a0 * 0.70710678118654752f));
        a1 = 0.5f * a1 * (1.f + erff(a1 * 0.70710678118654752f));
        union { bf16 hh[2]; unsigned int u; } o2;
        o2.hh[0] = (bf16)a0;
        o2.hh[1] = (bf16)a1;
        *(unsigned int*)(h2 + (base + (size_t)h * cW + w0 + j) * 512 + c2) = o2.u;
#pragma unroll
        for (int r = 0; r < 3; ++r) { cm[r] = c0[r]; c0[r] = cp[r]; }
    }
}

// ---------------------------------------------------------------------------
// Window attention, MFMA flash-style, sink softmax (shift-invariant exact).
// qk: [tok][256] = {q,k}. vt: [(b*64+win)*128 + ch][480 keys] (pre-rolled).
// Grid (128 = b*64+win, 8 qblocks). Block 256 = 4 waves x 16 q-rows.
// Double-buffered LDS, 1 barrier/tile; l via MFMA(P, ones); defer-max THR=8.
// ---------------------------------------------------------------------------
template<bool SHIFT>
__global__ __launch_bounds__(256) void k_win_attn(const bf16* __restrict__ qk,
                                                  const bf16* __restrict__ vt,
                                                  bf16* __restrict__ out)
{
    __shared__ bf16 Ks[2][32][136];
    __shared__ bf16 Vs[2][128][40];
    __shared__ bf16 Ps[4][16][40];

    const int t = threadIdx.x, lane = t & 63, wid = t >> 6;
    const int lr = lane & 15, lg = lane >> 4;
    const int wb = blockIdx.x;            // b*64 + win
    const int b  = wb >> 6, win = wb & 63;
    const int nh = win >> 3, nw = win & 7;
    const int qbase = blockIdx.y * 64 + wid * 16;

    const float SCALE   = 0.088388347648318447f;   // 1/sqrt(128)
    const float MASKRAW = 100.f / 0.088388347648318447f;

    auto tokOf = [&](int p) {
        int ph = nh * 12 + p / 40;
        int pw = nw * 40 + (p % 40);
        if (SHIFT) {
            ph += 6;  if (ph >= cH) ph -= cH;
            pw += 20; if (pw >= cW) pw -= cW;
        }
        return b * cNPIX + ph * cW + pw;
    };
    auto labOf = [&](int p) {
        int ph = nh * 12 + p / 40;
        int pw = nw * 40 + (p % 40);
        int rh = ph < 84 ? 0 : (ph < 90 ? 1 : 2);
        int rc = pw < 280 ? 0 : (pw < 300 ? 1 : 2);
        return rh * 3 + rc;
    };

    // Q fragments
    int qp = min(qbase + lr, 479);
    const bf16* qptr = qk + (size_t)tokOf(qp) * 256;
    bf16x8 qf[4];
#pragma unroll
    for (int c = 0; c < 4; ++c)
        qf[c] = *(const bf16x8*)(qptr + c * 32 + lg * 8);

    int labq[4];
    if (SHIFT) {
#pragma unroll
        for (int r = 0; r < 4; ++r) labq[r] = labOf(min(qbase + lg * 4 + r, 479));
    }

    const bf16* vbase = vt + (size_t)wb * 128 * 480;
    auto loadK = [&](int kt, int i) {
        int idx = t + i * 256;
        int key = idx >> 4, cg = (idx & 15) * 8;
        return *(const bf16x8*)(qk + (size_t)tokOf(kt * 32 + key) * 256 + 128 + cg);
    };
    auto loadV = [&](int kt, int i) {
        int idx = t + i * 256;
        int ch = idx >> 2, kq = (idx & 3) * 8;
        return *(const bf16x8*)(vbase + (size_t)ch * 480 + kt * 32 + kq);
    };

    bf16x8 kreg0 = loadK(0, 0), kreg1 = loadK(0, 1);
    bf16x8 vreg0 = loadV(0, 0), vreg1 = loadV(0, 1);

    const f32x4 zero4 = {0.f, 0.f, 0.f, 0.f};
    float m_run[4] = {0.f, 0.f, 0.f, 0.f};
    float mguard = 8.f;
    f32x4 l4 = zero4;
    f32x4 o[8];
#pragma unroll
    for (int nf = 0; nf < 8; ++nf) o[nf] = zero4;

    bf16x8 ones8;
#pragma unroll
    for (int j = 0; j < 8; ++j) ones8[j] = (bf16)1.f;

    int buf = 0;
    for (int kt = 0; kt < 15; ++kt) {
        // write staged regs -> LDS[buf]
        {
            int i0 = t, i1 = t + 256;
            *(bf16x8*)&Ks[buf][i0 >> 4][(i0 & 15) * 8] = kreg0;
            *(bf16x8*)&Ks[buf][i1 >> 4][(i1 & 15) * 8] = kreg1;
            *(bf16x8*)&Vs[buf][i0 >> 2][(i0 & 3) * 8] = vreg0;
            *(bf16x8*)&Vs[buf][i1 >> 2][(i1 & 3) * 8] = vreg1;
        }
        // issue next tile's global loads (land under compute)
        if (kt + 1 < 15) {
            kreg0 = loadK(kt + 1, 0); kreg1 = loadK(kt + 1, 1);
            vreg0 = loadV(kt + 1, 0); vreg1 = loadV(kt + 1, 1);
        }
        __syncthreads();

        // QK^T
        f32x4 s0 = zero4, s1 = zero4;
        __builtin_amdgcn_s_setprio(1);
#pragma unroll
        for (int c = 0; c < 4; ++c) {
            bf16x8 kf0 = *(const bf16x8*)&Ks[buf][lr][c * 32 + lg * 8];
            bf16x8 kf1 = *(const bf16x8*)&Ks[buf][16 + lr][c * 32 + lg * 8];
            s0 = MFMA_BF16(qf[c], kf0, s0);
            s1 = MFMA_BF16(qf[c], kf1, s1);
        }
        __builtin_amdgcn_s_setprio(0);

        if (SHIFT) {
            int lab0 = labOf(kt * 32 + lr);
            int lab1 = labOf(kt * 32 + 16 + lr);
#pragma unroll
            for (int r = 0; r < 4; ++r) {
                if (labq[r] != lab0) s0[r] -= MASKRAW;
                if (labq[r] != lab1) s1[r] -= MASKRAW;
            }
        }

        // overflow guard (defer-max, exact for sink softmax)
        float tm = fmaxf(fmaxf(fmaxf(s0[0], s0[1]), fmaxf(s0[2], s0[3])),
                         fmaxf(fmaxf(s1[0], s1[1]), fmaxf(s1[2], s1[3])));
#pragma unroll
        for (int off = 1; off < 16; off <<= 1) tm = fmaxf(tm, __shfl_xor(tm, off));
        if (tm * SCALE > mguard) {
#pragma unroll
            for (int r = 0; r < 4; ++r) {
                float mx = fmaxf(s0[r], s1[r]);
#pragma unroll
                for (int off = 1; off < 16; off <<= 1) mx = fmaxf(mx, __shfl_xor(mx, off));
                float nm = fmaxf(m_run[r], mx * SCALE);
                float sc = __expf(m_run[r] - nm);
#pragma unroll
                for (int nf = 0; nf < 8; ++nf) o[nf][r] *= sc;
                l4[r] *= sc;
                m_run[r] = nm;
            }
            mguard = fminf(fminf(m_run[0], m_run[1]), fminf(m_run[2], m_run[3])) + 8.f;
        }

        // P = exp(s*SCALE - m) -> per-wave LDS
#pragma unroll
        for (int r = 0; r < 4; ++r) {
            float p0 = __expf(fmaf(s0[r], SCALE, -m_run[r]));
            float p1 = __expf(fmaf(s1[r], SCALE, -m_run[r]));
            Ps[wid][lg * 4 + r][lr]      = (bf16)p0;
            Ps[wid][lg * 4 + r][16 + lr] = (bf16)p1;
        }

        // PV + row-sum (l) via MFMA
        bf16x8 pa = *(const bf16x8*)&Ps[wid][lr][lg * 8];
        __builtin_amdgcn_s_setprio(1);
        l4 = MFMA_BF16(pa, ones8, l4);
#pragma unroll
        for (int nf = 0; nf < 8; ++nf) {
            bf16x8 bv = *(const bf16x8*)&Vs[buf][nf * 16 + lr][lg * 8];
            o[nf] = MFMA_BF16(pa, bv, o[nf]);
        }
        __builtin_amdgcn_s_setprio(0);
        __syncthreads();
        buf ^= 1;
    }

#pragma unroll
    for (int r = 0; r < 4; ++r) {
        int qrow = qbase + lg * 4 + r;
        if (qrow >= 480) continue;
        float inv = 1.f / (l4[r] + __expf(-m_run[r]));   // + sink term
        size_t ooff = (size_t)tokOf(qrow) * 128;
#pragma unroll
        for (int nf = 0; nf < 8; ++nf)
            out[ooff + nf * 16 + lr] = (bf16)(o[nf][r] * inv);
    }
}

// ---------------------------------------------------------------------------
// Host launcher
// ---------------------------------------------------------------------------
extern "C" void kernel_launch(void* const* d_in, const int* in_sizes, int n_in,
                              void* d_out, int out_size, void* d_ws, size_t ws_size,
                              hipStream_t stream)
{
    (void)in_sizes; (void)n_in; (void)out_size; (void)ws_size;

    const float* X = (const float*)d_in[0];

    // ---- workspace layout ----
    char* ws = (char*)d_ws;
    float* f    = (float*)ws;                                 ws += (size_t)cNTOK * 128 * 4;
    bf16*  xnb  = (bf16*)ws;                                  ws += (size_t)cNTOK * 128 * 2;
    bf16*  bufA = (bf16*)ws;                                  ws += (size_t)cNTOK * 512 * 2;
    bf16*  bufB = (bf16*)ws;                                  ws += (size_t)cNTOK * 512 * 2;
    bf16*  wts  = (bf16*)ws;

    size_t wo_off = 0;
    auto nextw = [&](int K, int M) { bf16* p = wts + wo_off; wo_off += (size_t)K * M; return p; };
    bf16* agg_w1t = nextw(256, 128);
    bf16* agg_w2t = nextw(128, 128);
    bf16* ol_wvt  = nextw(128, 128);
    bf16* ol_wat  = nextw(128, 81);
    bf16* ol_wot  = nextw(128, 128);
    bf16* f1_w1t  = nextw(128, 512);
    bf16* f1_w2t  = nextw(512, 128);
    bf16* w_qkvt  = nextw(128, 384);
    bf16* w_wot   = nextw(128, 128);
    bf16* f2_w1t  = nextw(128, 512);
    bf16* f2_w2t  = nextw(512, 128);
    bf16* s_qkvt  = nextw(128, 384);
    bf16* s_wot   = nextw(128, 128);
    bf16* f3_w1t  = nextw(128, 512);
    bf16* f3_w2t  = nextw(512, 128);
    float* dwt1 = (float*)(wts + wo_off);
    float* dwt2 = dwt1 + 512 * 9;
    float* dwt3 = dwt2 + 512 * 9;
    float* ytab = dwt3 + 512 * 9;
    float* xtab = ytab + 96 * 64;

    WJobs jobs;
    int ji = 0;
    auto addj = [&](int src_idx, bf16* dst, int K, int M) {
        jobs.j[ji++] = WJob{(const float*)d_in[src_idx], dst, K, M};
    };
    addj(1,  agg_w1t, 256, 128);
    addj(3,  agg_w2t, 128, 128);
    addj(7,  ol_wvt,  128, 128);
    addj(8,  ol_wat,  128, 81);
    addj(10, ol_wot,  128, 128);
    addj(14, f1_w1t,  128, 512);
    addj(18, f1_w2t,  512, 128);
    addj(22, w_qkvt,           128, 128);   // wq
    addj(23, w_qkvt + 128*128, 128, 128);   // wk
    addj(24, w_qkvt + 256*128, 128, 128);   // wv
    addj(25, w_wot,   128, 128);
    addj(29, f2_w1t,  128, 512);
    addj(33, f2_w2t,  512, 128);
    addj(37, s_qkvt,           128, 128);
    addj(38, s_qkvt + 128*128, 128, 128);
    addj(39, s_qkvt + 256*128, 128, 128);
    addj(40, s_wot,   128, 128);
    addj(44, f3_w1t,  128, 512);
    addj(48, f3_w2t,  512, 128);
    k_wt<<<dim3(16, 16, 19), dim3(32, 8), 0, stream>>>(jobs);
    k_dwt<<<3, 256, 0, stream>>>((const float*)d_in[16], (const float*)d_in[31],
                                 (const float*)d_in[46], dwt1, dwt2, dwt3);
    k_postab<<<80, 256, 0, stream>>>(ytab, xtab);

    const dim3 gB1(1, cNTOK / 128), gB3(3, cNTOK / 128), gB4(4, cNTOK / 128);

    // ---- input transpose + aggregation MLP ----
    k_chw2hwc<<<dim3(cNPIX / 32, 256 / 32, cB), dim3(32, 8), 0, stream>>>(X, bufA);
    k_gemm_bf<true,  false, true,  false, false><<<gB1, 256, 0, stream>>>(
        bufA, agg_w1t, (const float*)d_in[2], nullptr, nullptr, bufB, 256, 128,
        nullptr, 0, 0, nullptr, nullptr);
    k_gemm_bf<false, false, false, false, false><<<gB1, 256, 0, stream>>>(
        bufB, agg_w2t, (const float*)d_in[4], nullptr, f, nullptr, 128, 128,
        nullptr, 0, 0, nullptr, nullptr);

    // ---- outlook attention ----
    {
        bf16*  vb   = bufA;
        bf16*  gout = bufA + (size_t)cNTOK * 128;
        float* atn  = (float*)bufB;
        float2* st  = (float2*)((float*)bufB + (size_t)cNTOK * 81);
        k_ln<<<cNTOK / 4, 256, 0, stream>>>(f, (const float*)d_in[5], (const float*)d_in[6], xnb);
        k_gemm_bf<false, false, true,  false, false><<<gB1, 256, 0, stream>>>(
            xnb, ol_wvt, nullptr, nullptr, nullptr, vb, 128, 128,
            nullptr, 0, 0, nullptr, nullptr);
        k_gemm_bf<false, false, false, false, false><<<gB1, 256, 0, stream>>>(
            xnb, ol_wat, (const float*)d_in[9], nullptr, atn, nullptr, 128, 81,
            nullptr, 0, 0, nullptr, nullptr);
        k_sm9_stats<<<cNTOK * 9 / 256, 256, 0, stream>>>(atn, st);
        k_olk_gather<<<cNTOK / 16, 256, 0, stream>>>(vb, atn, st, gout);
        k_gemm_bf<false, true, false, false, false><<<gB1, 256, 0, stream>>>(
            gout, ol_wot, (const float*)d_in[11], f, f, nullptr, 128, 128,
            nullptr, 0, 0, nullptr, nullptr);
    }

    // ---- conv FFN (POS: fuse positional embedding into f1's residual GEMM) ----
    auto run_ffn = [&](int base, bf16* w1t, bf16* w2t, float* dwt, bool pos) {
        k_ln<<<cNTOK / 4, 256, 0, stream>>>(f, (const float*)d_in[base], (const float*)d_in[base + 1], xnb);
        k_gemm_bf<false, false, true, false, false><<<gB4, 256, 0, stream>>>(
            xnb, w1t, (const float*)d_in[base + 3], nullptr, nullptr, bufA, 128, 512,
            nullptr, 0, 0, nullptr, nullptr);
        k_dwconv_gelu<<<cB * cH * 8, 256, 0, stream>>>(
            bufA, dwt, (const float*)d_in[base + 5], bufB);
        if (pos)
            k_gemm_bf<false, true, false, false, true><<<gB1, 256, 0, stream>>>(
                bufB, w2t, (const float*)d_in[base + 7], f, f, nullptr, 512, 128,
                nullptr, 0, 0, ytab, xtab);
        else
            k_gemm_bf<false, true, false, false, false><<<gB1, 256, 0, stream>>>(
                bufB, w2t, (const float*)d_in[base + 7], f, f, nullptr, 512, 128,
                nullptr, 0, 0, nullptr, nullptr);
    };

    // ---- window attention ----
    auto run_win = [&](int base, bf16* qkvt, bf16* wot, bool shift) {
        k_ln<<<cNTOK / 4, 256, 0, stream>>>(f, (const float*)d_in[base], (const float*)d_in[base + 1], xnb);
        bf16* qkb = bufA;                                   // [tok][256]
        bf16* vtb = bufA + (size_t)cNTOK * 256;             // [(b*64+win)*128+ch][480]
        bf16* ao  = bufB;                                   // [tok][128]
        k_gemm_bf<false, false, false, true, false><<<gB3, 256, 0, stream>>>(
            xnb, qkvt, nullptr, nullptr, nullptr, qkb, 128, 384,
            vtb, shift ? 6 : 0, shift ? 20 : 0, nullptr, nullptr);
        if (shift) k_win_attn<true ><<<dim3(128, 8), 256, 0, stream>>>(qkb, vtb, ao);
        else       k_win_attn<false><<<dim3(128, 8), 256, 0, stream>>>(qkb, vtb, ao);
        k_gemm_bf<false, true, false, false, false><<<gB1, 256, 0, stream>>>(
            ao, wot, (const float*)d_in[base + 6], f, f, nullptr, 128, 128,
            nullptr, 0, 0, nullptr, nullptr);
    };

    run_ffn(12, f1_w1t, f1_w2t, dwt1, true);                   // f1 (+pos fused)
    run_win(20, w_qkvt, w_wot, false);                         // w
    run_ffn(27, f2_w1t, f2_w2t, dwt2, false);                  // f2
    run_win(35, s_qkvt, s_wot, true);                          // s (shifted)
    run_ffn(42, f3_w1t, f3_w2t, dwt3, false);                  // f3

    // ---- output transpose ----
    k_hwc2chw<<<dim3(cNPIX / 32, cC / 32, cB), dim3(32, 8), 0, stream>>>(f, (float*)d_out);
}

// Round 6
// 772.636 us; speedup vs baseline: 5.0455x; 1.0185x over previous
//
#include <hip/hip_runtime.h>

typedef __bf16 bf16;
typedef __bf16 bf16x8 __attribute__((ext_vector_type(8)));
typedef __bf16 bf16x4 __attribute__((ext_vector_type(4)));
typedef float  f32x4  __attribute__((ext_vector_type(4)));

#define MFMA_BF16(a, b, c) __builtin_amdgcn_mfma_f32_16x16x32_bf16(a, b, c, 0, 0, 0)

constexpr int cB    = 2;
constexpr int cH    = 96;
constexpr int cW    = 320;
constexpr int cC    = 128;
constexpr int cNPIX = cH * cW;          // 30720
constexpr int cNTOK = cB * cNPIX;       // 61440
constexpr int cAS   = 84;               // padded attn-logit stride (81 -> 84)

// ---------------------------------------------------------------------------
// Weight transpose+convert: fp32 W (K x M) -> bf16 Wt (M x K)
// ---------------------------------------------------------------------------
struct WJob  { const float* src; bf16* dst; int K; int M; };
struct WJobs { WJob j[19]; };

__global__ __launch_bounds__(256) void k_wt(WJobs jobs)
{
    __shared__ float tile[32][33];
    const WJob jb = jobs.j[blockIdx.z];
    int k0 = blockIdx.y * 32, m0 = blockIdx.x * 32;
    if (k0 >= jb.K || m0 >= jb.M) return;
    int tx = threadIdx.x, ty = threadIdx.y;
#pragma unroll
    for (int i = 0; i < 32; i += 8) {
        int kk = k0 + ty + i, mm = m0 + tx;
        tile[ty + i][tx] = (kk < jb.K && mm < jb.M) ? jb.src[(size_t)kk * jb.M + mm] : 0.f;
    }
    __syncthreads();
#pragma unroll
    for (int i = 0; i < 32; i += 8) {
        int mm = m0 + ty + i, kk = k0 + tx;
        if (mm < jb.M && kk < jb.K)
            jb.dst[(size_t)mm * jb.K + kk] = (bf16)tile[tx][ty + i];
    }
}

__global__ __launch_bounds__(256) void k_dwt(const float* s0, const float* s1, const float* s2,
                                             float* d0, float* d1, float* d2)
{
    const float* s = blockIdx.x == 0 ? s0 : (blockIdx.x == 1 ? s1 : s2);
    float*       d = blockIdx.x == 0 ? d0 : (blockIdx.x == 1 ? d1 : d2);
    for (int i = threadIdx.x; i < 512 * 9; i += 256) {
        int c = i / 9, tap = i - c * 9;
        d[tap * 512 + c] = s[i];
    }
}

__global__ __launch_bounds__(256) void k_postab(float* __restrict__ yt, float* __restrict__ xt)
{
    int i = blockIdx.x * 256 + threadIdx.x;
    const float TWO_PI = 6.283185307179586f;
    const float KSC = -9.210340371976184f / 32.f;
    if (i < 96 * 64) {
        int h = i >> 6, c = i & 63;
        float p = (float)(h + 1) * (TWO_PI / (96.f + 1e-6f));
        float val = p * expf((float)(c >> 1) * KSC);
        yt[i] = (c & 1) ? cosf(val) : sinf(val);
    }
    if (i < 320 * 64) {
        int w = i >> 6, c = i & 63;
        float p = (float)(w + 1) * (TWO_PI / (320.f + 1e-6f));
        float val = p * expf((float)(c >> 1) * KSC);
        xt[i] = (c & 1) ? cosf(val) : sinf(val);
    }
}

// ---------------------------------------------------------------------------
// Transposes
// ---------------------------------------------------------------------------
__global__ __launch_bounds__(256) void k_chw2hwc(const float* __restrict__ in,
                                                 bf16* __restrict__ out)
{
    __shared__ float tile[32][33];
    const int Cc = 256;
    int s0 = blockIdx.x * 32;
    int c0 = blockIdx.y * 32;
    int b  = blockIdx.z;
    const float* ip = in  + (size_t)b * Cc * cNPIX;
    bf16*        op = out + (size_t)b * cNPIX * Cc;
    int tx = threadIdx.x, ty = threadIdx.y;
#pragma unroll
    for (int i = 0; i < 32; i += 8)
        tile[ty + i][tx] = ip[(size_t)(c0 + ty + i) * cNPIX + s0 + tx];
    __syncthreads();
#pragma unroll
    for (int i = 0; i < 32; i += 8)
        op[(size_t)(s0 + ty + i) * Cc + c0 + tx] = (bf16)tile[tx][ty + i];
}

__global__ __launch_bounds__(256) void k_hwc2chw(const float* __restrict__ in,
                                                 float* __restrict__ out)
{
    __shared__ float tile[32][33];
    int s0 = blockIdx.x * 32;
    int c0 = blockIdx.y * 32;
    int b  = blockIdx.z;
    const float* ip = in  + (size_t)b * cNPIX * cC;
    float*       op = out + (size_t)b * cC * cNPIX;
    int tx = threadIdx.x, ty = threadIdx.y;
#pragma unroll
    for (int i = 0; i < 32; i += 8)
        tile[ty + i][tx] = ip[(size_t)(s0 + ty + i) * cC + c0 + tx];
    __syncthreads();
#pragma unroll
    for (int i = 0; i < 32; i += 8)
        op[(size_t)(c0 + ty + i) * cNPIX + s0 + tx] = tile[tx][ty + i];
}

// ---------------------------------------------------------------------------
// Kernel 1: LN-fused GEMM, K=128, bf16 out. A- and W-tiles fully LDS-resident;
// zero barriers in the MFMA loop; LDS-staged coalesced epilogue.
// QKVS: -1 plain; 0/1 = QKV mode (cols 0..255 -> qkb stride 256,
//        cols 256..383 -> vt[win][ch][key] scatter, shift folded in).
// 1-D grid XCD-swizzled so the NS M-slices of a token tile share an XCD.
// ---------------------------------------------------------------------------
template<int QKVS>
__global__ __launch_bounds__(256) void k_gemm_ln(const float* __restrict__ F,
                                                 const float* __restrict__ gw,
                                                 const float* __restrict__ bw,
                                                 const bf16* __restrict__ Wt,
                                                 const float* __restrict__ bias,
                                                 bf16* __restrict__ outB, int M,
                                                 bf16* __restrict__ vtb)
{
    __shared__ bf16 As[128][136];
    __shared__ bf16 Bs[128][136];

    const int NS = M >> 7;
    const int l  = blockIdx.x;
    const int r8 = l % (8 * NS);
    const int qq = l / (8 * NS);
    const int bm = (qq * 8 + (r8 & 7)) * 128;   // token tile
    const int bn = (r8 >> 3) * 128;             // col tile

    const int t = threadIdx.x;
    const int lane = t & 63, wid = t >> 6;
    const int wm = (wid >> 1) * 64, wn = (wid & 1) * 64;
    const int lr = lane & 15, lg = lane >> 4;

    // ---- LN-fused A staging: 2 threads per row ----
    {
        const int row = t >> 1, hf = t & 1;
        const float* src = F + (size_t)(bm + row) * 128 + hf * 64;
        float4 v[16];
        float s = 0.f, sq = 0.f;
#pragma unroll
        for (int i = 0; i < 16; ++i) {
            v[i] = *(const float4*)(src + i * 4);
            s  += v[i].x + v[i].y + v[i].z + v[i].w;
            sq += v[i].x*v[i].x + v[i].y*v[i].y + v[i].z*v[i].z + v[i].w*v[i].w;
        }
        s  += __shfl_xor(s, 1);
        sq += __shfl_xor(sq, 1);
        const float mu = s * (1.f / 128.f);
        const float rs = rsqrtf(sq * (1.f / 128.f) - mu * mu + 1e-5f);
#pragma unroll
        for (int i = 0; i < 8; ++i) {
            float4 a  = v[2*i], b2 = v[2*i+1];
            float4 g0 = *(const float4*)(gw + hf*64 + i*8);
            float4 g1 = *(const float4*)(gw + hf*64 + i*8 + 4);
            float4 b0 = *(const float4*)(bw + hf*64 + i*8);
            float4 b1 = *(const float4*)(bw + hf*64 + i*8 + 4);
            bf16x8 o;
            o[0] = (bf16)((a.x  - mu) * rs * g0.x + b0.x);
            o[1] = (bf16)((a.y  - mu) * rs * g0.y + b0.y);
            o[2] = (bf16)((a.z  - mu) * rs * g0.z + b0.z);
            o[3] = (bf16)((a.w  - mu) * rs * g0.w + b0.w);
            o[4] = (bf16)((b2.x - mu) * rs * g1.x + b1.x);
            o[5] = (bf16)((b2.y - mu) * rs * g1.y + b1.y);
            o[6] = (bf16)((b2.z - mu) * rs * g1.z + b1.z);
            o[7] = (bf16)((b2.w - mu) * rs * g1.w + b1.w);
            *(bf16x8*)&As[row][hf*64 + i*8] = o;
        }
    }
    // ---- W staging (full 128x128 tile) ----
#pragma unroll
    for (int i = 0; i < 8; ++i) {
        int o = i * 256 + t;
        int col = o >> 4, kg = (o & 15) * 8;
        *(bf16x8*)&Bs[col][kg] = *(const bf16x8*)(Wt + (size_t)(bn + col) * 128 + kg);
    }
    __syncthreads();

    // ---- MFMA: 4 k-steps, no barriers ----
    const f32x4 zero4 = {0.f, 0.f, 0.f, 0.f};
    f32x4 acc[4][4];
#pragma unroll
    for (int i = 0; i < 4; ++i)
#pragma unroll
        for (int j = 0; j < 4; ++j) acc[i][j] = zero4;

    __builtin_amdgcn_s_setprio(1);
#pragma unroll
    for (int ks = 0; ks < 4; ++ks) {
        bf16x8 af[4], bf[4];
#pragma unroll
        for (int mf = 0; mf < 4; ++mf)
            af[mf] = *(const bf16x8*)&As[wm + mf*16 + lr][ks*32 + lg*8];
#pragma unroll
        for (int nf = 0; nf < 4; ++nf)
            bf[nf] = *(const bf16x8*)&Bs[wn + nf*16 + lr][ks*32 + lg*8];
#pragma unroll
        for (int mf = 0; mf < 4; ++mf)
#pragma unroll
            for (int nf = 0; nf < 4; ++nf)
                acc[mf][nf] = MFMA_BF16(af[mf], bf[nf], acc[mf][nf]);
    }
    __builtin_amdgcn_s_setprio(0);
    __syncthreads();

    // ---- epilogue: stage (reuse As), coalesced store ----
    const bool vpart = (QKVS >= 0) && (bn == 256);
    bf16 (*Ss)[136] = As;
#pragma unroll
    for (int nf = 0; nf < 4; ++nf) {
        int col = wn + nf * 16 + lr;
        float bv = (bias && !vpart) ? bias[bn + col] : 0.f;
#pragma unroll
        for (int mf = 0; mf < 4; ++mf) {
#pragma unroll
            for (int r = 0; r < 4; ++r) {
                int row = wm + mf * 16 + lg * 4 + r;
                float vv = acc[mf][nf][r] + bv;
                if (vpart) Ss[col][row] = (bf16)vv;   // transposed: [ch][tok]
                else       Ss[row][col] = (bf16)vv;
            }
        }
    }
    __syncthreads();

    if (!vpart) {
        const int ldo = (QKVS >= 0) ? 256 : M;
#pragma unroll
        for (int i = 0; i < 8; ++i) {
            int o = i * 256 + t;
            int row = o >> 4, cg = (o & 15) * 8;
            *(bf16x8*)(outB + (size_t)(bm + row) * ldo + bn + cg) = *(const bf16x8*)&Ss[row][cg];
        }
    } else {
        // V scatter: vt[((b*64+win)*128+ch)*480 + key], 2x bf16x4 per octet
        const int lr_ = t & 15, cg_ = t >> 4;
        const int gt = bm + lr_ * 8;
        const int b_ = gt / cNPIX, hw = gt % cNPIX;
        const int h = hw / cW, w = hw % cW;
        const int h0 = (QKVS == 1) ? ((h + 90) % 96) : h;
        const int nh = h0 / 12, kh = h0 - nh * 12;
#pragma unroll
        for (int i = 0; i < 8; ++i) {
            int ch = cg_ + 16 * i;
            bf16x8 e = *(const bf16x8*)&Ss[ch][lr_ * 8];
#pragma unroll
            for (int hi = 0; hi < 2; ++hi) {
                int wv = (QKVS == 1) ? ((w + hi * 4 + 300) % 320) : (w + hi * 4);
                int nw = wv / 40, kw = wv - nw * 40;
                bf16* dst = vtb + ((size_t)((b_ * 64 + nh * 8 + nw) * 128 + ch)) * 480 + kh * 40 + kw;
                bf16x4 hv;
#pragma unroll
                for (int j = 0; j < 4; ++j) hv[j] = e[hi * 4 + j];
                *(bf16x4*)dst = hv;
            }
        }
    }
}

// ---------------------------------------------------------------------------
// Kernel 2: LN-fused GEMM for outlook attn logits: K=128, M=81 (stride 84),
// fp32 out, two-pass staged float4 epilogue.
// ---------------------------------------------------------------------------
__global__ __launch_bounds__(256) void k_gemm_ln_wa(const float* __restrict__ F,
                                                    const float* __restrict__ gw,
                                                    const float* __restrict__ bw,
                                                    const bf16* __restrict__ Wt,
                                                    const float* __restrict__ bias,
                                                    float* __restrict__ outF)
{
    __shared__ bf16 As[128][136];
    __shared__ bf16 Bs[128][136];
    __shared__ float Sf[64][136];

    const int bm = blockIdx.x * 128;
    const int t = threadIdx.x;
    const int lane = t & 63, wid = t >> 6;
    const int wm = (wid >> 1) * 64, wn = (wid & 1) * 64;
    const int lr = lane & 15, lg = lane >> 4;

    {
        const int row = t >> 1, hf = t & 1;
        const float* src = F + (size_t)(bm + row) * 128 + hf * 64;
        float4 v[16];
        float s = 0.f, sq = 0.f;
#pragma unroll
        for (int i = 0; i < 16; ++i) {
            v[i] = *(const float4*)(src + i * 4);
            s  += v[i].x + v[i].y + v[i].z + v[i].w;
            sq += v[i].x*v[i].x + v[i].y*v[i].y + v[i].z*v[i].z + v[i].w*v[i].w;
        }
        s  += __shfl_xor(s, 1);
        sq += __shfl_xor(sq, 1);
        const float mu = s * (1.f / 128.f);
        const float rs = rsqrtf(sq * (1.f / 128.f) - mu * mu + 1e-5f);
#pragma unroll
        for (int i = 0; i < 8; ++i) {
            float4 a  = v[2*i], b2 = v[2*i+1];
            float4 g0 = *(const float4*)(gw + hf*64 + i*8);
            float4 g1 = *(const float4*)(gw + hf*64 + i*8 + 4);
            float4 b0 = *(const float4*)(bw + hf*64 + i*8);
            float4 b1 = *(const float4*)(bw + hf*64 + i*8 + 4);
            bf16x8 o;
            o[0] = (bf16)((a.x  - mu) * rs * g0.x + b0.x);
            o[1] = (bf16)((a.y  - mu) * rs * g0.y + b0.y);
            o[2] = (bf16)((a.z  - mu) * rs * g0.z + b0.z);
            o[3] = (bf16)((a.w  - mu) * rs * g0.w + b0.w);
            o[4] = (bf16)((b2.x - mu) * rs * g1.x + b1.x);
            o[5] = (bf16)((b2.y - mu) * rs * g1.y + b1.y);
            o[6] = (bf16)((b2.z - mu) * rs * g1.z + b1.z);
            o[7] = (bf16)((b2.w - mu) * rs * g1.w + b1.w);
            *(bf16x8*)&As[row][hf*64 + i*8] = o;
        }
    }
    bf16x8 zrow;
#pragma unroll
    for (int j = 0; j < 8; ++j) zrow[j] = (bf16)0.f;
#pragma unroll
    for (int i = 0; i < 8; ++i) {
        int o = i * 256 + t;
        int col = o >> 4, kg = (o & 15) * 8;
        *(bf16x8*)&Bs[col][kg] = (col < 81) ? *(const bf16x8*)(Wt + (size_t)col * 128 + kg) : zrow;
    }
    __syncthreads();

    const f32x4 zero4 = {0.f, 0.f, 0.f, 0.f};
    f32x4 acc[4][4];
#pragma unroll
    for (int i = 0; i < 4; ++i)
#pragma unroll
        for (int j = 0; j < 4; ++j) acc[i][j] = zero4;

    __builtin_amdgcn_s_setprio(1);
#pragma unroll
    for (int ks = 0; ks < 4; ++ks) {
        bf16x8 af[4], bf[4];
#pragma unroll
        for (int mf = 0; mf < 4; ++mf)
            af[mf] = *(const bf16x8*)&As[wm + mf*16 + lr][ks*32 + lg*8];
#pragma unroll
        for (int nf = 0; nf < 4; ++nf)
            bf[nf] = *(const bf16x8*)&Bs[wn + nf*16 + lr][ks*32 + lg*8];
#pragma unroll
        for (int mf = 0; mf < 4; ++mf)
#pragma unroll
            for (int nf = 0; nf < 4; ++nf)
                acc[mf][nf] = MFMA_BF16(af[mf], bf[nf], acc[mf][nf]);
    }
    __builtin_amdgcn_s_setprio(0);

    for (int half = 0; half < 2; ++half) {
        __syncthreads();
        if ((wid >> 1) == half) {
#pragma unroll
            for (int nf = 0; nf < 4; ++nf) {
                int col = wn + nf * 16 + lr;
                float bv = (col < 81) ? bias[col] : 0.f;
#pragma unroll
                for (int mf = 0; mf < 4; ++mf)
#pragma unroll
                    for (int r = 0; r < 4; ++r)
                        Sf[mf * 16 + lg * 4 + r][col] = acc[mf][nf][r] + bv;
            }
        }
        __syncthreads();
#pragma unroll
        for (int i = 0; i < 6; ++i) {
            int o = i * 256 + t;
            if (o < 64 * 21) {
                int row = o / 21, cq = (o - row * 21) * 4;
                *(float4*)(outF + (size_t)(bm + half * 64 + row) * cAS + cq) = *(const float4*)&Sf[row][cq];
            }
        }
    }
}

// ---------------------------------------------------------------------------
// Kernel 3: generic k-loop GEMM, M=128, A bf16. Staged coalesced epilogue:
// OUTBF -> bf16[tok][128]; else fp32 = acc + bias [+pos] [+res] (float4).
// ---------------------------------------------------------------------------
template<bool OUTBF, bool RELU, bool RES, bool POS>
__global__ __launch_bounds__(256) void k_gemm_res(const bf16* __restrict__ A,
                                                  const bf16* __restrict__ Wt,
                                                  const float* __restrict__ bias,
                                                  const float* __restrict__ res,
                                                  float* __restrict__ outF,
                                                  bf16* __restrict__ outB,
                                                  int K,
                                                  const float* __restrict__ ytab,
                                                  const float* __restrict__ xtab)
{
    __shared__ bf16 As[128][40];
    __shared__ bf16 Bs[128][40];
    __shared__ float Sf[64][136];           // aliased as bf16[128][136] for OUTBF

    const int bm = blockIdx.x * 128;
    const int t = threadIdx.x;
    const int lane = t & 63, wid = t >> 6;
    const int wm = (wid >> 1) * 64, wn = (wid & 1) * 64;
    const int lr = lane & 15, lg = lane >> 4;

    const f32x4 zero4 = {0.f, 0.f, 0.f, 0.f};
    f32x4 acc[4][4];
#pragma unroll
    for (int i = 0; i < 4; ++i)
#pragma unroll
        for (int j = 0; j < 4; ++j) acc[i][j] = zero4;

    for (int k0 = 0; k0 < K; k0 += 32) {
#pragma unroll
        for (int i = 0; i < 2; ++i) {
            int idx = t + i * 256;
            int row = idx >> 2, kg = (idx & 3) * 8;
            *(bf16x8*)&As[row][kg] = *(const bf16x8*)(A + (size_t)(bm + row) * K + k0 + kg);
            *(bf16x8*)&Bs[row][kg] = *(const bf16x8*)(Wt + (size_t)row * K + k0 + kg);
        }
        __syncthreads();
        bf16x8 af[4], bf[4];
#pragma unroll
        for (int mf = 0; mf < 4; ++mf)
            af[mf] = *(const bf16x8*)&As[wm + mf*16 + lr][lg * 8];
#pragma unroll
        for (int nf = 0; nf < 4; ++nf)
            bf[nf] = *(const bf16x8*)&Bs[wn + nf*16 + lr][lg * 8];
        __builtin_amdgcn_s_setprio(1);
#pragma unroll
        for (int mf = 0; mf < 4; ++mf)
#pragma unroll
            for (int nf = 0; nf < 4; ++nf)
                acc[mf][nf] = MFMA_BF16(af[mf], bf[nf], acc[mf][nf]);
        __builtin_amdgcn_s_setprio(0);
        __syncthreads();
    }

    if (OUTBF) {
        bf16 (*Sb)[136] = (bf16(*)[136])Sf;
#pragma unroll
        for (int nf = 0; nf < 4; ++nf) {
            int col = wn + nf * 16 + lr;
            float bv = bias ? bias[col] : 0.f;
#pragma unroll
            for (int mf = 0; mf < 4; ++mf)
#pragma unroll
                for (int r = 0; r < 4; ++r) {
                    float vv = acc[mf][nf][r] + bv;
                    if (RELU) vv = fmaxf(vv, 0.f);
                    Sb[wm + mf * 16 + lg * 4 + r][col] = (bf16)vv;
                }
        }
        __syncthreads();
#pragma unroll
        for (int i = 0; i < 8; ++i) {
            int o = i * 256 + t;
            int row = o >> 4, cg = (o & 15) * 8;
            *(bf16x8*)(outB + (size_t)(bm + row) * 128 + cg) = *(const bf16x8*)&Sb[row][cg];
        }
    } else {
        for (int half = 0; half < 2; ++half) {
            __syncthreads();
            if ((wid >> 1) == half) {
#pragma unroll
                for (int nf = 0; nf < 4; ++nf) {
                    int col = wn + nf * 16 + lr;
                    float bv = bias ? bias[col] : 0.f;
#pragma unroll
                    for (int mf = 0; mf < 4; ++mf)
#pragma unroll
                        for (int r = 0; r < 4; ++r)
                            Sf[mf * 16 + lg * 4 + r][col] = acc[mf][nf][r] + bv;
                }
            }
            __syncthreads();
#pragma unroll
            for (int i = 0; i < 8; ++i) {
                int o = i * 256 + t;
                int row = o >> 5, cq = (o & 31) * 4;
                int grow = bm + half * 64 + row;
                float4 v = *(const float4*)&Sf[row][cq];
                if (POS) {
                    int hw = grow % cNPIX;
                    int h = hw / cW, w = hw - (hw / cW) * cW;
                    float4 p = (cq < 64) ? *(const float4*)(ytab + (h << 6) + cq)
                                         : *(const float4*)(xtab + (w << 6) + cq - 64);
                    v.x += p.x; v.y += p.y; v.z += p.z; v.w += p.w;
                }
                if (RES) {
                    float4 rr = *(const float4*)(res + (size_t)grow * 128 + cq);
                    v.x += rr.x; v.y += rr.y; v.z += rr.z; v.w += rr.w;
                }
                *(float4*)(outF + (size_t)grow * 128 + cq) = v;
            }
        }
    }
}

// ---------------------------------------------------------------------------
// Outlook fused gather (stats folded in; attn stride 84).
// ---------------------------------------------------------------------------
__global__ __launch_bounds__(256) void k_olk_gather(const bf16* __restrict__ v,
                                                    const float* __restrict__ attn,
                                                    bf16* __restrict__ y)
{
    __shared__ float pr[16][84];
    __shared__ float coef[16][26];

    const int t  = threadIdx.x;
    const int px = t >> 4;
    const int j  = t & 15;
    const int pix = blockIdx.x * 16 + px;
    const int b  = pix / cNPIX;
    const int hw = pix % cNPIX;
    const int h = hw / cW, w = hw % cW;

    if (j < 9) {
        const int p  = j;
        const int pi = p / 3, pj = p - pi * 3;
        const int hh = h + 1 - pi, ww = w + 1 - pj;
        float prv[9];
        if ((unsigned)hh < (unsigned)cH && (unsigned)ww < (unsigned)cW) {
            const size_t row = (size_t)(b * cNPIX + hh * cW + ww);
            const float* arow = attn + row * cAS + p * 9;
            float lg[9];
            float m = 0.f;
#pragma unroll
            for (int q = 0; q < 9; ++q) { lg[q] = arow[q]; m = fmaxf(m, lg[q]); }
            float se = 0.f;
#pragma unroll
            for (int q = 0; q < 9; ++q) { prv[q] = __expf(lg[q] - m); se += prv[q]; }
            float inv = 1.f / (se + __expf(-m));
#pragma unroll
            for (int q = 0; q < 9; ++q) prv[q] *= inv;
        } else {
#pragma unroll
            for (int q = 0; q < 9; ++q) prv[q] = 0.f;
        }
#pragma unroll
        for (int q = 0; q < 9; ++q) pr[px][p * 9 + q] = prv[q];
    }
    __syncthreads();

    for (int d = j; d < 25; d += 16) {
        const int a  = d / 5, bb = d - a * 5;
        float s = 0.f;
#pragma unroll
        for (int pi = 0; pi < 3; ++pi) {
            const int qi = pi + a - 2;
            if ((unsigned)qi >= 3u) continue;
#pragma unroll
            for (int pj = 0; pj < 3; ++pj) {
                const int qj = pj + bb - 2;
                if ((unsigned)qj >= 3u) continue;
                s += pr[px][(pi * 3 + pj) * 9 + qi * 3 + qj];
            }
        }
        coef[px][d] = s;
    }
    __syncthreads();

    float acc[8] = {};
    const size_t bbase = (size_t)b * cNPIX;
#pragma unroll
    for (int a = 0; a < 5; ++a) {
        const int sh = h + a - 2;
        if ((unsigned)sh >= (unsigned)cH) continue;
#pragma unroll
        for (int bb = 0; bb < 5; ++bb) {
            const int sw = w + bb - 2;
            if ((unsigned)sw >= (unsigned)cW) continue;
            const float cf = coef[px][a * 5 + bb];
            const bf16x8 v8 = *(const bf16x8*)(v + ((bbase + (size_t)sh * cW + sw) * 128 + j * 8));
#pragma unroll
            for (int e = 0; e < 8; ++e) acc[e] = fmaf(cf, (float)v8[e], acc[e]);
        }
    }
    bf16x8 o8;
#pragma unroll
    for (int e = 0; e < 8; ++e) o8[e] = (bf16)acc[e];
    *(bf16x8*)(y + (size_t)pix * 128 + j * 8) = o8;
}

// ---------------------------------------------------------------------------
// Depthwise 3x3 + bias + exact GELU, row-sliding, NHWC 512 ch.
// ---------------------------------------------------------------------------
__global__ __launch_bounds__(256) void k_dwconv_gelu(const bf16* __restrict__ h1,
                                                     const float* __restrict__ dwt,
                                                     const float* __restrict__ bdw,
                                                     bf16* __restrict__ h2)
{
    const int t   = threadIdx.x;
    const int c2  = t * 2;
    const int blk = blockIdx.x;
    const int row = blk >> 3;
    const int seg = blk & 7;
    const int bb  = row / cH, h = row % cH;
    const int w0  = seg * 40;

    float2 wgt[9];
#pragma unroll
    for (int k = 0; k < 9; ++k)
        wgt[k] = *(const float2*)(dwt + k * 512 + c2);
    const float2 bias = *(const float2*)(bdw + c2);

    const size_t base = (size_t)bb * cNPIX;

    auto ld = [&](int hh, int ww) -> float2 {
        float2 r; r.x = 0.f; r.y = 0.f;
        if ((unsigned)hh < (unsigned)cH && (unsigned)ww < (unsigned)cW) {
            unsigned u = *(const unsigned*)(h1 + ((base + (size_t)hh * cW + ww) * 512 + c2));
            r.x = __uint_as_float(u << 16);
            r.y = __uint_as_float(u & 0xffff0000u);
        }
        return r;
    };

    float2 cm[3], c0[3], cp[3];
#pragma unroll
    for (int r = 0; r < 3; ++r) {
        cm[r] = ld(h + r - 1, w0 - 1);
        c0[r] = ld(h + r - 1, w0);
    }

    for (int j = 0; j < 40; ++j) {
#pragma unroll
        for (int r = 0; r < 3; ++r) cp[r] = ld(h + r - 1, w0 + j + 1);
        float a0 = bias.x, a1 = bias.y;
#pragma unroll
        for (int r = 0; r < 3; ++r) {
            a0 = fmaf(cm[r].x, wgt[r * 3 + 0].x, a0);
            a1 = fmaf(cm[r].y, wgt[r * 3 + 0].y, a1);
            a0 = fmaf(c0[r].x, wgt[r * 3 + 1].x, a0);
            a1 = fmaf(c0[r].y, wgt[r * 3 + 1].y, a1);
            a0 = fmaf(cp[r].x, wgt[r * 3 + 2].x, a0);
            a1 = fmaf(cp[r].y, wgt[r * 3 + 2].y, a1);
        }
        a0 = 0.5f * a0 * (1.f + erff(a0 * 0.70710678118654752f));
        a1 = 0.5f * a1 * (1.f + erff(a1 * 0.70710678118654752f));
        union { bf16 hh[2]; unsigned int u; } o2;
        o2.hh[0] = (bf16)a0;
        o2.hh[1] = (bf16)a1;
        *(unsigned int*)(h2 + (base + (size_t)h * cW + w0 + j) * 512 + c2) = o2.u;
#pragma unroll
        for (int r = 0; r < 3; ++r) { cm[r] = c0[r]; c0[r] = cp[r]; }
    }
}

// ---------------------------------------------------------------------------
// Window attention, MFMA flash-style (unchanged from R5).
// ---------------------------------------------------------------------------
template<bool SHIFT>
__global__ __launch_bounds__(256) void k_win_attn(const bf16* __restrict__ qk,
                                                  const bf16* __restrict__ vt,
                                                  bf16* __restrict__ out)
{
    __shared__ bf16 Ks[2][32][136];
    __shared__ bf16 Vs[2][128][40];
    __shared__ bf16 Ps[4][16][40];

    const int t = threadIdx.x, lane = t & 63, wid = t >> 6;
    const int lr = lane & 15, lg = lane >> 4;
    const int wb = blockIdx.x;
    const int b  = wb >> 6, win = wb & 63;
    const int nh = win >> 3, nw = win & 7;
    const int qbase = blockIdx.y * 64 + wid * 16;

    const float SCALE   = 0.088388347648318447f;
    const float MASKRAW = 100.f / 0.088388347648318447f;

    auto tokOf = [&](int p) {
        int ph = nh * 12 + p / 40;
        int pw = nw * 40 + (p % 40);
        if (SHIFT) {
            ph += 6;  if (ph >= cH) ph -= cH;
            pw += 20; if (pw >= cW) pw -= cW;
        }
        return b * cNPIX + ph * cW + pw;
    };
    auto labOf = [&](int p) {
        int ph = nh * 12 + p / 40;
        int pw = nw * 40 + (p % 40);
        int rh = ph < 84 ? 0 : (ph < 90 ? 1 : 2);
        int rc = pw < 280 ? 0 : (pw < 300 ? 1 : 2);
        return rh * 3 + rc;
    };

    int qp = min(qbase + lr, 479);
    const bf16* qptr = qk + (size_t)tokOf(qp) * 256;
    bf16x8 qf[4];
#pragma unroll
    for (int c = 0; c < 4; ++c)
        qf[c] = *(const bf16x8*)(qptr + c * 32 + lg * 8);

    int labq[4];
    if (SHIFT) {
#pragma unroll
        for (int r = 0; r < 4; ++r) labq[r] = labOf(min(qbase + lg * 4 + r, 479));
    }

    const bf16* vbase = vt + (size_t)wb * 128 * 480;
    auto loadK = [&](int kt, int i) {
        int idx = t + i * 256;
        int key = idx >> 4, cg = (idx & 15) * 8;
        return *(const bf16x8*)(qk + (size_t)tokOf(kt * 32 + key) * 256 + 128 + cg);
    };
    auto loadV = [&](int kt, int i) {
        int idx = t + i * 256;
        int ch = idx >> 2, kq = (idx & 3) * 8;
        return *(const bf16x8*)(vbase + (size_t)ch * 480 + kt * 32 + kq);
    };

    bf16x8 kreg0 = loadK(0, 0), kreg1 = loadK(0, 1);
    bf16x8 vreg0 = loadV(0, 0), vreg1 = loadV(0, 1);

    const f32x4 zero4 = {0.f, 0.f, 0.f, 0.f};
    float m_run[4] = {0.f, 0.f, 0.f, 0.f};
    float mguard = 8.f;
    f32x4 l4 = zero4;
    f32x4 o[8];
#pragma unroll
    for (int nf = 0; nf < 8; ++nf) o[nf] = zero4;

    bf16x8 ones8;
#pragma unroll
    for (int j = 0; j < 8; ++j) ones8[j] = (bf16)1.f;

    int buf = 0;
    for (int kt = 0; kt < 15; ++kt) {
        {
            int i0 = t, i1 = t + 256;
            *(bf16x8*)&Ks[buf][i0 >> 4][(i0 & 15) * 8] = kreg0;
            *(bf16x8*)&Ks[buf][i1 >> 4][(i1 & 15) * 8] = kreg1;
            *(bf16x8*)&Vs[buf][i0 >> 2][(i0 & 3) * 8] = vreg0;
            *(bf16x8*)&Vs[buf][i1 >> 2][(i1 & 3) * 8] = vreg1;
        }
        if (kt + 1 < 15) {
            kreg0 = loadK(kt + 1, 0); kreg1 = loadK(kt + 1, 1);
            vreg0 = loadV(kt + 1, 0); vreg1 = loadV(kt + 1, 1);
        }
        __syncthreads();

        f32x4 s0 = zero4, s1 = zero4;
        __builtin_amdgcn_s_setprio(1);
#pragma unroll
        for (int c = 0; c < 4; ++c) {
            bf16x8 kf0 = *(const bf16x8*)&Ks[buf][lr][c * 32 + lg * 8];
            bf16x8 kf1 = *(const bf16x8*)&Ks[buf][16 + lr][c * 32 + lg * 8];
            s0 = MFMA_BF16(qf[c], kf0, s0);
            s1 = MFMA_BF16(qf[c], kf1, s1);
        }
        __builtin_amdgcn_s_setprio(0);

        if (SHIFT) {
            int lab0 = labOf(kt * 32 + lr);
            int lab1 = labOf(kt * 32 + 16 + lr);
#pragma unroll
            for (int r = 0; r < 4; ++r) {
                if (labq[r] != lab0) s0[r] -= MASKRAW;
                if (labq[r] != lab1) s1[r] -= MASKRAW;
            }
        }

        float tm = fmaxf(fmaxf(fmaxf(s0[0], s0[1]), fmaxf(s0[2], s0[3])),
                         fmaxf(fmaxf(s1[0], s1[1]), fmaxf(s1[2], s1[3])));
#pragma unroll
        for (int off = 1; off < 16; off <<= 1) tm = fmaxf(tm, __shfl_xor(tm, off));
        if (tm * SCALE > mguard) {
#pragma unroll
            for (int r = 0; r < 4; ++r) {
                float mx = fmaxf(s0[r], s1[r]);
#pragma unroll
                for (int off = 1; off < 16; off <<= 1) mx = fmaxf(mx, __shfl_xor(mx, off));
                float nm = fmaxf(m_run[r], mx * SCALE);
                float sc = __expf(m_run[r] - nm);
#pragma unroll
                for (int nf = 0; nf < 8; ++nf) o[nf][r] *= sc;
                l4[r] *= sc;
                m_run[r] = nm;
            }
            mguard = fminf(fminf(m_run[0], m_run[1]), fminf(m_run[2], m_run[3])) + 8.f;
        }

#pragma unroll
        for (int r = 0; r < 4; ++r) {
            float p0 = __expf(fmaf(s0[r], SCALE, -m_run[r]));
            float p1 = __expf(fmaf(s1[r], SCALE, -m_run[r]));
            Ps[wid][lg * 4 + r][lr]      = (bf16)p0;
            Ps[wid][lg * 4 + r][16 + lr] = (bf16)p1;
        }

        bf16x8 pa = *(const bf16x8*)&Ps[wid][lr][lg * 8];
        __builtin_amdgcn_s_setprio(1);
        l4 = MFMA_BF16(pa, ones8, l4);
#pragma unroll
        for (int nf = 0; nf < 8; ++nf) {
            bf16x8 bv = *(const bf16x8*)&Vs[buf][nf * 16 + lr][lg * 8];
            o[nf] = MFMA_BF16(pa, bv, o[nf]);
        }
        __builtin_amdgcn_s_setprio(0);
        __syncthreads();
        buf ^= 1;
    }

#pragma unroll
    for (int r = 0; r < 4; ++r) {
        int qrow = qbase + lg * 4 + r;
        if (qrow >= 480) continue;
        float inv = 1.f / (l4[r] + __expf(-m_run[r]));
        size_t ooff = (size_t)tokOf(qrow) * 128;
#pragma unroll
        for (int nf = 0; nf < 8; ++nf)
            out[ooff + nf * 16 + lr] = (bf16)(o[nf][r] * inv);
    }
}

// ---------------------------------------------------------------------------
// Host launcher
// ---------------------------------------------------------------------------
extern "C" void kernel_launch(void* const* d_in, const int* in_sizes, int n_in,
                              void* d_out, int out_size, void* d_ws, size_t ws_size,
                              hipStream_t stream)
{
    (void)in_sizes; (void)n_in; (void)out_size; (void)ws_size;

    const float* X = (const float*)d_in[0];

    char* ws = (char*)d_ws;
    float* f    = (float*)ws;                                 ws += (size_t)cNTOK * 128 * 4;
    ws += (size_t)cNTOK * 128 * 2;  // (spare, was xnb)
    bf16*  bufA = (bf16*)ws;                                  ws += (size_t)cNTOK * 512 * 2;
    bf16*  bufB = (bf16*)ws;                                  ws += (size_t)cNTOK * 512 * 2;
    bf16*  wts  = (bf16*)ws;

    size_t wo_off = 0;
    auto nextw = [&](int K, int M) { bf16* p = wts + wo_off; wo_off += (size_t)K * M; return p; };
    bf16* agg_w1t = nextw(256, 128);
    bf16* agg_w2t = nextw(128, 128);
    bf16* ol_wvt  = nextw(128, 128);
    bf16* ol_wat  = nextw(128, 81);
    bf16* ol_wot  = nextw(128, 128);
    bf16* f1_w1t  = nextw(128, 512);
    bf16* f1_w2t  = nextw(512, 128);
    bf16* w_qkvt  = nextw(128, 384);
    bf16* w_wot   = nextw(128, 128);
    bf16* f2_w1t  = nextw(128, 512);
    bf16* f2_w2t  = nextw(512, 128);
    bf16* s_qkvt  = nextw(128, 384);
    bf16* s_wot   = nextw(128, 128);
    bf16* f3_w1t  = nextw(128, 512);
    bf16* f3_w2t  = nextw(512, 128);
    float* dwt1 = (float*)(wts + wo_off);
    float* dwt2 = dwt1 + 512 * 9;
    float* dwt3 = dwt2 + 512 * 9;
    float* ytab = dwt3 + 512 * 9;
    float* xtab = ytab + 96 * 64;

    WJobs jobs;
    int ji = 0;
    auto addj = [&](int src_idx, bf16* dst, int K, int M) {
        jobs.j[ji++] = WJob{(const float*)d_in[src_idx], dst, K, M};
    };
    addj(1,  agg_w1t, 256, 128);
    addj(3,  agg_w2t, 128, 128);
    addj(7,  ol_wvt,  128, 128);
    addj(8,  ol_wat,  128, 81);
    addj(10, ol_wot,  128, 128);
    addj(14, f1_w1t,  128, 512);
    addj(18, f1_w2t,  512, 128);
    addj(22, w_qkvt,           128, 128);
    addj(23, w_qkvt + 128*128, 128, 128);
    addj(24, w_qkvt + 256*128, 128, 128);
    addj(25, w_wot,   128, 128);
    addj(29, f2_w1t,  128, 512);
    addj(33, f2_w2t,  512, 128);
    addj(37, s_qkvt,           128, 128);
    addj(38, s_qkvt + 128*128, 128, 128);
    addj(39, s_qkvt + 256*128, 128, 128);
    addj(40, s_wot,   128, 128);
    addj(44, f3_w1t,  128, 512);
    addj(48, f3_w2t,  512, 128);
    k_wt<<<dim3(16, 16, 19), dim3(32, 8), 0, stream>>>(jobs);
    k_dwt<<<3, 256, 0, stream>>>((const float*)d_in[16], (const float*)d_in[31],
                                 (const float*)d_in[46], dwt1, dwt2, dwt3);
    k_postab<<<80, 256, 0, stream>>>(ytab, xtab);

    const int nTT = cNTOK / 128;   // 480 token tiles

    // ---- input transpose + aggregation MLP ----
    k_chw2hwc<<<dim3(cNPIX / 32, 256 / 32, cB), dim3(32, 8), 0, stream>>>(X, bufA);
    k_gemm_res<true, true, false, false><<<nTT, 256, 0, stream>>>(
        bufA, agg_w1t, (const float*)d_in[2], nullptr, nullptr, bufB, 256, nullptr, nullptr);
    k_gemm_res<false, false, false, false><<<nTT, 256, 0, stream>>>(
        bufB, agg_w2t, (const float*)d_in[4], nullptr, f, nullptr, 128, nullptr, nullptr);

    // ---- outlook attention ----
    {
        bf16*  vb   = bufA;
        bf16*  gout = bufA + (size_t)cNTOK * 128;
        float* atn  = (float*)bufB;
        k_gemm_ln<-1><<<nTT, 256, 0, stream>>>(
            f, (const float*)d_in[5], (const float*)d_in[6], ol_wvt, nullptr, vb, 128, nullptr);
        k_gemm_ln_wa<<<nTT, 256, 0, stream>>>(
            f, (const float*)d_in[5], (const float*)d_in[6], ol_wat, (const float*)d_in[9], atn);
        k_olk_gather<<<cNTOK / 16, 256, 0, stream>>>(vb, atn, gout);
        k_gemm_res<false, false, true, false><<<nTT, 256, 0, stream>>>(
            gout, ol_wot, (const float*)d_in[11], f, f, nullptr, 128, nullptr, nullptr);
    }

    // ---- conv FFN ----
    auto run_ffn = [&](int base, bf16* w1t, bf16* w2t, float* dwt, bool pos) {
        k_gemm_ln<-1><<<nTT * 4, 256, 0, stream>>>(
            f, (const float*)d_in[base], (const float*)d_in[base + 1], w1t,
            (const float*)d_in[base + 3], bufA, 512, nullptr);
        k_dwconv_gelu<<<cB * cH * 8, 256, 0, stream>>>(
            bufA, dwt, (const float*)d_in[base + 5], bufB);
        if (pos)
            k_gemm_res<false, false, true, true><<<nTT, 256, 0, stream>>>(
                bufB, w2t, (const float*)d_in[base + 7], f, f, nullptr, 512, ytab, xtab);
        else
            k_gemm_res<false, false, true, false><<<nTT, 256, 0, stream>>>(
                bufB, w2t, (const float*)d_in[base + 7], f, f, nullptr, 512, nullptr, nullptr);
    };

    // ---- window attention ----
    auto run_win = [&](int base, bf16* qkvt, bf16* wot, bool shift) {
        bf16* qkb = bufA;
        bf16* vtb = bufA + (size_t)cNTOK * 256;
        bf16* ao  = bufB;
        if (shift)
            k_gemm_ln<1><<<nTT * 3, 256, 0, stream>>>(
                f, (const float*)d_in[base], (const float*)d_in[base + 1], qkvt, nullptr, qkb, 384, vtb);
        else
            k_gemm_ln<0><<<nTT * 3, 256, 0, stream>>>(
                f, (const float*)d_in[base], (const float*)d_in[base + 1], qkvt, nullptr, qkb, 384, vtb);
        if (shift) k_win_attn<true ><<<dim3(128, 8), 256, 0, stream>>>(qkb, vtb, ao);
        else       k_win_attn<false><<<dim3(128, 8), 256, 0, stream>>>(qkb, vtb, ao);
        k_gemm_res<false, false, true, false><<<nTT, 256, 0, stream>>>(
            ao, wot, (const float*)d_in[base + 6], f, f, nullptr, 128, nullptr, nullptr);
    };

    run_ffn(12, f1_w1t, f1_w2t, dwt1, true);                   // f1 (+pos fused)
    run_win(20, w_qkvt, w_wot, false);                         // w
    run_ffn(27, f2_w1t, f2_w2t, dwt2, false);                  // f2
    run_win(35, s_qkvt, s_wot, true);                          // s (shifted)
    run_ffn(42, f3_w1t, f3_w2t, dwt3, false);                  // f3

    k_hwc2chw<<<dim3(cNPIX / 32, cC / 32, cB), dim3(32, 8), 0, stream>>>(f, (float*)d_out);
}

// Round 7
// 743.440 us; speedup vs baseline: 5.2436x; 1.0393x over previous
//
#include <hip/hip_runtime.h>

typedef __bf16 bf16;
typedef __bf16 bf16x8 __attribute__((ext_vector_type(8)));
typedef __bf16 bf16x4 __attribute__((ext_vector_type(4)));
typedef float  f32x4  __attribute__((ext_vector_type(4)));

#define MFMA_BF16(a, b, c) __builtin_amdgcn_mfma_f32_16x16x32_bf16(a, b, c, 0, 0, 0)

constexpr int cB    = 2;
constexpr int cH    = 96;
constexpr int cW    = 320;
constexpr int cC    = 128;
constexpr int cNPIX = cH * cW;          // 30720
constexpr int cNTOK = cB * cNPIX;       // 61440
constexpr int cAS   = 84;               // padded attn-logit stride (81 -> 84)

// ---------------------------------------------------------------------------
// Weight transpose+convert: fp32 W (K x M) -> bf16 Wt (M x K)
// ---------------------------------------------------------------------------
struct WJob  { const float* src; bf16* dst; int K; int M; };
struct WJobs { WJob j[19]; };

__global__ __launch_bounds__(256) void k_wt(WJobs jobs)
{
    __shared__ float tile[32][33];
    const WJob jb = jobs.j[blockIdx.z];
    int k0 = blockIdx.y * 32, m0 = blockIdx.x * 32;
    if (k0 >= jb.K || m0 >= jb.M) return;
    int tx = threadIdx.x, ty = threadIdx.y;
#pragma unroll
    for (int i = 0; i < 32; i += 8) {
        int kk = k0 + ty + i, mm = m0 + tx;
        tile[ty + i][tx] = (kk < jb.K && mm < jb.M) ? jb.src[(size_t)kk * jb.M + mm] : 0.f;
    }
    __syncthreads();
#pragma unroll
    for (int i = 0; i < 32; i += 8) {
        int mm = m0 + ty + i, kk = k0 + tx;
        if (mm < jb.M && kk < jb.K)
            jb.dst[(size_t)mm * jb.K + kk] = (bf16)tile[tx][ty + i];
    }
}

__global__ __launch_bounds__(256) void k_dwt(const float* s0, const float* s1, const float* s2,
                                             float* d0, float* d1, float* d2)
{
    const float* s = blockIdx.x == 0 ? s0 : (blockIdx.x == 1 ? s1 : s2);
    float*       d = blockIdx.x == 0 ? d0 : (blockIdx.x == 1 ? d1 : d2);
    for (int i = threadIdx.x; i < 512 * 9; i += 256) {
        int c = i / 9, tap = i - c * 9;
        d[tap * 512 + c] = s[i];
    }
}

__global__ __launch_bounds__(256) void k_postab(float* __restrict__ yt, float* __restrict__ xt)
{
    int i = blockIdx.x * 256 + threadIdx.x;
    const float TWO_PI = 6.283185307179586f;
    const float KSC = -9.210340371976184f / 32.f;
    if (i < 96 * 64) {
        int h = i >> 6, c = i & 63;
        float p = (float)(h + 1) * (TWO_PI / (96.f + 1e-6f));
        float val = p * expf((float)(c >> 1) * KSC);
        yt[i] = (c & 1) ? cosf(val) : sinf(val);
    }
    if (i < 320 * 64) {
        int w = i >> 6, c = i & 63;
        float p = (float)(w + 1) * (TWO_PI / (320.f + 1e-6f));
        float val = p * expf((float)(c >> 1) * KSC);
        xt[i] = (c & 1) ? cosf(val) : sinf(val);
    }
}

// ---------------------------------------------------------------------------
// Transposes
// ---------------------------------------------------------------------------
__global__ __launch_bounds__(256) void k_chw2hwc(const float* __restrict__ in,
                                                 bf16* __restrict__ out)
{
    __shared__ float tile[32][33];
    const int Cc = 256;
    int s0 = blockIdx.x * 32;
    int c0 = blockIdx.y * 32;
    int b  = blockIdx.z;
    const float* ip = in  + (size_t)b * Cc * cNPIX;
    bf16*        op = out + (size_t)b * cNPIX * Cc;
    int tx = threadIdx.x, ty = threadIdx.y;
#pragma unroll
    for (int i = 0; i < 32; i += 8)
        tile[ty + i][tx] = ip[(size_t)(c0 + ty + i) * cNPIX + s0 + tx];
    __syncthreads();
#pragma unroll
    for (int i = 0; i < 32; i += 8)
        op[(size_t)(s0 + ty + i) * Cc + c0 + tx] = (bf16)tile[tx][ty + i];
}

__global__ __launch_bounds__(256) void k_hwc2chw(const float* __restrict__ in,
                                                 float* __restrict__ out)
{
    __shared__ float tile[32][33];
    int s0 = blockIdx.x * 32;
    int c0 = blockIdx.y * 32;
    int b  = blockIdx.z;
    const float* ip = in  + (size_t)b * cNPIX * cC;
    float*       op = out + (size_t)b * cC * cNPIX;
    int tx = threadIdx.x, ty = threadIdx.y;
#pragma unroll
    for (int i = 0; i < 32; i += 8)
        tile[ty + i][tx] = ip[(size_t)(s0 + ty + i) * cC + c0 + tx];
    __syncthreads();
#pragma unroll
    for (int i = 0; i < 32; i += 8)
        op[(size_t)(c0 + ty + i) * cNPIX + s0 + tx] = tile[tx][ty + i];
}

// ---------------------------------------------------------------------------
// LN-fused GEMM, K=128, bf16 out. A-tile LN'd into LDS; W fragments loaded
// global->VGPR (L2-resident panel), double-buffered per k-step; two-pass
// LDS-staged coalesced epilogue (Sb 64 rows). LDS 52KB -> 3 blocks/CU.
// QKVS: -1 plain; 0/1 QKV (cols 0..255 -> qkb; 256..383 -> vt scatter).
// ---------------------------------------------------------------------------
template<int QKVS>
__global__ __launch_bounds__(256) void k_gemm_ln(const float* __restrict__ F,
                                                 const float* __restrict__ gw,
                                                 const float* __restrict__ bw,
                                                 const bf16* __restrict__ Wt,
                                                 const float* __restrict__ bias,
                                                 bf16* __restrict__ outB, int M,
                                                 bf16* __restrict__ vtb)
{
    __shared__ bf16 As[128][136];
    __shared__ bf16 Sb[64][136];

    const int NS = M >> 7;
    const int l  = blockIdx.x;
    const int r8 = l % (8 * NS);
    const int qq = l / (8 * NS);
    const int bm = (qq * 8 + (r8 & 7)) * 128;   // token tile
    const int bn = (r8 >> 3) * 128;             // col tile

    const int t = threadIdx.x;
    const int lane = t & 63, wid = t >> 6;
    const int wm = (wid >> 1) * 64, wn = (wid & 1) * 64;
    const int lr = lane & 15, lg = lane >> 4;

    // ---- issue ks=0 W fragment loads first (L2; overlaps LN staging) ----
    const bf16* wp = Wt + (size_t)(bn + wn + lr) * 128 + lg * 8;
    bf16x8 bwA[4], bwB[4];
#pragma unroll
    for (int nf = 0; nf < 4; ++nf)
        bwA[nf] = *(const bf16x8*)(wp + (size_t)(nf * 16) * 128);

    // ---- LN-fused A staging: 2 threads per row ----
    {
        const int row = t >> 1, hf = t & 1;
        const float* src = F + (size_t)(bm + row) * 128 + hf * 64;
        float4 v[16];
        float s = 0.f, sq = 0.f;
#pragma unroll
        for (int i = 0; i < 16; ++i) {
            v[i] = *(const float4*)(src + i * 4);
            s  += v[i].x + v[i].y + v[i].z + v[i].w;
            sq += v[i].x*v[i].x + v[i].y*v[i].y + v[i].z*v[i].z + v[i].w*v[i].w;
        }
        s  += __shfl_xor(s, 1);
        sq += __shfl_xor(sq, 1);
        const float mu = s * (1.f / 128.f);
        const float rs = rsqrtf(sq * (1.f / 128.f) - mu * mu + 1e-5f);
#pragma unroll
        for (int i = 0; i < 8; ++i) {
            float4 a  = v[2*i], b2 = v[2*i+1];
            float4 g0 = *(const float4*)(gw + hf*64 + i*8);
            float4 g1 = *(const float4*)(gw + hf*64 + i*8 + 4);
            float4 b0 = *(const float4*)(bw + hf*64 + i*8);
            float4 b1 = *(const float4*)(bw + hf*64 + i*8 + 4);
            bf16x8 o;
            o[0] = (bf16)((a.x  - mu) * rs * g0.x + b0.x);
            o[1] = (bf16)((a.y  - mu) * rs * g0.y + b0.y);
            o[2] = (bf16)((a.z  - mu) * rs * g0.z + b0.z);
            o[3] = (bf16)((a.w  - mu) * rs * g0.w + b0.w);
            o[4] = (bf16)((b2.x - mu) * rs * g1.x + b1.x);
            o[5] = (bf16)((b2.y - mu) * rs * g1.y + b1.y);
            o[6] = (bf16)((b2.z - mu) * rs * g1.z + b1.z);
            o[7] = (bf16)((b2.w - mu) * rs * g1.w + b1.w);
            *(bf16x8*)&As[row][hf*64 + i*8] = o;
        }
    }
    __syncthreads();

    // ---- MFMA: 4 k-steps, W double-buffered in regs, no barriers ----
    const f32x4 zero4 = {0.f, 0.f, 0.f, 0.f};
    f32x4 acc[4][4];
#pragma unroll
    for (int i = 0; i < 4; ++i)
#pragma unroll
        for (int j = 0; j < 4; ++j) acc[i][j] = zero4;

#pragma unroll
    for (int ks = 0; ks < 4; ++ks) {
        const bf16x8* cur = (ks & 1) ? bwB : bwA;
        bf16x8*       nxt = (ks & 1) ? bwA : bwB;
        if (ks < 3) {
#pragma unroll
            for (int nf = 0; nf < 4; ++nf)
                nxt[nf] = *(const bf16x8*)(wp + (size_t)(nf * 16) * 128 + (ks + 1) * 32);
        }
        bf16x8 af[4];
#pragma unroll
        for (int mf = 0; mf < 4; ++mf)
            af[mf] = *(const bf16x8*)&As[wm + mf*16 + lr][ks*32 + lg*8];
        __builtin_amdgcn_s_setprio(1);
#pragma unroll
        for (int mf = 0; mf < 4; ++mf)
#pragma unroll
            for (int nf = 0; nf < 4; ++nf)
                acc[mf][nf] = MFMA_BF16(af[mf], cur[nf], acc[mf][nf]);
        __builtin_amdgcn_s_setprio(0);
    }

    // ---- epilogue ----
    const bool vpart = (QKVS >= 0) && (bn == 256);
    if (!vpart) {
        const int ldo = (QKVS >= 0) ? 256 : M;
#pragma unroll
        for (int half = 0; half < 2; ++half) {
            __syncthreads();
            if ((wid >> 1) == half) {
#pragma unroll
                for (int nf = 0; nf < 4; ++nf) {
                    int col = wn + nf * 16 + lr;
                    float bv = bias ? bias[bn + col] : 0.f;
#pragma unroll
                    for (int mf = 0; mf < 4; ++mf)
#pragma unroll
                        for (int r = 0; r < 4; ++r)
                            Sb[mf * 16 + lg * 4 + r][col] = (bf16)(acc[mf][nf][r] + bv);
                }
            }
            __syncthreads();
#pragma unroll
            for (int i = 0; i < 4; ++i) {
                int o = i * 256 + t;
                int row = o >> 4, cg = (o & 15) * 8;
                *(bf16x8*)(outB + (size_t)(bm + half * 64 + row) * ldo + bn + cg) =
                    *(const bf16x8*)&Sb[row][cg];
            }
        }
    } else {
        // V scatter: vt[((b*64+win)*128+ch)*480 + key]; stage transposed.
        const int lr_ = t & 15, cg_ = t >> 4;
        const int gt = bm + lr_ * 8;
        const int b_ = gt / cNPIX, hw = gt % cNPIX;
        const int h = hw / cW, w = hw % cW;
        const int h0 = (QKVS == 1) ? ((h + 90) % 96) : h;
        const int nh = h0 / 12, kh = h0 - nh * 12;
#pragma unroll
        for (int cp = 0; cp < 2; ++cp) {
            __syncthreads();
            if ((wid & 1) == cp) {
#pragma unroll
                for (int nf = 0; nf < 4; ++nf) {
                    int cl = nf * 16 + lr;          // local col 0..63
#pragma unroll
                    for (int mf = 0; mf < 4; ++mf)
#pragma unroll
                        for (int r = 0; r < 4; ++r)
                            Sb[cl][wm + mf * 16 + lg * 4 + r] = (bf16)acc[mf][nf][r];
                }
            }
            __syncthreads();
#pragma unroll
            for (int i = 0; i < 4; ++i) {
                int chl = cg_ + 16 * i;
                int ch  = cp * 64 + chl;
                bf16x8 e = *(const bf16x8*)&Sb[chl][lr_ * 8];
#pragma unroll
                for (int hi = 0; hi < 2; ++hi) {
                    int wv = (QKVS == 1) ? ((w + hi * 4 + 300) % 320) : (w + hi * 4);
                    int nw = wv / 40, kw = wv - nw * 40;
                    bf16* dst = vtb + ((size_t)((b_ * 64 + nh * 8 + nw) * 128 + ch)) * 480 + kh * 40 + kw;
                    bf16x4 hv;
#pragma unroll
                    for (int j = 0; j < 4; ++j) hv[j] = e[hi * 4 + j];
                    *(bf16x4*)dst = hv;
                }
            }
        }
    }
}

// ---------------------------------------------------------------------------
// LN-fused GEMM for outlook attn logits: K=128, M=81 (stride 84), bf16 out.
// W->regs (guarded), Sb[64][88] bf16 staging. LDS 46KB -> 3 blocks/CU.
// ---------------------------------------------------------------------------
__global__ __launch_bounds__(256) void k_gemm_ln_wa(const float* __restrict__ F,
                                                    const float* __restrict__ gw,
                                                    const float* __restrict__ bw,
                                                    const bf16* __restrict__ Wt,
                                                    const float* __restrict__ bias,
                                                    bf16* __restrict__ outA)
{
    __shared__ bf16 As[128][136];
    __shared__ bf16 Sb[64][88];

    const int bm = blockIdx.x * 128;
    const int t = threadIdx.x;
    const int lane = t & 63, wid = t >> 6;
    const int wm = (wid >> 1) * 64, wn = (wid & 1) * 64;
    const int lr = lane & 15, lg = lane >> 4;

    bf16x8 zrow;
#pragma unroll
    for (int j = 0; j < 8; ++j) zrow[j] = (bf16)0.f;

    bool okc[4];
    const bf16* wp = Wt + (size_t)(wn + lr) * 128 + lg * 8;
#pragma unroll
    for (int nf = 0; nf < 4; ++nf) okc[nf] = (wn + nf * 16 + lr) < 81;

    bf16x8 bwA[4], bwB[4];
#pragma unroll
    for (int nf = 0; nf < 4; ++nf)
        bwA[nf] = okc[nf] ? *(const bf16x8*)(wp + (size_t)(nf * 16) * 128) : zrow;

    {
        const int row = t >> 1, hf = t & 1;
        const float* src = F + (size_t)(bm + row) * 128 + hf * 64;
        float4 v[16];
        float s = 0.f, sq = 0.f;
#pragma unroll
        for (int i = 0; i < 16; ++i) {
            v[i] = *(const float4*)(src + i * 4);
            s  += v[i].x + v[i].y + v[i].z + v[i].w;
            sq += v[i].x*v[i].x + v[i].y*v[i].y + v[i].z*v[i].z + v[i].w*v[i].w;
        }
        s  += __shfl_xor(s, 1);
        sq += __shfl_xor(sq, 1);
        const float mu = s * (1.f / 128.f);
        const float rs = rsqrtf(sq * (1.f / 128.f) - mu * mu + 1e-5f);
#pragma unroll
        for (int i = 0; i < 8; ++i) {
            float4 a  = v[2*i], b2 = v[2*i+1];
            float4 g0 = *(const float4*)(gw + hf*64 + i*8);
            float4 g1 = *(const float4*)(gw + hf*64 + i*8 + 4);
            float4 b0 = *(const float4*)(bw + hf*64 + i*8);
            float4 b1 = *(const float4*)(bw + hf*64 + i*8 + 4);
            bf16x8 o;
            o[0] = (bf16)((a.x  - mu) * rs * g0.x + b0.x);
            o[1] = (bf16)((a.y  - mu) * rs * g0.y + b0.y);
            o[2] = (bf16)((a.z  - mu) * rs * g0.z + b0.z);
            o[3] = (bf16)((a.w  - mu) * rs * g0.w + b0.w);
            o[4] = (bf16)((b2.x - mu) * rs * g1.x + b1.x);
            o[5] = (bf16)((b2.y - mu) * rs * g1.y + b1.y);
            o[6] = (bf16)((b2.z - mu) * rs * g1.z + b1.z);
            o[7] = (bf16)((b2.w - mu) * rs * g1.w + b1.w);
            *(bf16x8*)&As[row][hf*64 + i*8] = o;
        }
    }
    __syncthreads();

    const f32x4 zero4 = {0.f, 0.f, 0.f, 0.f};
    f32x4 acc[4][4];
#pragma unroll
    for (int i = 0; i < 4; ++i)
#pragma unroll
        for (int j = 0; j < 4; ++j) acc[i][j] = zero4;

#pragma unroll
    for (int ks = 0; ks < 4; ++ks) {
        const bf16x8* cur = (ks & 1) ? bwB : bwA;
        bf16x8*       nxt = (ks & 1) ? bwA : bwB;
        if (ks < 3) {
#pragma unroll
            for (int nf = 0; nf < 4; ++nf)
                nxt[nf] = okc[nf] ? *(const bf16x8*)(wp + (size_t)(nf * 16) * 128 + (ks + 1) * 32) : zrow;
        }
        bf16x8 af[4];
#pragma unroll
        for (int mf = 0; mf < 4; ++mf)
            af[mf] = *(const bf16x8*)&As[wm + mf*16 + lr][ks*32 + lg*8];
        __builtin_amdgcn_s_setprio(1);
#pragma unroll
        for (int mf = 0; mf < 4; ++mf)
#pragma unroll
            for (int nf = 0; nf < 4; ++nf)
                acc[mf][nf] = MFMA_BF16(af[mf], cur[nf], acc[mf][nf]);
        __builtin_amdgcn_s_setprio(0);
    }

#pragma unroll
    for (int half = 0; half < 2; ++half) {
        __syncthreads();
        if ((wid >> 1) == half) {
#pragma unroll
            for (int nf = 0; nf < 4; ++nf) {
                int col = wn + nf * 16 + lr;
                if (col >= 84) continue;
                float bv = (col < 81) ? bias[col] : 0.f;
#pragma unroll
                for (int mf = 0; mf < 4; ++mf)
#pragma unroll
                    for (int r = 0; r < 4; ++r) {
                        float vv = (col < 81) ? (acc[mf][nf][r] + bv) : 0.f;
                        Sb[mf * 16 + lg * 4 + r][col] = (bf16)vv;
                    }
            }
        }
        __syncthreads();
#pragma unroll
        for (int i = 0; i < 6; ++i) {
            int o = i * 256 + t;
            if (o < 64 * 21) {
                int row = o / 21, cq = (o - row * 21) * 4;
                *(bf16x4*)(outA + (size_t)(bm + half * 64 + row) * cAS + cq) =
                    *(const bf16x4*)&Sb[row][cq];
            }
        }
    }
}

// ---------------------------------------------------------------------------
// Generic k-loop GEMM, M=128, A bf16 (unchanged from R6).
// ---------------------------------------------------------------------------
template<bool OUTBF, bool RELU, bool RES, bool POS>
__global__ __launch_bounds__(256) void k_gemm_res(const bf16* __restrict__ A,
                                                  const bf16* __restrict__ Wt,
                                                  const float* __restrict__ bias,
                                                  const float* __restrict__ res,
                                                  float* __restrict__ outF,
                                                  bf16* __restrict__ outB,
                                                  int K,
                                                  const float* __restrict__ ytab,
                                                  const float* __restrict__ xtab)
{
    __shared__ bf16 As[128][40];
    __shared__ bf16 Bs[128][40];
    __shared__ float Sf[64][136];

    const int bm = blockIdx.x * 128;
    const int t = threadIdx.x;
    const int lane = t & 63, wid = t >> 6;
    const int wm = (wid >> 1) * 64, wn = (wid & 1) * 64;
    const int lr = lane & 15, lg = lane >> 4;

    const f32x4 zero4 = {0.f, 0.f, 0.f, 0.f};
    f32x4 acc[4][4];
#pragma unroll
    for (int i = 0; i < 4; ++i)
#pragma unroll
        for (int j = 0; j < 4; ++j) acc[i][j] = zero4;

    for (int k0 = 0; k0 < K; k0 += 32) {
#pragma unroll
        for (int i = 0; i < 2; ++i) {
            int idx = t + i * 256;
            int row = idx >> 2, kg = (idx & 3) * 8;
            *(bf16x8*)&As[row][kg] = *(const bf16x8*)(A + (size_t)(bm + row) * K + k0 + kg);
            *(bf16x8*)&Bs[row][kg] = *(const bf16x8*)(Wt + (size_t)row * K + k0 + kg);
        }
        __syncthreads();
        bf16x8 af[4], bf[4];
#pragma unroll
        for (int mf = 0; mf < 4; ++mf)
            af[mf] = *(const bf16x8*)&As[wm + mf*16 + lr][lg * 8];
#pragma unroll
        for (int nf = 0; nf < 4; ++nf)
            bf[nf] = *(const bf16x8*)&Bs[wn + nf*16 + lr][lg * 8];
        __builtin_amdgcn_s_setprio(1);
#pragma unroll
        for (int mf = 0; mf < 4; ++mf)
#pragma unroll
            for (int nf = 0; nf < 4; ++nf)
                acc[mf][nf] = MFMA_BF16(af[mf], bf[nf], acc[mf][nf]);
        __builtin_amdgcn_s_setprio(0);
        __syncthreads();
    }

    if (OUTBF) {
        bf16 (*Sb)[136] = (bf16(*)[136])Sf;
#pragma unroll
        for (int nf = 0; nf < 4; ++nf) {
            int col = wn + nf * 16 + lr;
            float bv = bias ? bias[col] : 0.f;
#pragma unroll
            for (int mf = 0; mf < 4; ++mf)
#pragma unroll
                for (int r = 0; r < 4; ++r) {
                    float vv = acc[mf][nf][r] + bv;
                    if (RELU) vv = fmaxf(vv, 0.f);
                    Sb[wm + mf * 16 + lg * 4 + r][col] = (bf16)vv;
                }
        }
        __syncthreads();
#pragma unroll
        for (int i = 0; i < 8; ++i) {
            int o = i * 256 + t;
            int row = o >> 4, cg = (o & 15) * 8;
            *(bf16x8*)(outB + (size_t)(bm + row) * 128 + cg) = *(const bf16x8*)&Sb[row][cg];
        }
    } else {
        for (int half = 0; half < 2; ++half) {
            __syncthreads();
            if ((wid >> 1) == half) {
#pragma unroll
                for (int nf = 0; nf < 4; ++nf) {
                    int col = wn + nf * 16 + lr;
                    float bv = bias ? bias[col] : 0.f;
#pragma unroll
                    for (int mf = 0; mf < 4; ++mf)
#pragma unroll
                        for (int r = 0; r < 4; ++r)
                            Sf[mf * 16 + lg * 4 + r][col] = acc[mf][nf][r] + bv;
                }
            }
            __syncthreads();
#pragma unroll
            for (int i = 0; i < 8; ++i) {
                int o = i * 256 + t;
                int row = o >> 5, cq = (o & 31) * 4;
                int grow = bm + half * 64 + row;
                float4 v = *(const float4*)&Sf[row][cq];
                if (POS) {
                    int hw = grow % cNPIX;
                    int h = hw / cW, w = hw - (hw / cW) * cW;
                    float4 p = (cq < 64) ? *(const float4*)(ytab + (h << 6) + cq)
                                         : *(const float4*)(xtab + (w << 6) + cq - 64);
                    v.x += p.x; v.y += p.y; v.z += p.z; v.w += p.w;
                }
                if (RES) {
                    float4 rr = *(const float4*)(res + (size_t)grow * 128 + cq);
                    v.x += rr.x; v.y += rr.y; v.z += rr.z; v.w += rr.w;
                }
                *(float4*)(outF + (size_t)grow * 128 + cq) = v;
            }
        }
    }
}

// ---------------------------------------------------------------------------
// Outlook fused gather (bf16 logits, stride 84).
// ---------------------------------------------------------------------------
__global__ __launch_bounds__(256) void k_olk_gather(const bf16* __restrict__ v,
                                                    const bf16* __restrict__ attn,
                                                    bf16* __restrict__ y)
{
    __shared__ float pr[16][84];
    __shared__ float coef[16][26];

    const int t  = threadIdx.x;
    const int px = t >> 4;
    const int j  = t & 15;
    const int pix = blockIdx.x * 16 + px;
    const int b  = pix / cNPIX;
    const int hw = pix % cNPIX;
    const int h = hw / cW, w = hw % cW;

    if (j < 9) {
        const int p  = j;
        const int pi = p / 3, pj = p - pi * 3;
        const int hh = h + 1 - pi, ww = w + 1 - pj;
        float prv[9];
        if ((unsigned)hh < (unsigned)cH && (unsigned)ww < (unsigned)cW) {
            const size_t row = (size_t)(b * cNPIX + hh * cW + ww);
            const bf16* arow = attn + row * cAS + p * 9;
            float lg[9];
            float m = 0.f;
#pragma unroll
            for (int q = 0; q < 9; ++q) { lg[q] = (float)arow[q]; m = fmaxf(m, lg[q]); }
            float se = 0.f;
#pragma unroll
            for (int q = 0; q < 9; ++q) { prv[q] = __expf(lg[q] - m); se += prv[q]; }
            float inv = 1.f / (se + __expf(-m));
#pragma unroll
            for (int q = 0; q < 9; ++q) prv[q] *= inv;
        } else {
#pragma unroll
            for (int q = 0; q < 9; ++q) prv[q] = 0.f;
        }
#pragma unroll
        for (int q = 0; q < 9; ++q) pr[px][p * 9 + q] = prv[q];
    }
    __syncthreads();

    for (int d = j; d < 25; d += 16) {
        const int a  = d / 5, bb = d - a * 5;
        float s = 0.f;
#pragma unroll
        for (int pi = 0; pi < 3; ++pi) {
            const int qi = pi + a - 2;
            if ((unsigned)qi >= 3u) continue;
#pragma unroll
            for (int pj = 0; pj < 3; ++pj) {
                const int qj = pj + bb - 2;
                if ((unsigned)qj >= 3u) continue;
                s += pr[px][(pi * 3 + pj) * 9 + qi * 3 + qj];
            }
        }
        coef[px][d] = s;
    }
    __syncthreads();

    float acc[8] = {};
    const size_t bbase = (size_t)b * cNPIX;
#pragma unroll
    for (int a = 0; a < 5; ++a) {
        const int sh = h + a - 2;
        if ((unsigned)sh >= (unsigned)cH) continue;
#pragma unroll
        for (int bb = 0; bb < 5; ++bb) {
            const int sw = w + bb - 2;
            if ((unsigned)sw >= (unsigned)cW) continue;
            const float cf = coef[px][a * 5 + bb];
            const bf16x8 v8 = *(const bf16x8*)(v + ((bbase + (size_t)sh * cW + sw) * 128 + j * 8));
#pragma unroll
            for (int e = 0; e < 8; ++e) acc[e] = fmaf(cf, (float)v8[e], acc[e]);
        }
    }
    bf16x8 o8;
#pragma unroll
    for (int e = 0; e < 8; ++e) o8[e] = (bf16)acc[e];
    *(bf16x8*)(y + (size_t)pix * 128 + j * 8) = o8;
}

// ---------------------------------------------------------------------------
// Depthwise 3x3 + bias + exact GELU, row-sliding, NHWC 512 ch.
// ---------------------------------------------------------------------------
__global__ __launch_bounds__(256) void k_dwconv_gelu(const bf16* __restrict__ h1,
                                                     const float* __restrict__ dwt,
                                                     const float* __restrict__ bdw,
                                                     bf16* __restrict__ h2)
{
    const int t   = threadIdx.x;
    const int c2  = t * 2;
    const int blk = blockIdx.x;
    const int row = blk >> 3;
    const int seg = blk & 7;
    const int bb  = row / cH, h = row % cH;
    const int w0  = seg * 40;

    float2 wgt[9];
#pragma unroll
    for (int k = 0; k < 9; ++k)
        wgt[k] = *(const float2*)(dwt + k * 512 + c2);
    const float2 bias = *(const float2*)(bdw + c2);

    const size_t base = (size_t)bb * cNPIX;

    auto ld = [&](int hh, int ww) -> float2 {
        float2 r; r.x = 0.f; r.y = 0.f;
        if ((unsigned)hh < (unsigned)cH && (unsigned)ww < (unsigned)cW) {
            unsigned u = *(const unsigned*)(h1 + ((base + (size_t)hh * cW + ww) * 512 + c2));
            r.x = __uint_as_float(u << 16);
            r.y = __uint_as_float(u & 0xffff0000u);
        }
        return r;
    };

    float2 cm[3], c0[3], cp[3];
#pragma unroll
    for (int r = 0; r < 3; ++r) {
        cm[r] = ld(h + r - 1, w0 - 1);
        c0[r] = ld(h + r - 1, w0);
    }

    for (int j = 0; j < 40; ++j) {
#pragma unroll
        for (int r = 0; r < 3; ++r) cp[r] = ld(h + r - 1, w0 + j + 1);
        float a0 = bias.x, a1 = bias.y;
#pragma unroll
        for (int r = 0; r < 3; ++r) {
            a0 = fmaf(cm[r].x, wgt[r * 3 + 0].x, a0);
            a1 = fmaf(cm[r].y, wgt[r * 3 + 0].y, a1);
            a0 = fmaf(c0[r].x, wgt[r * 3 + 1].x, a0);
            a1 = fmaf(c0[r].y, wgt[r * 3 + 1].y, a1);
            a0 = fmaf(cp[r].x, wgt[r * 3 + 2].x, a0);
            a1 = fmaf(cp[r].y, wgt[r * 3 + 2].y, a1);
        }
        a0 = 0.5f * a0 * (1.f + erff(a0 * 0.70710678118654752f));
        a1 = 0.5f * a1 * (1.f + erff(a1 * 0.70710678118654752f));
        union { bf16 hh[2]; unsigned int u; } o2;
        o2.hh[0] = (bf16)a0;
        o2.hh[1] = (bf16)a1;
        *(unsigned int*)(h2 + (base + (size_t)h * cW + w0 + j) * 512 + c2) = o2.u;
#pragma unroll
        for (int r = 0; r < 3; ++r) { cm[r] = c0[r]; c0[r] = cp[r]; }
    }
}

// ---------------------------------------------------------------------------
// Window attention, MFMA flash-style (unchanged from R5/R6).
// ---------------------------------------------------------------------------
template<bool SHIFT>
__global__ __launch_bounds__(256) void k_win_attn(const bf16* __restrict__ qk,
                                                  const bf16* __restrict__ vt,
                                                  bf16* __restrict__ out)
{
    __shared__ bf16 Ks[2][32][136];
    __shared__ bf16 Vs[2][128][40];
    __shared__ bf16 Ps[4][16][40];

    const int t = threadIdx.x, lane = t & 63, wid = t >> 6;
    const int lr = lane & 15, lg = lane >> 4;
    const int wb = blockIdx.x;
    const int b  = wb >> 6, win = wb & 63;
    const int nh = win >> 3, nw = win & 7;
    const int qbase = blockIdx.y * 64 + wid * 16;

    const float SCALE   = 0.088388347648318447f;
    const float MASKRAW = 100.f / 0.088388347648318447f;

    auto tokOf = [&](int p) {
        int ph = nh * 12 + p / 40;
        int pw = nw * 40 + (p % 40);
        if (SHIFT) {
            ph += 6;  if (ph >= cH) ph -= cH;
            pw += 20; if (pw >= cW) pw -= cW;
        }
        return b * cNPIX + ph * cW + pw;
    };
    auto labOf = [&](int p) {
        int ph = nh * 12 + p / 40;
        int pw = nw * 40 + (p % 40);
        int rh = ph < 84 ? 0 : (ph < 90 ? 1 : 2);
        int rc = pw < 280 ? 0 : (pw < 300 ? 1 : 2);
        return rh * 3 + rc;
    };

    int qp = min(qbase + lr, 479);
    const bf16* qptr = qk + (size_t)tokOf(qp) * 256;
    bf16x8 qf[4];
#pragma unroll
    for (int c = 0; c < 4; ++c)
        qf[c] = *(const bf16x8*)(qptr + c * 32 + lg * 8);

    int labq[4];
    if (SHIFT) {
#pragma unroll
        for (int r = 0; r < 4; ++r) labq[r] = labOf(min(qbase + lg * 4 + r, 479));
    }

    const bf16* vbase = vt + (size_t)wb * 128 * 480;
    auto loadK = [&](int kt, int i) {
        int idx = t + i * 256;
        int key = idx >> 4, cg = (idx & 15) * 8;
        return *(const bf16x8*)(qk + (size_t)tokOf(kt * 32 + key) * 256 + 128 + cg);
    };
    auto loadV = [&](int kt, int i) {
        int idx = t + i * 256;
        int ch = idx >> 2, kq = (idx & 3) * 8;
        return *(const bf16x8*)(vbase + (size_t)ch * 480 + kt * 32 + kq);
    };

    bf16x8 kreg0 = loadK(0, 0), kreg1 = loadK(0, 1);
    bf16x8 vreg0 = loadV(0, 0), vreg1 = loadV(0, 1);

    const f32x4 zero4 = {0.f, 0.f, 0.f, 0.f};
    float m_run[4] = {0.f, 0.f, 0.f, 0.f};
    float mguard = 8.f;
    f32x4 l4 = zero4;
    f32x4 o[8];
#pragma unroll
    for (int nf = 0; nf < 8; ++nf) o[nf] = zero4;

    bf16x8 ones8;
#pragma unroll
    for (int j = 0; j < 8; ++j) ones8[j] = (bf16)1.f;

    int buf = 0;
    for (int kt = 0; kt < 15; ++kt) {
        {
            int i0 = t, i1 = t + 256;
            *(bf16x8*)&Ks[buf][i0 >> 4][(i0 & 15) * 8] = kreg0;
            *(bf16x8*)&Ks[buf][i1 >> 4][(i1 & 15) * 8] = kreg1;
            *(bf16x8*)&Vs[buf][i0 >> 2][(i0 & 3) * 8] = vreg0;
            *(bf16x8*)&Vs[buf][i1 >> 2][(i1 & 3) * 8] = vreg1;
        }
        if (kt + 1 < 15) {
            kreg0 = loadK(kt + 1, 0); kreg1 = loadK(kt + 1, 1);
            vreg0 = loadV(kt + 1, 0); vreg1 = loadV(kt + 1, 1);
        }
        __syncthreads();

        f32x4 s0 = zero4, s1 = zero4;
        __builtin_amdgcn_s_setprio(1);
#pragma unroll
        for (int c = 0; c < 4; ++c) {
            bf16x8 kf0 = *(const bf16x8*)&Ks[buf][lr][c * 32 + lg * 8];
            bf16x8 kf1 = *(const bf16x8*)&Ks[buf][16 + lr][c * 32 + lg * 8];
            s0 = MFMA_BF16(qf[c], kf0, s0);
            s1 = MFMA_BF16(qf[c], kf1, s1);
        }
        __builtin_amdgcn_s_setprio(0);

        if (SHIFT) {
            int lab0 = labOf(kt * 32 + lr);
            int lab1 = labOf(kt * 32 + 16 + lr);
#pragma unroll
            for (int r = 0; r < 4; ++r) {
                if (labq[r] != lab0) s0[r] -= MASKRAW;
                if (labq[r] != lab1) s1[r] -= MASKRAW;
            }
        }

        float tm = fmaxf(fmaxf(fmaxf(s0[0], s0[1]), fmaxf(s0[2], s0[3])),
                         fmaxf(fmaxf(s1[0], s1[1]), fmaxf(s1[2], s1[3])));
#pragma unroll
        for (int off = 1; off < 16; off <<= 1) tm = fmaxf(tm, __shfl_xor(tm, off));
        if (tm * SCALE > mguard) {
#pragma unroll
            for (int r = 0; r < 4; ++r) {
                float mx = fmaxf(s0[r], s1[r]);
#pragma unroll
                for (int off = 1; off < 16; off <<= 1) mx = fmaxf(mx, __shfl_xor(mx, off));
                float nm = fmaxf(m_run[r], mx * SCALE);
                float sc = __expf(m_run[r] - nm);
#pragma unroll
                for (int nf = 0; nf < 8; ++nf) o[nf][r] *= sc;
                l4[r] *= sc;
                m_run[r] = nm;
            }
            mguard = fminf(fminf(m_run[0], m_run[1]), fminf(m_run[2], m_run[3])) + 8.f;
        }

#pragma unroll
        for (int r = 0; r < 4; ++r) {
            float p0 = __expf(fmaf(s0[r], SCALE, -m_run[r]));
            float p1 = __expf(fmaf(s1[r], SCALE, -m_run[r]));
            Ps[wid][lg * 4 + r][lr]      = (bf16)p0;
            Ps[wid][lg * 4 + r][16 + lr] = (bf16)p1;
        }

        bf16x8 pa = *(const bf16x8*)&Ps[wid][lr][lg * 8];
        __builtin_amdgcn_s_setprio(1);
        l4 = MFMA_BF16(pa, ones8, l4);
#pragma unroll
        for (int nf = 0; nf < 8; ++nf) {
            bf16x8 bv = *(const bf16x8*)&Vs[buf][nf * 16 + lr][lg * 8];
            o[nf] = MFMA_BF16(pa, bv, o[nf]);
        }
        __builtin_amdgcn_s_setprio(0);
        __syncthreads();
        buf ^= 1;
    }

#pragma unroll
    for (int r = 0; r < 4; ++r) {
        int qrow = qbase + lg * 4 + r;
        if (qrow >= 480) continue;
        float inv = 1.f / (l4[r] + __expf(-m_run[r]));
        size_t ooff = (size_t)tokOf(qrow) * 128;
#pragma unroll
        for (int nf = 0; nf < 8; ++nf)
            out[ooff + nf * 16 + lr] = (bf16)(o[nf][r] * inv);
    }
}

// ---------------------------------------------------------------------------
// Host launcher
// ---------------------------------------------------------------------------
extern "C" void kernel_launch(void* const* d_in, const int* in_sizes, int n_in,
                              void* d_out, int out_size, void* d_ws, size_t ws_size,
                              hipStream_t stream)
{
    (void)in_sizes; (void)n_in; (void)out_size; (void)ws_size;

    const float* X = (const float*)d_in[0];

    char* ws = (char*)d_ws;
    float* f    = (float*)ws;                                 ws += (size_t)cNTOK * 128 * 4;
    ws += (size_t)cNTOK * 128 * 2;
    bf16*  bufA = (bf16*)ws;                                  ws += (size_t)cNTOK * 512 * 2;
    bf16*  bufB = (bf16*)ws;                                  ws += (size_t)cNTOK * 512 * 2;
    bf16*  wts  = (bf16*)ws;

    size_t wo_off = 0;
    auto nextw = [&](int K, int M) { bf16* p = wts + wo_off; wo_off += (size_t)K * M; return p; };
    bf16* agg_w1t = nextw(256, 128);
    bf16* agg_w2t = nextw(128, 128);
    bf16* ol_wvt  = nextw(128, 128);
    bf16* ol_wat  = nextw(128, 81);
    bf16* ol_wot  = nextw(128, 128);
    bf16* f1_w1t  = nextw(128, 512);
    bf16* f1_w2t  = nextw(512, 128);
    bf16* w_qkvt  = nextw(128, 384);
    bf16* w_wot   = nextw(128, 128);
    bf16* f2_w1t  = nextw(128, 512);
    bf16* f2_w2t  = nextw(512, 128);
    bf16* s_qkvt  = nextw(128, 384);
    bf16* s_wot   = nextw(128, 128);
    bf16* f3_w1t  = nextw(128, 512);
    bf16* f3_w2t  = nextw(512, 128);
    float* dwt1 = (float*)(wts + wo_off);
    float* dwt2 = dwt1 + 512 * 9;
    float* dwt3 = dwt2 + 512 * 9;
    float* ytab = dwt3 + 512 * 9;
    float* xtab = ytab + 96 * 64;

    WJobs jobs;
    int ji = 0;
    auto addj = [&](int src_idx, bf16* dst, int K, int M) {
        jobs.j[ji++] = WJob{(const float*)d_in[src_idx], dst, K, M};
    };
    addj(1,  agg_w1t, 256, 128);
    addj(3,  agg_w2t, 128, 128);
    addj(7,  ol_wvt,  128, 128);
    addj(8,  ol_wat,  128, 81);
    addj(10, ol_wot,  128, 128);
    addj(14, f1_w1t,  128, 512);
    addj(18, f1_w2t,  512, 128);
    addj(22, w_qkvt,           128, 128);
    addj(23, w_qkvt + 128*128, 128, 128);
    addj(24, w_qkvt + 256*128, 128, 128);
    addj(25, w_wot,   128, 128);
    addj(29, f2_w1t,  128, 512);
    addj(33, f2_w2t,  512, 128);
    addj(37, s_qkvt,           128, 128);
    addj(38, s_qkvt + 128*128, 128, 128);
    addj(39, s_qkvt + 256*128, 128, 128);
    addj(40, s_wot,   128, 128);
    addj(44, f3_w1t,  128, 512);
    addj(48, f3_w2t,  512, 128);
    k_wt<<<dim3(16, 16, 19), dim3(32, 8), 0, stream>>>(jobs);
    k_dwt<<<3, 256, 0, stream>>>((const float*)d_in[16], (const float*)d_in[31],
                                 (const float*)d_in[46], dwt1, dwt2, dwt3);
    k_postab<<<80, 256, 0, stream>>>(ytab, xtab);

    const int nTT = cNTOK / 128;   // 480 token tiles

    // ---- input transpose + aggregation MLP ----
    k_chw2hwc<<<dim3(cNPIX / 32, 256 / 32, cB), dim3(32, 8), 0, stream>>>(X, bufA);
    k_gemm_res<true, true, false, false><<<nTT, 256, 0, stream>>>(
        bufA, agg_w1t, (const float*)d_in[2], nullptr, nullptr, bufB, 256, nullptr, nullptr);
    k_gemm_res<false, false, false, false><<<nTT, 256, 0, stream>>>(
        bufB, agg_w2t, (const float*)d_in[4], nullptr, f, nullptr, 128, nullptr, nullptr);

    // ---- outlook attention ----
    {
        bf16*  vb   = bufA;
        bf16*  gout = bufA + (size_t)cNTOK * 128;
        bf16*  atn  = bufB;
        k_gemm_ln<-1><<<nTT, 256, 0, stream>>>(
            f, (const float*)d_in[5], (const float*)d_in[6], ol_wvt, nullptr, vb, 128, nullptr);
        k_gemm_ln_wa<<<nTT, 256, 0, stream>>>(
            f, (const float*)d_in[5], (const float*)d_in[6], ol_wat, (const float*)d_in[9], atn);
        k_olk_gather<<<cNTOK / 16, 256, 0, stream>>>(vb, atn, gout);
        k_gemm_res<false, false, true, false><<<nTT, 256, 0, stream>>>(
            gout, ol_wot, (const float*)d_in[11], f, f, nullptr, 128, nullptr, nullptr);
    }

    // ---- conv FFN ----
    auto run_ffn = [&](int base, bf16* w1t, bf16* w2t, float* dwt, bool pos) {
        k_gemm_ln<-1><<<nTT * 4, 256, 0, stream>>>(
            f, (const float*)d_in[base], (const float*)d_in[base + 1], w1t,
            (const float*)d_in[base + 3], bufA, 512, nullptr);
        k_dwconv_gelu<<<cB * cH * 8, 256, 0, stream>>>(
            bufA, dwt, (const float*)d_in[base + 5], bufB);
        if (pos)
            k_gemm_res<false, false, true, true><<<nTT, 256, 0, stream>>>(
                bufB, w2t, (const float*)d_in[base + 7], f, f, nullptr, 512, ytab, xtab);
        else
            k_gemm_res<false, false, true, false><<<nTT, 256, 0, stream>>>(
                bufB, w2t, (const float*)d_in[base + 7], f, f, nullptr, 512, nullptr, nullptr);
    };

    // ---- window attention ----
    auto run_win = [&](int base, bf16* qkvt, bf16* wot, bool shift) {
        bf16* qkb = bufA;
        bf16* vtb = bufA + (size_t)cNTOK * 256;
        bf16* ao  = bufB;
        if (shift)
            k_gemm_ln<1><<<nTT * 3, 256, 0, stream>>>(
                f, (const float*)d_in[base], (const float*)d_in[base + 1], qkvt, nullptr, qkb, 384, vtb);
        else
            k_gemm_ln<0><<<nTT * 3, 256, 0, stream>>>(
                f, (const float*)d_in[base], (const float*)d_in[base + 1], qkvt, nullptr, qkb, 384, vtb);
        if (shift) k_win_attn<true ><<<dim3(128, 8), 256, 0, stream>>>(qkb, vtb, ao);
        else       k_win_attn<false><<<dim3(128, 8), 256, 0, stream>>>(qkb, vtb, ao);
        k_gemm_res<false, false, true, false><<<nTT, 256, 0, stream>>>(
            ao, wot, (const float*)d_in[base + 6], f, f, nullptr, 128, nullptr, nullptr);
    };

    run_ffn(12, f1_w1t, f1_w2t, dwt1, true);                   // f1 (+pos fused)
    run_win(20, w_qkvt, w_wot, false);                         // w
    run_ffn(27, f2_w1t, f2_w2t, dwt2, false);                  // f2
    run_win(35, s_qkvt, s_wot, true);                          // s (shifted)
    run_ffn(42, f3_w1t, f3_w2t, dwt3, false);                  // f3

    k_hwc2chw<<<dim3(cNPIX / 32, cC / 32, cB), dim3(32, 8), 0, stream>>>(f, (float*)d_out);
}

// Round 8
// 678.283 us; speedup vs baseline: 5.7473x; 1.0961x over previous
//
#include <hip/hip_runtime.h>

typedef __bf16 bf16;
typedef __bf16 bf16x8 __attribute__((ext_vector_type(8)));
typedef __bf16 bf16x4 __attribute__((ext_vector_type(4)));
typedef float  f32x4  __attribute__((ext_vector_type(4)));

#define MFMA_BF16(a, b, c) __builtin_amdgcn_mfma_f32_16x16x32_bf16(a, b, c, 0, 0, 0)

constexpr int cB    = 2;
constexpr int cH    = 96;
constexpr int cW    = 320;
constexpr int cC    = 128;
constexpr int cNPIX = cH * cW;          // 30720
constexpr int cNTOK = cB * cNPIX;       // 61440
constexpr int cAS   = 84;               // padded attn-logit stride (81 -> 84)

// ---------------------------------------------------------------------------
// Weight transpose+convert: fp32 W (K x M) -> bf16 Wt (M x K)
// ---------------------------------------------------------------------------
struct WJob  { const float* src; bf16* dst; int K; int M; };
struct WJobs { WJob j[19]; };

__global__ __launch_bounds__(256) void k_wt(WJobs jobs)
{
    __shared__ float tile[32][33];
    const WJob jb = jobs.j[blockIdx.z];
    int k0 = blockIdx.y * 32, m0 = blockIdx.x * 32;
    if (k0 >= jb.K || m0 >= jb.M) return;
    int tx = threadIdx.x, ty = threadIdx.y;
#pragma unroll
    for (int i = 0; i < 32; i += 8) {
        int kk = k0 + ty + i, mm = m0 + tx;
        tile[ty + i][tx] = (kk < jb.K && mm < jb.M) ? jb.src[(size_t)kk * jb.M + mm] : 0.f;
    }
    __syncthreads();
#pragma unroll
    for (int i = 0; i < 32; i += 8) {
        int mm = m0 + ty + i, kk = k0 + tx;
        if (mm < jb.M && kk < jb.K)
            jb.dst[(size_t)mm * jb.K + kk] = (bf16)tile[tx][ty + i];
    }
}

__global__ __launch_bounds__(256) void k_dwt(const float* s0, const float* s1, const float* s2,
                                             float* d0, float* d1, float* d2)
{
    const float* s = blockIdx.x == 0 ? s0 : (blockIdx.x == 1 ? s1 : s2);
    float*       d = blockIdx.x == 0 ? d0 : (blockIdx.x == 1 ? d1 : d2);
    for (int i = threadIdx.x; i < 512 * 9; i += 256) {
        int c = i / 9, tap = i - c * 9;
        d[tap * 512 + c] = s[i];
    }
}

__global__ __launch_bounds__(256) void k_postab(float* __restrict__ yt, float* __restrict__ xt)
{
    int i = blockIdx.x * 256 + threadIdx.x;
    const float TWO_PI = 6.283185307179586f;
    const float KSC = -9.210340371976184f / 32.f;
    if (i < 96 * 64) {
        int h = i >> 6, c = i & 63;
        float p = (float)(h + 1) * (TWO_PI / (96.f + 1e-6f));
        float val = p * expf((float)(c >> 1) * KSC);
        yt[i] = (c & 1) ? cosf(val) : sinf(val);
    }
    if (i < 320 * 64) {
        int w = i >> 6, c = i & 63;
        float p = (float)(w + 1) * (TWO_PI / (320.f + 1e-6f));
        float val = p * expf((float)(c >> 1) * KSC);
        xt[i] = (c & 1) ? cosf(val) : sinf(val);
    }
}

// ---------------------------------------------------------------------------
// Transposes
// ---------------------------------------------------------------------------
__global__ __launch_bounds__(256) void k_chw2hwc(const float* __restrict__ in,
                                                 bf16* __restrict__ out)
{
    __shared__ float tile[32][33];
    const int Cc = 256;
    int s0 = blockIdx.x * 32;
    int c0 = blockIdx.y * 32;
    int b  = blockIdx.z;
    const float* ip = in  + (size_t)b * Cc * cNPIX;
    bf16*        op = out + (size_t)b * cNPIX * Cc;
    int tx = threadIdx.x, ty = threadIdx.y;
#pragma unroll
    for (int i = 0; i < 32; i += 8)
        tile[ty + i][tx] = ip[(size_t)(c0 + ty + i) * cNPIX + s0 + tx];
    __syncthreads();
#pragma unroll
    for (int i = 0; i < 32; i += 8)
        op[(size_t)(s0 + ty + i) * Cc + c0 + tx] = (bf16)tile[tx][ty + i];
}

__global__ __launch_bounds__(256) void k_hwc2chw(const float* __restrict__ in,
                                                 float* __restrict__ out)
{
    __shared__ float tile[32][33];
    int s0 = blockIdx.x * 32;
    int c0 = blockIdx.y * 32;
    int b  = blockIdx.z;
    const float* ip = in  + (size_t)b * cNPIX * cC;
    float*       op = out + (size_t)b * cC * cNPIX;
    int tx = threadIdx.x, ty = threadIdx.y;
#pragma unroll
    for (int i = 0; i < 32; i += 8)
        tile[ty + i][tx] = ip[(size_t)(s0 + ty + i) * cC + c0 + tx];
    __syncthreads();
#pragma unroll
    for (int i = 0; i < 32; i += 8)
        op[(size_t)(c0 + ty + i) * cNPIX + s0 + tx] = tile[tx][ty + i];
}

// ---------------------------------------------------------------------------
// LayerNorm over C=128 (fp32 in, bf16 out) — coalesced float2/lane.
// ---------------------------------------------------------------------------
__global__ __launch_bounds__(256) void k_ln(const float* __restrict__ x,
                                            const float* __restrict__ g,
                                            const float* __restrict__ b,
                                            bf16* __restrict__ out)
{
    int tok  = blockIdx.x * 4 + (threadIdx.x >> 6);
    int lane = threadIdx.x & 63;
    float2 v = *(const float2*)(x + (size_t)tok * cC + lane * 2);
    float s = v.x + v.y;
#pragma unroll
    for (int o = 1; o < 64; o <<= 1) s += __shfl_xor(s, o);
    float mu = s * (1.f / cC);
    float dx = v.x - mu, dy = v.y - mu;
    float sq = dx * dx + dy * dy;
#pragma unroll
    for (int o = 1; o < 64; o <<= 1) sq += __shfl_xor(sq, o);
    float rs = rsqrtf(sq * (1.f / cC) + 1e-5f);
    float2 gv = *(const float2*)(g + lane * 2);
    float2 bv = *(const float2*)(b + lane * 2);
    union { bf16 h[2]; unsigned int u; } o2;
    o2.h[0] = (bf16)(dx * rs * gv.x + bv.x);
    o2.h[1] = (bf16)(dy * rs * gv.y + bv.y);
    *(unsigned int*)(out + (size_t)tok * cC + lane * 2) = o2.u;
}

// ---------------------------------------------------------------------------
// K=128 single-shot GEMM, A bf16 [tok][128] coalesced-staged into LDS;
// W fragments global->VGPR (L2 panel), double-buffered; two-pass Sb epilogue.
// QKVS: -1 plain bf16 out [tok][M]; 0/1 QKV (cols 0..255 -> qkb stride 256;
//        256..383 -> vt[win][ch][key] scatter, shift folded in).
// ---------------------------------------------------------------------------
template<int QKVS>
__global__ __launch_bounds__(256) void k_gemm128(const bf16* __restrict__ A,
                                                 const bf16* __restrict__ Wt,
                                                 const float* __restrict__ bias,
                                                 bf16* __restrict__ outB, int M,
                                                 bf16* __restrict__ vtb)
{
    __shared__ bf16 As[128][136];
    __shared__ bf16 Sb[64][136];

    const int NS = M >> 7;
    const int l  = blockIdx.x;
    const int r8 = l % (8 * NS);
    const int qq = l / (8 * NS);
    const int bm = (qq * 8 + (r8 & 7)) * 128;   // token tile
    const int bn = (r8 >> 3) * 128;             // col tile

    const int t = threadIdx.x;
    const int lane = t & 63, wid = t >> 6;
    const int wm = (wid >> 1) * 64, wn = (wid & 1) * 64;
    const int lr = lane & 15, lg = lane >> 4;

    // ---- ks=0 W fragment loads (L2; overlap A staging) ----
    const bf16* wp = Wt + (size_t)(bn + wn + lr) * 128 + lg * 8;
    bf16x8 bwA[4], bwB[4];
#pragma unroll
    for (int nf = 0; nf < 4; ++nf)
        bwA[nf] = *(const bf16x8*)(wp + (size_t)(nf * 16) * 128);

    // ---- A staging: fully coalesced (16 lanes x 16B = one 256B row) ----
#pragma unroll
    for (int i = 0; i < 8; ++i) {
        int o = i * 256 + t;
        int row = o >> 4, cg = (o & 15) * 8;
        *(bf16x8*)&As[row][cg] = *(const bf16x8*)(A + (size_t)(bm + row) * 128 + cg);
    }
    __syncthreads();

    // ---- MFMA: 4 k-steps, W double-buffered in regs, no barriers ----
    const f32x4 zero4 = {0.f, 0.f, 0.f, 0.f};
    f32x4 acc[4][4];
#pragma unroll
    for (int i = 0; i < 4; ++i)
#pragma unroll
        for (int j = 0; j < 4; ++j) acc[i][j] = zero4;

#pragma unroll
    for (int ks = 0; ks < 4; ++ks) {
        const bf16x8* cur = (ks & 1) ? bwB : bwA;
        bf16x8*       nxt = (ks & 1) ? bwA : bwB;
        if (ks < 3) {
#pragma unroll
            for (int nf = 0; nf < 4; ++nf)
                nxt[nf] = *(const bf16x8*)(wp + (size_t)(nf * 16) * 128 + (ks + 1) * 32);
        }
        bf16x8 af[4];
#pragma unroll
        for (int mf = 0; mf < 4; ++mf)
            af[mf] = *(const bf16x8*)&As[wm + mf*16 + lr][ks*32 + lg*8];
        __builtin_amdgcn_s_setprio(1);
#pragma unroll
        for (int mf = 0; mf < 4; ++mf)
#pragma unroll
            for (int nf = 0; nf < 4; ++nf)
                acc[mf][nf] = MFMA_BF16(af[mf], cur[nf], acc[mf][nf]);
        __builtin_amdgcn_s_setprio(0);
    }

    // ---- epilogue ----
    const bool vpart = (QKVS >= 0) && (bn == 256);
    if (!vpart) {
        const int ldo = (QKVS >= 0) ? 256 : M;
#pragma unroll
        for (int half = 0; half < 2; ++half) {
            __syncthreads();
            if ((wid >> 1) == half) {
#pragma unroll
                for (int nf = 0; nf < 4; ++nf) {
                    int col = wn + nf * 16 + lr;
                    float bv = bias ? bias[bn + col] : 0.f;
#pragma unroll
                    for (int mf = 0; mf < 4; ++mf)
#pragma unroll
                        for (int r = 0; r < 4; ++r)
                            Sb[mf * 16 + lg * 4 + r][col] = (bf16)(acc[mf][nf][r] + bv);
                }
            }
            __syncthreads();
#pragma unroll
            for (int i = 0; i < 4; ++i) {
                int o = i * 256 + t;
                int row = o >> 4, cg = (o & 15) * 8;
                *(bf16x8*)(outB + (size_t)(bm + half * 64 + row) * ldo + bn + cg) =
                    *(const bf16x8*)&Sb[row][cg];
            }
        }
    } else {
        // V scatter: vt[((b*64+win)*128+ch)*480 + key]; stage transposed.
        const int lr_ = t & 15, cg_ = t >> 4;
        const int gt = bm + lr_ * 8;
        const int b_ = gt / cNPIX, hw = gt % cNPIX;
        const int h = hw / cW, w = hw % cW;
        const int h0 = (QKVS == 1) ? ((h + 90) % 96) : h;
        const int nh = h0 / 12, kh = h0 - nh * 12;
#pragma unroll
        for (int cp = 0; cp < 2; ++cp) {
            __syncthreads();
            if ((wid & 1) == cp) {
#pragma unroll
                for (int nf = 0; nf < 4; ++nf) {
                    int cl = nf * 16 + lr;          // local col 0..63
#pragma unroll
                    for (int mf = 0; mf < 4; ++mf)
#pragma unroll
                        for (int r = 0; r < 4; ++r)
                            Sb[cl][wm + mf * 16 + lg * 4 + r] = (bf16)acc[mf][nf][r];
                }
            }
            __syncthreads();
#pragma unroll
            for (int i = 0; i < 4; ++i) {
                int chl = cg_ + 16 * i;
                int ch  = cp * 64 + chl;
                bf16x8 e = *(const bf16x8*)&Sb[chl][lr_ * 8];
#pragma unroll
                for (int hi = 0; hi < 2; ++hi) {
                    int wv = (QKVS == 1) ? ((w + hi * 4 + 300) % 320) : (w + hi * 4);
                    int nw = wv / 40, kw = wv - nw * 40;
                    bf16* dst = vtb + ((size_t)((b_ * 64 + nh * 8 + nw) * 128 + ch)) * 480 + kh * 40 + kw;
                    bf16x4 hv;
#pragma unroll
                    for (int j = 0; j < 4; ++j) hv[j] = e[hi * 4 + j];
                    *(bf16x4*)dst = hv;
                }
            }
        }
    }
}

// ---------------------------------------------------------------------------
// K=128 GEMM for outlook attn logits: M=81 (stride 84), bf16 out.
// ---------------------------------------------------------------------------
__global__ __launch_bounds__(256) void k_gemm128_wa(const bf16* __restrict__ A,
                                                    const bf16* __restrict__ Wt,
                                                    const float* __restrict__ bias,
                                                    bf16* __restrict__ outA)
{
    __shared__ bf16 As[128][136];
    __shared__ bf16 Sb[64][88];

    const int bm = blockIdx.x * 128;
    const int t = threadIdx.x;
    const int lane = t & 63, wid = t >> 6;
    const int wm = (wid >> 1) * 64, wn = (wid & 1) * 64;
    const int lr = lane & 15, lg = lane >> 4;

    bf16x8 zrow;
#pragma unroll
    for (int j = 0; j < 8; ++j) zrow[j] = (bf16)0.f;

    bool okc[4];
    const bf16* wp = Wt + (size_t)(wn + lr) * 128 + lg * 8;
#pragma unroll
    for (int nf = 0; nf < 4; ++nf) okc[nf] = (wn + nf * 16 + lr) < 81;

    bf16x8 bwA[4], bwB[4];
#pragma unroll
    for (int nf = 0; nf < 4; ++nf)
        bwA[nf] = okc[nf] ? *(const bf16x8*)(wp + (size_t)(nf * 16) * 128) : zrow;

#pragma unroll
    for (int i = 0; i < 8; ++i) {
        int o = i * 256 + t;
        int row = o >> 4, cg = (o & 15) * 8;
        *(bf16x8*)&As[row][cg] = *(const bf16x8*)(A + (size_t)(bm + row) * 128 + cg);
    }
    __syncthreads();

    const f32x4 zero4 = {0.f, 0.f, 0.f, 0.f};
    f32x4 acc[4][4];
#pragma unroll
    for (int i = 0; i < 4; ++i)
#pragma unroll
        for (int j = 0; j < 4; ++j) acc[i][j] = zero4;

#pragma unroll
    for (int ks = 0; ks < 4; ++ks) {
        const bf16x8* cur = (ks & 1) ? bwB : bwA;
        bf16x8*       nxt = (ks & 1) ? bwA : bwB;
        if (ks < 3) {
#pragma unroll
            for (int nf = 0; nf < 4; ++nf)
                nxt[nf] = okc[nf] ? *(const bf16x8*)(wp + (size_t)(nf * 16) * 128 + (ks + 1) * 32) : zrow;
        }
        bf16x8 af[4];
#pragma unroll
        for (int mf = 0; mf < 4; ++mf)
            af[mf] = *(const bf16x8*)&As[wm + mf*16 + lr][ks*32 + lg*8];
        __builtin_amdgcn_s_setprio(1);
#pragma unroll
        for (int mf = 0; mf < 4; ++mf)
#pragma unroll
            for (int nf = 0; nf < 4; ++nf)
                acc[mf][nf] = MFMA_BF16(af[mf], cur[nf], acc[mf][nf]);
        __builtin_amdgcn_s_setprio(0);
    }

#pragma unroll
    for (int half = 0; half < 2; ++half) {
        __syncthreads();
        if ((wid >> 1) == half) {
#pragma unroll
            for (int nf = 0; nf < 4; ++nf) {
                int col = wn + nf * 16 + lr;
                if (col >= 84) continue;
                float bv = (col < 81) ? bias[col] : 0.f;
#pragma unroll
                for (int mf = 0; mf < 4; ++mf)
#pragma unroll
                    for (int r = 0; r < 4; ++r) {
                        float vv = (col < 81) ? (acc[mf][nf][r] + bv) : 0.f;
                        Sb[mf * 16 + lg * 4 + r][col] = (bf16)vv;
                    }
            }
        }
        __syncthreads();
#pragma unroll
        for (int i = 0; i < 6; ++i) {
            int o = i * 256 + t;
            if (o < 64 * 21) {
                int row = o / 21, cq = (o - row * 21) * 4;
                *(bf16x4*)(outA + (size_t)(bm + half * 64 + row) * cAS + cq) =
                    *(const bf16x4*)&Sb[row][cq];
            }
        }
    }
}

// ---------------------------------------------------------------------------
// Generic k-loop GEMM, M=128, A bf16 (unchanged).
// ---------------------------------------------------------------------------
template<bool OUTBF, bool RELU, bool RES, bool POS>
__global__ __launch_bounds__(256) void k_gemm_res(const bf16* __restrict__ A,
                                                  const bf16* __restrict__ Wt,
                                                  const float* __restrict__ bias,
                                                  const float* __restrict__ res,
                                                  float* __restrict__ outF,
                                                  bf16* __restrict__ outB,
                                                  int K,
                                                  const float* __restrict__ ytab,
                                                  const float* __restrict__ xtab)
{
    __shared__ bf16 As[128][40];
    __shared__ bf16 Bs[128][40];
    __shared__ float Sf[64][136];

    const int bm = blockIdx.x * 128;
    const int t = threadIdx.x;
    const int lane = t & 63, wid = t >> 6;
    const int wm = (wid >> 1) * 64, wn = (wid & 1) * 64;
    const int lr = lane & 15, lg = lane >> 4;

    const f32x4 zero4 = {0.f, 0.f, 0.f, 0.f};
    f32x4 acc[4][4];
#pragma unroll
    for (int i = 0; i < 4; ++i)
#pragma unroll
        for (int j = 0; j < 4; ++j) acc[i][j] = zero4;

    for (int k0 = 0; k0 < K; k0 += 32) {
#pragma unroll
        for (int i = 0; i < 2; ++i) {
            int idx = t + i * 256;
            int row = idx >> 2, kg = (idx & 3) * 8;
            *(bf16x8*)&As[row][kg] = *(const bf16x8*)(A + (size_t)(bm + row) * K + k0 + kg);
            *(bf16x8*)&Bs[row][kg] = *(const bf16x8*)(Wt + (size_t)row * K + k0 + kg);
        }
        __syncthreads();
        bf16x8 af[4], bf[4];
#pragma unroll
        for (int mf = 0; mf < 4; ++mf)
            af[mf] = *(const bf16x8*)&As[wm + mf*16 + lr][lg * 8];
#pragma unroll
        for (int nf = 0; nf < 4; ++nf)
            bf[nf] = *(const bf16x8*)&Bs[wn + nf*16 + lr][lg * 8];
        __builtin_amdgcn_s_setprio(1);
#pragma unroll
        for (int mf = 0; mf < 4; ++mf)
#pragma unroll
            for (int nf = 0; nf < 4; ++nf)
                acc[mf][nf] = MFMA_BF16(af[mf], bf[nf], acc[mf][nf]);
        __builtin_amdgcn_s_setprio(0);
        __syncthreads();
    }

    if (OUTBF) {
        bf16 (*Sb)[136] = (bf16(*)[136])Sf;
#pragma unroll
        for (int nf = 0; nf < 4; ++nf) {
            int col = wn + nf * 16 + lr;
            float bv = bias ? bias[col] : 0.f;
#pragma unroll
            for (int mf = 0; mf < 4; ++mf)
#pragma unroll
                for (int r = 0; r < 4; ++r) {
                    float vv = acc[mf][nf][r] + bv;
                    if (RELU) vv = fmaxf(vv, 0.f);
                    Sb[wm + mf * 16 + lg * 4 + r][col] = (bf16)vv;
                }
        }
        __syncthreads();
#pragma unroll
        for (int i = 0; i < 8; ++i) {
            int o = i * 256 + t;
            int row = o >> 4, cg = (o & 15) * 8;
            *(bf16x8*)(outB + (size_t)(bm + row) * 128 + cg) = *(const bf16x8*)&Sb[row][cg];
        }
    } else {
        for (int half = 0; half < 2; ++half) {
            __syncthreads();
            if ((wid >> 1) == half) {
#pragma unroll
                for (int nf = 0; nf < 4; ++nf) {
                    int col = wn + nf * 16 + lr;
                    float bv = bias ? bias[col] : 0.f;
#pragma unroll
                    for (int mf = 0; mf < 4; ++mf)
#pragma unroll
                        for (int r = 0; r < 4; ++r)
                            Sf[mf * 16 + lg * 4 + r][col] = acc[mf][nf][r] + bv;
                }
            }
            __syncthreads();
#pragma unroll
            for (int i = 0; i < 8; ++i) {
                int o = i * 256 + t;
                int row = o >> 5, cq = (o & 31) * 4;
                int grow = bm + half * 64 + row;
                float4 v = *(const float4*)&Sf[row][cq];
                if (POS) {
                    int hw = grow % cNPIX;
                    int h = hw / cW, w = hw - (hw / cW) * cW;
                    float4 p = (cq < 64) ? *(const float4*)(ytab + (h << 6) + cq)
                                         : *(const float4*)(xtab + (w << 6) + cq - 64);
                    v.x += p.x; v.y += p.y; v.z += p.z; v.w += p.w;
                }
                if (RES) {
                    float4 rr = *(const float4*)(res + (size_t)grow * 128 + cq);
                    v.x += rr.x; v.y += rr.y; v.z += rr.z; v.w += rr.w;
                }
                *(float4*)(outF + (size_t)grow * 128 + cq) = v;
            }
        }
    }
}

// ---------------------------------------------------------------------------
// Outlook fused gather (bf16 logits, stride 84).
// ---------------------------------------------------------------------------
__global__ __launch_bounds__(256) void k_olk_gather(const bf16* __restrict__ v,
                                                    const bf16* __restrict__ attn,
                                                    bf16* __restrict__ y)
{
    __shared__ float pr[16][84];
    __shared__ float coef[16][26];

    const int t  = threadIdx.x;
    const int px = t >> 4;
    const int j  = t & 15;
    const int pix = blockIdx.x * 16 + px;
    const int b  = pix / cNPIX;
    const int hw = pix % cNPIX;
    const int h = hw / cW, w = hw % cW;

    if (j < 9) {
        const int p  = j;
        const int pi = p / 3, pj = p - pi * 3;
        const int hh = h + 1 - pi, ww = w + 1 - pj;
        float prv[9];
        if ((unsigned)hh < (unsigned)cH && (unsigned)ww < (unsigned)cW) {
            const size_t row = (size_t)(b * cNPIX + hh * cW + ww);
            const bf16* arow = attn + row * cAS + p * 9;
            float lg[9];
            float m = 0.f;
#pragma unroll
            for (int q = 0; q < 9; ++q) { lg[q] = (float)arow[q]; m = fmaxf(m, lg[q]); }
            float se = 0.f;
#pragma unroll
            for (int q = 0; q < 9; ++q) { prv[q] = __expf(lg[q] - m); se += prv[q]; }
            float inv = 1.f / (se + __expf(-m));
#pragma unroll
            for (int q = 0; q < 9; ++q) prv[q] *= inv;
        } else {
#pragma unroll
            for (int q = 0; q < 9; ++q) prv[q] = 0.f;
        }
#pragma unroll
        for (int q = 0; q < 9; ++q) pr[px][p * 9 + q] = prv[q];
    }
    __syncthreads();

    for (int d = j; d < 25; d += 16) {
        const int a  = d / 5, bb = d - a * 5;
        float s = 0.f;
#pragma unroll
        for (int pi = 0; pi < 3; ++pi) {
            const int qi = pi + a - 2;
            if ((unsigned)qi >= 3u) continue;
#pragma unroll
            for (int pj = 0; pj < 3; ++pj) {
                const int qj = pj + bb - 2;
                if ((unsigned)qj >= 3u) continue;
                s += pr[px][(pi * 3 + pj) * 9 + qi * 3 + qj];
            }
        }
        coef[px][d] = s;
    }
    __syncthreads();

    float acc[8] = {};
    const size_t bbase = (size_t)b * cNPIX;
#pragma unroll
    for (int a = 0; a < 5; ++a) {
        const int sh = h + a - 2;
        if ((unsigned)sh >= (unsigned)cH) continue;
#pragma unroll
        for (int bb = 0; bb < 5; ++bb) {
            const int sw = w + bb - 2;
            if ((unsigned)sw >= (unsigned)cW) continue;
            const float cf = coef[px][a * 5 + bb];
            const bf16x8 v8 = *(const bf16x8*)(v + ((bbase + (size_t)sh * cW + sw) * 128 + j * 8));
#pragma unroll
            for (int e = 0; e < 8; ++e) acc[e] = fmaf(cf, (float)v8[e], acc[e]);
        }
    }
    bf16x8 o8;
#pragma unroll
    for (int e = 0; e < 8; ++e) o8[e] = (bf16)acc[e];
    *(bf16x8*)(y + (size_t)pix * 128 + j * 8) = o8;
}

// ---------------------------------------------------------------------------
// Depthwise 3x3 + bias + exact GELU, row-sliding, NHWC 512 ch.
// ---------------------------------------------------------------------------
__global__ __launch_bounds__(256) void k_dwconv_gelu(const bf16* __restrict__ h1,
                                                     const float* __restrict__ dwt,
                                                     const float* __restrict__ bdw,
                                                     bf16* __restrict__ h2)
{
    const int t   = threadIdx.x;
    const int c2  = t * 2;
    const int blk = blockIdx.x;
    const int row = blk >> 3;
    const int seg = blk & 7;
    const int bb  = row / cH, h = row % cH;
    const int w0  = seg * 40;

    float2 wgt[9];
#pragma unroll
    for (int k = 0; k < 9; ++k)
        wgt[k] = *(const float2*)(dwt + k * 512 + c2);
    const float2 bias = *(const float2*)(bdw + c2);

    const size_t base = (size_t)bb * cNPIX;

    auto ld = [&](int hh, int ww) -> float2 {
        float2 r; r.x = 0.f; r.y = 0.f;
        if ((unsigned)hh < (unsigned)cH && (unsigned)ww < (unsigned)cW) {
            unsigned u = *(const unsigned*)(h1 + ((base + (size_t)hh * cW + ww) * 512 + c2));
            r.x = __uint_as_float(u << 16);
            r.y = __uint_as_float(u & 0xffff0000u);
        }
        return r;
    };

    float2 cm[3], c0[3], cp[3];
#pragma unroll
    for (int r = 0; r < 3; ++r) {
        cm[r] = ld(h + r - 1, w0 - 1);
        c0[r] = ld(h + r - 1, w0);
    }

    for (int j = 0; j < 40; ++j) {
#pragma unroll
        for (int r = 0; r < 3; ++r) cp[r] = ld(h + r - 1, w0 + j + 1);
        float a0 = bias.x, a1 = bias.y;
#pragma unroll
        for (int r = 0; r < 3; ++r) {
            a0 = fmaf(cm[r].x, wgt[r * 3 + 0].x, a0);
            a1 = fmaf(cm[r].y, wgt[r * 3 + 0].y, a1);
            a0 = fmaf(c0[r].x, wgt[r * 3 + 1].x, a0);
            a1 = fmaf(c0[r].y, wgt[r * 3 + 1].y, a1);
            a0 = fmaf(cp[r].x, wgt[r * 3 + 2].x, a0);
            a1 = fmaf(cp[r].y, wgt[r * 3 + 2].y, a1);
        }
        a0 = 0.5f * a0 * (1.f + erff(a0 * 0.70710678118654752f));
        a1 = 0.5f * a1 * (1.f + erff(a1 * 0.70710678118654752f));
        union { bf16 hh[2]; unsigned int u; } o2;
        o2.hh[0] = (bf16)a0;
        o2.hh[1] = (bf16)a1;
        *(unsigned int*)(h2 + (base + (size_t)h * cW + w0 + j) * 512 + c2) = o2.u;
#pragma unroll
        for (int r = 0; r < 3; ++r) { cm[r] = c0[r]; c0[r] = cp[r]; }
    }
}

// ---------------------------------------------------------------------------
// Window attention, MFMA flash-style (unchanged).
// ---------------------------------------------------------------------------
template<bool SHIFT>
__global__ __launch_bounds__(256) void k_win_attn(const bf16* __restrict__ qk,
                                                  const bf16* __restrict__ vt,
                                                  bf16* __restrict__ out)
{
    __shared__ bf16 Ks[2][32][136];
    __shared__ bf16 Vs[2][128][40];
    __shared__ bf16 Ps[4][16][40];

    const int t = threadIdx.x, lane = t & 63, wid = t >> 6;
    const int lr = lane & 15, lg = lane >> 4;
    const int wb = blockIdx.x;
    const int b  = wb >> 6, win = wb & 63;
    const int nh = win >> 3, nw = win & 7;
    const int qbase = blockIdx.y * 64 + wid * 16;

    const float SCALE   = 0.088388347648318447f;
    const float MASKRAW = 100.f / 0.088388347648318447f;

    auto tokOf = [&](int p) {
        int ph = nh * 12 + p / 40;
        int pw = nw * 40 + (p % 40);
        if (SHIFT) {
            ph += 6;  if (ph >= cH) ph -= cH;
            pw += 20; if (pw >= cW) pw -= cW;
        }
        return b * cNPIX + ph * cW + pw;
    };
    auto labOf = [&](int p) {
        int ph = nh * 12 + p / 40;
        int pw = nw * 40 + (p % 40);
        int rh = ph < 84 ? 0 : (ph < 90 ? 1 : 2);
        int rc = pw < 280 ? 0 : (pw < 300 ? 1 : 2);
        return rh * 3 + rc;
    };

    int qp = min(qbase + lr, 479);
    const bf16* qptr = qk + (size_t)tokOf(qp) * 256;
    bf16x8 qf[4];
#pragma unroll
    for (int c = 0; c < 4; ++c)
        qf[c] = *(const bf16x8*)(qptr + c * 32 + lg * 8);

    int labq[4];
    if (SHIFT) {
#pragma unroll
        for (int r = 0; r < 4; ++r) labq[r] = labOf(min(qbase + lg * 4 + r, 479));
    }

    const bf16* vbase = vt + (size_t)wb * 128 * 480;
    auto loadK = [&](int kt, int i) {
        int idx = t + i * 256;
        int key = idx >> 4, cg = (idx & 15) * 8;
        return *(const bf16x8*)(qk + (size_t)tokOf(kt * 32 + key) * 256 + 128 + cg);
    };
    auto loadV = [&](int kt, int i) {
        int idx = t + i * 256;
        int ch = idx >> 2, kq = (idx & 3) * 8;
        return *(const bf16x8*)(vbase + (size_t)ch * 480 + kt * 32 + kq);
    };

    bf16x8 kreg0 = loadK(0, 0), kreg1 = loadK(0, 1);
    bf16x8 vreg0 = loadV(0, 0), vreg1 = loadV(0, 1);

    const f32x4 zero4 = {0.f, 0.f, 0.f, 0.f};
    float m_run[4] = {0.f, 0.f, 0.f, 0.f};
    float mguard = 8.f;
    f32x4 l4 = zero4;
    f32x4 o[8];
#pragma unroll
    for (int nf = 0; nf < 8; ++nf) o[nf] = zero4;

    bf16x8 ones8;
#pragma unroll
    for (int j = 0; j < 8; ++j) ones8[j] = (bf16)1.f;

    int buf = 0;
    for (int kt = 0; kt < 15; ++kt) {
        {
            int i0 = t, i1 = t + 256;
            *(bf16x8*)&Ks[buf][i0 >> 4][(i0 & 15) * 8] = kreg0;
            *(bf16x8*)&Ks[buf][i1 >> 4][(i1 & 15) * 8] = kreg1;
            *(bf16x8*)&Vs[buf][i0 >> 2][(i0 & 3) * 8] = vreg0;
            *(bf16x8*)&Vs[buf][i1 >> 2][(i1 & 3) * 8] = vreg1;
        }
        if (kt + 1 < 15) {
            kreg0 = loadK(kt + 1, 0); kreg1 = loadK(kt + 1, 1);
            vreg0 = loadV(kt + 1, 0); vreg1 = loadV(kt + 1, 1);
        }
        __syncthreads();

        f32x4 s0 = zero4, s1 = zero4;
        __builtin_amdgcn_s_setprio(1);
#pragma unroll
        for (int c = 0; c < 4; ++c) {
            bf16x8 kf0 = *(const bf16x8*)&Ks[buf][lr][c * 32 + lg * 8];
            bf16x8 kf1 = *(const bf16x8*)&Ks[buf][16 + lr][c * 32 + lg * 8];
            s0 = MFMA_BF16(qf[c], kf0, s0);
            s1 = MFMA_BF16(qf[c], kf1, s1);
        }
        __builtin_amdgcn_s_setprio(0);

        if (SHIFT) {
            int lab0 = labOf(kt * 32 + lr);
            int lab1 = labOf(kt * 32 + 16 + lr);
#pragma unroll
            for (int r = 0; r < 4; ++r) {
                if (labq[r] != lab0) s0[r] -= MASKRAW;
                if (labq[r] != lab1) s1[r] -= MASKRAW;
            }
        }

        float tm = fmaxf(fmaxf(fmaxf(s0[0], s0[1]), fmaxf(s0[2], s0[3])),
                         fmaxf(fmaxf(s1[0], s1[1]), fmaxf(s1[2], s1[3])));
#pragma unroll
        for (int off = 1; off < 16; off <<= 1) tm = fmaxf(tm, __shfl_xor(tm, off));
        if (tm * SCALE > mguard) {
#pragma unroll
            for (int r = 0; r < 4; ++r) {
                float mx = fmaxf(s0[r], s1[r]);
#pragma unroll
                for (int off = 1; off < 16; off <<= 1) mx = fmaxf(mx, __shfl_xor(mx, off));
                float nm = fmaxf(m_run[r], mx * SCALE);
                float sc = __expf(m_run[r] - nm);
#pragma unroll
                for (int nf = 0; nf < 8; ++nf) o[nf][r] *= sc;
                l4[r] *= sc;
                m_run[r] = nm;
            }
            mguard = fminf(fminf(m_run[0], m_run[1]), fminf(m_run[2], m_run[3])) + 8.f;
        }

#pragma unroll
        for (int r = 0; r < 4; ++r) {
            float p0 = __expf(fmaf(s0[r], SCALE, -m_run[r]));
            float p1 = __expf(fmaf(s1[r], SCALE, -m_run[r]));
            Ps[wid][lg * 4 + r][lr]      = (bf16)p0;
            Ps[wid][lg * 4 + r][16 + lr] = (bf16)p1;
        }

        bf16x8 pa = *(const bf16x8*)&Ps[wid][lr][lg * 8];
        __builtin_amdgcn_s_setprio(1);
        l4 = MFMA_BF16(pa, ones8, l4);
#pragma unroll
        for (int nf = 0; nf < 8; ++nf) {
            bf16x8 bv = *(const bf16x8*)&Vs[buf][nf * 16 + lr][lg * 8];
            o[nf] = MFMA_BF16(pa, bv, o[nf]);
        }
        __builtin_amdgcn_s_setprio(0);
        __syncthreads();
        buf ^= 1;
    }

#pragma unroll
    for (int r = 0; r < 4; ++r) {
        int qrow = qbase + lg * 4 + r;
        if (qrow >= 480) continue;
        float inv = 1.f / (l4[r] + __expf(-m_run[r]));
        size_t ooff = (size_t)tokOf(qrow) * 128;
#pragma unroll
        for (int nf = 0; nf < 8; ++nf)
            out[ooff + nf * 16 + lr] = (bf16)(o[nf][r] * inv);
    }
}

// ---------------------------------------------------------------------------
// Host launcher
// ---------------------------------------------------------------------------
extern "C" void kernel_launch(void* const* d_in, const int* in_sizes, int n_in,
                              void* d_out, int out_size, void* d_ws, size_t ws_size,
                              hipStream_t stream)
{
    (void)in_sizes; (void)n_in; (void)out_size; (void)ws_size;

    const float* X = (const float*)d_in[0];

    char* ws = (char*)d_ws;
    float* f    = (float*)ws;                                 ws += (size_t)cNTOK * 128 * 4;
    bf16*  xnb  = (bf16*)ws;                                  ws += (size_t)cNTOK * 128 * 2;
    bf16*  bufA = (bf16*)ws;                                  ws += (size_t)cNTOK * 512 * 2;
    bf16*  bufB = (bf16*)ws;                                  ws += (size_t)cNTOK * 512 * 2;
    bf16*  wts  = (bf16*)ws;

    size_t wo_off = 0;
    auto nextw = [&](int K, int M) { bf16* p = wts + wo_off; wo_off += (size_t)K * M; return p; };
    bf16* agg_w1t = nextw(256, 128);
    bf16* agg_w2t = nextw(128, 128);
    bf16* ol_wvt  = nextw(128, 128);
    bf16* ol_wat  = nextw(128, 81);
    bf16* ol_wot  = nextw(128, 128);
    bf16* f1_w1t  = nextw(128, 512);
    bf16* f1_w2t  = nextw(512, 128);
    bf16* w_qkvt  = nextw(128, 384);
    bf16* w_wot   = nextw(128, 128);
    bf16* f2_w1t  = nextw(128, 512);
    bf16* f2_w2t  = nextw(512, 128);
    bf16* s_qkvt  = nextw(128, 384);
    bf16* s_wot   = nextw(128, 128);
    bf16* f3_w1t  = nextw(128, 512);
    bf16* f3_w2t  = nextw(512, 128);
    float* dwt1 = (float*)(wts + wo_off);
    float* dwt2 = dwt1 + 512 * 9;
    float* dwt3 = dwt2 + 512 * 9;
    float* ytab = dwt3 + 512 * 9;
    float* xtab = ytab + 96 * 64;

    WJobs jobs;
    int ji = 0;
    auto addj = [&](int src_idx, bf16* dst, int K, int M) {
        jobs.j[ji++] = WJob{(const float*)d_in[src_idx], dst, K, M};
    };
    addj(1,  agg_w1t, 256, 128);
    addj(3,  agg_w2t, 128, 128);
    addj(7,  ol_wvt,  128, 128);
    addj(8,  ol_wat,  128, 81);
    addj(10, ol_wot,  128, 128);
    addj(14, f1_w1t,  128, 512);
    addj(18, f1_w2t,  512, 128);
    addj(22, w_qkvt,           128, 128);
    addj(23, w_qkvt + 128*128, 128, 128);
    addj(24, w_qkvt + 256*128, 128, 128);
    addj(25, w_wot,   128, 128);
    addj(29, f2_w1t,  128, 512);
    addj(33, f2_w2t,  512, 128);
    addj(37, s_qkvt,           128, 128);
    addj(38, s_qkvt + 128*128, 128, 128);
    addj(39, s_qkvt + 256*128, 128, 128);
    addj(40, s_wot,   128, 128);
    addj(44, f3_w1t,  128, 512);
    addj(48, f3_w2t,  512, 128);
    k_wt<<<dim3(16, 16, 19), dim3(32, 8), 0, stream>>>(jobs);
    k_dwt<<<3, 256, 0, stream>>>((const float*)d_in[16], (const float*)d_in[31],
                                 (const float*)d_in[46], dwt1, dwt2, dwt3);
    k_postab<<<80, 256, 0, stream>>>(ytab, xtab);

    const int nTT = cNTOK / 128;   // 480 token tiles

    // ---- input transpose + aggregation MLP ----
    k_chw2hwc<<<dim3(cNPIX / 32, 256 / 32, cB), dim3(32, 8), 0, stream>>>(X, bufA);
    k_gemm_res<true, true, false, false><<<nTT, 256, 0, stream>>>(
        bufA, agg_w1t, (const float*)d_in[2], nullptr, nullptr, bufB, 256, nullptr, nullptr);
    k_gemm_res<false, false, false, false><<<nTT, 256, 0, stream>>>(
        bufB, agg_w2t, (const float*)d_in[4], nullptr, f, nullptr, 128, nullptr, nullptr);

    // ---- outlook attention ----
    {
        bf16*  vb   = bufA;
        bf16*  gout = bufA + (size_t)cNTOK * 128;
        bf16*  atn  = bufB;
        k_ln<<<cNTOK / 4, 256, 0, stream>>>(f, (const float*)d_in[5], (const float*)d_in[6], xnb);
        k_gemm128<-1><<<nTT, 256, 0, stream>>>(xnb, ol_wvt, nullptr, vb, 128, nullptr);
        k_gemm128_wa<<<nTT, 256, 0, stream>>>(xnb, ol_wat, (const float*)d_in[9], atn);
        k_olk_gather<<<cNTOK / 16, 256, 0, stream>>>(vb, atn, gout);
        k_gemm_res<false, false, true, false><<<nTT, 256, 0, stream>>>(
            gout, ol_wot, (const float*)d_in[11], f, f, nullptr, 128, nullptr, nullptr);
    }

    // ---- conv FFN ----
    auto run_ffn = [&](int base, bf16* w1t, bf16* w2t, float* dwt, bool pos) {
        k_ln<<<cNTOK / 4, 256, 0, stream>>>(f, (const float*)d_in[base], (const float*)d_in[base + 1], xnb);
        k_gemm128<-1><<<nTT * 4, 256, 0, stream>>>(
            xnb, w1t, (const float*)d_in[base + 3], bufA, 512, nullptr);
        k_dwconv_gelu<<<cB * cH * 8, 256, 0, stream>>>(
            bufA, dwt, (const float*)d_in[base + 5], bufB);
        if (pos)
            k_gemm_res<false, false, true, true><<<nTT, 256, 0, stream>>>(
                bufB, w2t, (const float*)d_in[base + 7], f, f, nullptr, 512, ytab, xtab);
        else
            k_gemm_res<false, false, true, false><<<nTT, 256, 0, stream>>>(
                bufB, w2t, (const float*)d_in[base + 7], f, f, nullptr, 512, nullptr, nullptr);
    };

    // ---- window attention ----
    auto run_win = [&](int base, bf16* qkvt, bf16* wot, bool shift) {
        bf16* qkb = bufA;
        bf16* vtb = bufA + (size_t)cNTOK * 256;
        bf16* ao  = bufB;
        k_ln<<<cNTOK / 4, 256, 0, stream>>>(f, (const float*)d_in[base], (const float*)d_in[base + 1], xnb);
        if (shift)
            k_gemm128<1><<<nTT * 3, 256, 0, stream>>>(xnb, qkvt, nullptr, qkb, 384, vtb);
        else
            k_gemm128<0><<<nTT * 3, 256, 0, stream>>>(xnb, qkvt, nullptr, qkb, 384, vtb);
        if (shift) k_win_attn<true ><<<dim3(128, 8), 256, 0, stream>>>(qkb, vtb, ao);
        else       k_win_attn<false><<<dim3(128, 8), 256, 0, stream>>>(qkb, vtb, ao);
        k_gemm_res<false, false, true, false><<<nTT, 256, 0, stream>>>(
            ao, wot, (const float*)d_in[base + 6], f, f, nullptr, 128, nullptr, nullptr);
    };

    run_ffn(12, f1_w1t, f1_w2t, dwt1, true);                   // f1 (+pos fused)
    run_win(20, w_qkvt, w_wot, false);                         // w
    run_ffn(27, f2_w1t, f2_w2t, dwt2, false);                  // f2
    run_win(35, s_qkvt, s_wot, true);                          // s (shifted)
    run_ffn(42, f3_w1t, f3_w2t, dwt3, false);                  // f3

    k_hwc2chw<<<dim3(cNPIX / 32, cC / 32, cB), dim3(32, 8), 0, stream>>>(f, (float*)d_out);
}

// Round 9
// 627.091 us; speedup vs baseline: 6.2165x; 1.0816x over previous
//
#include <hip/hip_runtime.h>

typedef __bf16 bf16;
typedef __bf16 bf16x8 __attribute__((ext_vector_type(8)));
typedef __bf16 bf16x4 __attribute__((ext_vector_type(4)));
typedef float  f32x4  __attribute__((ext_vector_type(4)));

#define MFMA_BF16(a, b, c) __builtin_amdgcn_mfma_f32_16x16x32_bf16(a, b, c, 0, 0, 0)

constexpr int cB    = 2;
constexpr int cH    = 96;
constexpr int cW    = 320;
constexpr int cC    = 128;
constexpr int cNPIX = cH * cW;          // 30720
constexpr int cNTOK = cB * cNPIX;       // 61440
constexpr int cAS   = 84;               // padded attn-logit stride (81 -> 84)

// ---------------------------------------------------------------------------
// Weight transpose+convert: fp32 W (K x M) -> bf16 Wt (M x K)
// ---------------------------------------------------------------------------
struct WJob  { const float* src; bf16* dst; int K; int M; };
struct WJobs { WJob j[19]; };

__global__ __launch_bounds__(256) void k_wt(WJobs jobs)
{
    __shared__ float tile[32][33];
    const WJob jb = jobs.j[blockIdx.z];
    int k0 = blockIdx.y * 32, m0 = blockIdx.x * 32;
    if (k0 >= jb.K || m0 >= jb.M) return;
    int tx = threadIdx.x, ty = threadIdx.y;
#pragma unroll
    for (int i = 0; i < 32; i += 8) {
        int kk = k0 + ty + i, mm = m0 + tx;
        tile[ty + i][tx] = (kk < jb.K && mm < jb.M) ? jb.src[(size_t)kk * jb.M + mm] : 0.f;
    }
    __syncthreads();
#pragma unroll
    for (int i = 0; i < 32; i += 8) {
        int mm = m0 + ty + i, kk = k0 + tx;
        if (mm < jb.M && kk < jb.K)
            jb.dst[(size_t)mm * jb.K + kk] = (bf16)tile[tx][ty + i];
    }
}

__global__ __launch_bounds__(256) void k_dwt(const float* s0, const float* s1, const float* s2,
                                             float* d0, float* d1, float* d2)
{
    const float* s = blockIdx.x == 0 ? s0 : (blockIdx.x == 1 ? s1 : s2);
    float*       d = blockIdx.x == 0 ? d0 : (blockIdx.x == 1 ? d1 : d2);
    for (int i = threadIdx.x; i < 512 * 9; i += 256) {
        int c = i / 9, tap = i - c * 9;
        d[tap * 512 + c] = s[i];
    }
}

__global__ __launch_bounds__(256) void k_postab(float* __restrict__ yt, float* __restrict__ xt)
{
    int i = blockIdx.x * 256 + threadIdx.x;
    const float TWO_PI = 6.283185307179586f;
    const float KSC = -9.210340371976184f / 32.f;
    if (i < 96 * 64) {
        int h = i >> 6, c = i & 63;
        float p = (float)(h + 1) * (TWO_PI / (96.f + 1e-6f));
        float val = p * expf((float)(c >> 1) * KSC);
        yt[i] = (c & 1) ? cosf(val) : sinf(val);
    }
    if (i < 320 * 64) {
        int w = i >> 6, c = i & 63;
        float p = (float)(w + 1) * (TWO_PI / (320.f + 1e-6f));
        float val = p * expf((float)(c >> 1) * KSC);
        xt[i] = (c & 1) ? cosf(val) : sinf(val);
    }
}

// ---------------------------------------------------------------------------
// Transposes
// ---------------------------------------------------------------------------
__global__ __launch_bounds__(256) void k_chw2hwc(const float* __restrict__ in,
                                                 bf16* __restrict__ out)
{
    __shared__ float tile[32][33];
    const int Cc = 256;
    int s0 = blockIdx.x * 32;
    int c0 = blockIdx.y * 32;
    int b  = blockIdx.z;
    const float* ip = in  + (size_t)b * Cc * cNPIX;
    bf16*        op = out + (size_t)b * cNPIX * Cc;
    int tx = threadIdx.x, ty = threadIdx.y;
#pragma unroll
    for (int i = 0; i < 32; i += 8)
        tile[ty + i][tx] = ip[(size_t)(c0 + ty + i) * cNPIX + s0 + tx];
    __syncthreads();
#pragma unroll
    for (int i = 0; i < 32; i += 8)
        op[(size_t)(s0 + ty + i) * Cc + c0 + tx] = (bf16)tile[tx][ty + i];
}

__global__ __launch_bounds__(256) void k_hwc2chw(const float* __restrict__ in,
                                                 float* __restrict__ out)
{
    __shared__ float tile[32][33];
    int s0 = blockIdx.x * 32;
    int c0 = blockIdx.y * 32;
    int b  = blockIdx.z;
    const float* ip = in  + (size_t)b * cNPIX * cC;
    float*       op = out + (size_t)b * cC * cNPIX;
    int tx = threadIdx.x, ty = threadIdx.y;
#pragma unroll
    for (int i = 0; i < 32; i += 8)
        tile[ty + i][tx] = ip[(size_t)(s0 + ty + i) * cC + c0 + tx];
    __syncthreads();
#pragma unroll
    for (int i = 0; i < 32; i += 8)
        op[(size_t)(c0 + ty + i) * cNPIX + s0 + tx] = tile[tx][ty + i];
}

// ---------------------------------------------------------------------------
// K=128 single-shot GEMM, A bf16 [tok][128]; W frags global->VGPR dbuf.
// QKVS: -1 plain bf16 out [tok][M];
//       0/1 QKV: bn==0 -> q[tok][128]; bn==128 -> ks[wb*480+key][128]
//       (row-permuted, shift folded); bn==256 -> vt[wb][ch][key] scatter.
// ---------------------------------------------------------------------------
template<int QKVS>
__global__ __launch_bounds__(256) void k_gemm128(const bf16* __restrict__ A,
                                                 const bf16* __restrict__ Wt,
                                                 const float* __restrict__ bias,
                                                 bf16* __restrict__ outB, int M,
                                                 bf16* __restrict__ vtb,
                                                 bf16* __restrict__ ksb)
{
    __shared__ bf16 As[128][136];
    __shared__ bf16 Sb[64][136];

    const int NS = M >> 7;
    const int l  = blockIdx.x;
    const int r8 = l % (8 * NS);
    const int qq = l / (8 * NS);
    const int bm = (qq * 8 + (r8 & 7)) * 128;   // token tile
    const int bn = (r8 >> 3) * 128;             // col tile

    const int t = threadIdx.x;
    const int lane = t & 63, wid = t >> 6;
    const int wm = (wid >> 1) * 64, wn = (wid & 1) * 64;
    const int lr = lane & 15, lg = lane >> 4;

    // ---- ks=0 W fragment loads (L2; overlap A staging) ----
    const bf16* wp = Wt + (size_t)(bn + wn + lr) * 128 + lg * 8;
    bf16x8 bwA[4], bwB[4];
#pragma unroll
    for (int nf = 0; nf < 4; ++nf)
        bwA[nf] = *(const bf16x8*)(wp + (size_t)(nf * 16) * 128);

    // ---- A staging: fully coalesced ----
#pragma unroll
    for (int i = 0; i < 8; ++i) {
        int o = i * 256 + t;
        int row = o >> 4, cg = (o & 15) * 8;
        *(bf16x8*)&As[row][cg] = *(const bf16x8*)(A + (size_t)(bm + row) * 128 + cg);
    }
    __syncthreads();

    const f32x4 zero4 = {0.f, 0.f, 0.f, 0.f};
    f32x4 acc[4][4];
#pragma unroll
    for (int i = 0; i < 4; ++i)
#pragma unroll
        for (int j = 0; j < 4; ++j) acc[i][j] = zero4;

#pragma unroll
    for (int ks = 0; ks < 4; ++ks) {
        const bf16x8* cur = (ks & 1) ? bwB : bwA;
        bf16x8*       nxt = (ks & 1) ? bwA : bwB;
        if (ks < 3) {
#pragma unroll
            for (int nf = 0; nf < 4; ++nf)
                nxt[nf] = *(const bf16x8*)(wp + (size_t)(nf * 16) * 128 + (ks + 1) * 32);
        }
        bf16x8 af[4];
#pragma unroll
        for (int mf = 0; mf < 4; ++mf)
            af[mf] = *(const bf16x8*)&As[wm + mf*16 + lr][ks*32 + lg*8];
        __builtin_amdgcn_s_setprio(1);
#pragma unroll
        for (int mf = 0; mf < 4; ++mf)
#pragma unroll
            for (int nf = 0; nf < 4; ++nf)
                acc[mf][nf] = MFMA_BF16(af[mf], cur[nf], acc[mf][nf]);
        __builtin_amdgcn_s_setprio(0);
    }

    // ---- epilogue ----
    const bool vpart = (QKVS >= 0) && (bn == 256);
    const bool kpart = (QKVS >= 0) && (bn == 128);
    if (!vpart) {
#pragma unroll
        for (int half = 0; half < 2; ++half) {
            __syncthreads();
            if ((wid >> 1) == half) {
#pragma unroll
                for (int nf = 0; nf < 4; ++nf) {
                    int col = wn + nf * 16 + lr;
                    float bv = bias ? bias[bn + col] : 0.f;
#pragma unroll
                    for (int mf = 0; mf < 4; ++mf)
#pragma unroll
                        for (int r = 0; r < 4; ++r)
                            Sb[mf * 16 + lg * 4 + r][col] = (bf16)(acc[mf][nf][r] + bv);
                }
            }
            __syncthreads();
            if (!kpart) {
                const int ldo = (QKVS >= 0) ? 128 : M;   // Q part: ldo 128, bn==0
#pragma unroll
                for (int i = 0; i < 4; ++i) {
                    int o = i * 256 + t;
                    int row = o >> 4, cg = (o & 15) * 8;
                    *(bf16x8*)(outB + (size_t)(bm + half * 64 + row) * ldo + bn + cg) =
                        *(const bf16x8*)&Sb[row][cg];
                }
            } else {
                // K: permuted-row store to ks[(b*64+win)*480 + key][128]
#pragma unroll
                for (int i = 0; i < 4; ++i) {
                    int o = i * 256 + t;
                    int row = o >> 4, cg = (o & 15) * 8;
                    int gt = bm + half * 64 + row;
                    int b_ = gt / cNPIX, hw = gt - b_ * cNPIX;
                    int h = hw / cW, w = hw - (hw / cW) * cW;
                    int h0 = (QKVS == 1) ? ((h + 90) % 96)  : h;
                    int w0 = (QKVS == 1) ? ((w + 300) % 320) : w;
                    int nh = h0 / 12, kh = h0 - nh * 12;
                    int nw = w0 / 40, kw = w0 - nw * 40;
                    size_t krow = (size_t)((b_ * 64 + nh * 8 + nw) * 480 + kh * 40 + kw);
                    *(bf16x8*)(ksb + krow * 128 + cg) = *(const bf16x8*)&Sb[row][cg];
                }
            }
        }
    } else {
        // V scatter: vt[((b*64+win)*128+ch)*480 + key]; stage transposed.
        const int lr_ = t & 15, cg_ = t >> 4;
        const int gt = bm + lr_ * 8;
        const int b_ = gt / cNPIX, hw = gt % cNPIX;
        const int h = hw / cW, w = hw % cW;
        const int h0 = (QKVS == 1) ? ((h + 90) % 96) : h;
        const int nh = h0 / 12, kh = h0 - nh * 12;
#pragma unroll
        for (int cp = 0; cp < 2; ++cp) {
            __syncthreads();
            if ((wid & 1) == cp) {
#pragma unroll
                for (int nf = 0; nf < 4; ++nf) {
                    int cl = nf * 16 + lr;
#pragma unroll
                    for (int mf = 0; mf < 4; ++mf)
#pragma unroll
                        for (int r = 0; r < 4; ++r)
                            Sb[cl][wm + mf * 16 + lg * 4 + r] = (bf16)acc[mf][nf][r];
                }
            }
            __syncthreads();
#pragma unroll
            for (int i = 0; i < 4; ++i) {
                int chl = cg_ + 16 * i;
                int ch  = cp * 64 + chl;
                bf16x8 e = *(const bf16x8*)&Sb[chl][lr_ * 8];
#pragma unroll
                for (int hi = 0; hi < 2; ++hi) {
                    int wv = (QKVS == 1) ? ((w + hi * 4 + 300) % 320) : (w + hi * 4);
                    int nw = wv / 40, kw = wv - nw * 40;
                    bf16* dst = vtb + ((size_t)((b_ * 64 + nh * 8 + nw) * 128 + ch)) * 480 + kh * 40 + kw;
                    bf16x4 hv;
#pragma unroll
                    for (int j = 0; j < 4; ++j) hv[j] = e[hi * 4 + j];
                    *(bf16x4*)dst = hv;
                }
            }
        }
    }
}

// ---------------------------------------------------------------------------
// K=128 GEMM for outlook attn logits: M=81 (stride 84), bf16 out.
// ---------------------------------------------------------------------------
__global__ __launch_bounds__(256) void k_gemm128_wa(const bf16* __restrict__ A,
                                                    const bf16* __restrict__ Wt,
                                                    const float* __restrict__ bias,
                                                    bf16* __restrict__ outA)
{
    __shared__ bf16 As[128][136];
    __shared__ bf16 Sb[64][88];

    const int bm = blockIdx.x * 128;
    const int t = threadIdx.x;
    const int lane = t & 63, wid = t >> 6;
    const int wm = (wid >> 1) * 64, wn = (wid & 1) * 64;
    const int lr = lane & 15, lg = lane >> 4;

    bf16x8 zrow;
#pragma unroll
    for (int j = 0; j < 8; ++j) zrow[j] = (bf16)0.f;

    bool okc[4];
    const bf16* wp = Wt + (size_t)(wn + lr) * 128 + lg * 8;
#pragma unroll
    for (int nf = 0; nf < 4; ++nf) okc[nf] = (wn + nf * 16 + lr) < 81;

    bf16x8 bwA[4], bwB[4];
#pragma unroll
    for (int nf = 0; nf < 4; ++nf)
        bwA[nf] = okc[nf] ? *(const bf16x8*)(wp + (size_t)(nf * 16) * 128) : zrow;

#pragma unroll
    for (int i = 0; i < 8; ++i) {
        int o = i * 256 + t;
        int row = o >> 4, cg = (o & 15) * 8;
        *(bf16x8*)&As[row][cg] = *(const bf16x8*)(A + (size_t)(bm + row) * 128 + cg);
    }
    __syncthreads();

    const f32x4 zero4 = {0.f, 0.f, 0.f, 0.f};
    f32x4 acc[4][4];
#pragma unroll
    for (int i = 0; i < 4; ++i)
#pragma unroll
        for (int j = 0; j < 4; ++j) acc[i][j] = zero4;

#pragma unroll
    for (int ks = 0; ks < 4; ++ks) {
        const bf16x8* cur = (ks & 1) ? bwB : bwA;
        bf16x8*       nxt = (ks & 1) ? bwA : bwB;
        if (ks < 3) {
#pragma unroll
            for (int nf = 0; nf < 4; ++nf)
                nxt[nf] = okc[nf] ? *(const bf16x8*)(wp + (size_t)(nf * 16) * 128 + (ks + 1) * 32) : zrow;
        }
        bf16x8 af[4];
#pragma unroll
        for (int mf = 0; mf < 4; ++mf)
            af[mf] = *(const bf16x8*)&As[wm + mf*16 + lr][ks*32 + lg*8];
        __builtin_amdgcn_s_setprio(1);
#pragma unroll
        for (int mf = 0; mf < 4; ++mf)
#pragma unroll
            for (int nf = 0; nf < 4; ++nf)
                acc[mf][nf] = MFMA_BF16(af[mf], cur[nf], acc[mf][nf]);
        __builtin_amdgcn_s_setprio(0);
    }

#pragma unroll
    for (int half = 0; half < 2; ++half) {
        __syncthreads();
        if ((wid >> 1) == half) {
#pragma unroll
            for (int nf = 0; nf < 4; ++nf) {
                int col = wn + nf * 16 + lr;
                if (col >= 84) continue;
                float bv = (col < 81) ? bias[col] : 0.f;
#pragma unroll
                for (int mf = 0; mf < 4; ++mf)
#pragma unroll
                    for (int r = 0; r < 4; ++r) {
                        float vv = (col < 81) ? (acc[mf][nf][r] + bv) : 0.f;
                        Sb[mf * 16 + lg * 4 + r][col] = (bf16)vv;
                    }
            }
        }
        __syncthreads();
#pragma unroll
        for (int i = 0; i < 6; ++i) {
            int o = i * 256 + t;
            if (o < 64 * 21) {
                int row = o / 21, cq = (o - row * 21) * 4;
                *(bf16x4*)(outA + (size_t)(bm + half * 64 + row) * cAS + cq) =
                    *(const bf16x4*)&Sb[row][cq];
            }
        }
    }
}

// ---------------------------------------------------------------------------
// Generic k-loop GEMM, M=128. LNOUT: fuse next-layer LayerNorm into the
// fp32 epilogue (row fully resident across 32 consecutive lanes).
// ---------------------------------------------------------------------------
template<bool OUTBF, bool RELU, bool RES, bool POS, bool LNOUT>
__global__ __launch_bounds__(256) void k_gemm_res(const bf16* __restrict__ A,
                                                  const bf16* __restrict__ Wt,
                                                  const float* __restrict__ bias,
                                                  const float* __restrict__ res,
                                                  float* __restrict__ outF,
                                                  bf16* __restrict__ outB,
                                                  int K,
                                                  const float* __restrict__ ytab,
                                                  const float* __restrict__ xtab,
                                                  const float* __restrict__ lng,
                                                  const float* __restrict__ lnb,
                                                  bf16* __restrict__ xnbO)
{
    __shared__ bf16 As[128][40];
    __shared__ bf16 Bs[128][40];
    __shared__ float Sf[64][136];

    const int bm = blockIdx.x * 128;
    const int t = threadIdx.x;
    const int lane = t & 63, wid = t >> 6;
    const int wm = (wid >> 1) * 64, wn = (wid & 1) * 64;
    const int lr = lane & 15, lg = lane >> 4;

    const f32x4 zero4 = {0.f, 0.f, 0.f, 0.f};
    f32x4 acc[4][4];
#pragma unroll
    for (int i = 0; i < 4; ++i)
#pragma unroll
        for (int j = 0; j < 4; ++j) acc[i][j] = zero4;

    for (int k0 = 0; k0 < K; k0 += 32) {
#pragma unroll
        for (int i = 0; i < 2; ++i) {
            int idx = t + i * 256;
            int row = idx >> 2, kg = (idx & 3) * 8;
            *(bf16x8*)&As[row][kg] = *(const bf16x8*)(A + (size_t)(bm + row) * K + k0 + kg);
            *(bf16x8*)&Bs[row][kg] = *(const bf16x8*)(Wt + (size_t)row * K + k0 + kg);
        }
        __syncthreads();
        bf16x8 af[4], bf[4];
#pragma unroll
        for (int mf = 0; mf < 4; ++mf)
            af[mf] = *(const bf16x8*)&As[wm + mf*16 + lr][lg * 8];
#pragma unroll
        for (int nf = 0; nf < 4; ++nf)
            bf[nf] = *(const bf16x8*)&Bs[wn + nf*16 + lr][lg * 8];
        __builtin_amdgcn_s_setprio(1);
#pragma unroll
        for (int mf = 0; mf < 4; ++mf)
#pragma unroll
            for (int nf = 0; nf < 4; ++nf)
                acc[mf][nf] = MFMA_BF16(af[mf], bf[nf], acc[mf][nf]);
        __builtin_amdgcn_s_setprio(0);
        __syncthreads();
    }

    if (OUTBF) {
        bf16 (*Sb)[136] = (bf16(*)[136])Sf;
#pragma unroll
        for (int nf = 0; nf < 4; ++nf) {
            int col = wn + nf * 16 + lr;
            float bv = bias ? bias[col] : 0.f;
#pragma unroll
            for (int mf = 0; mf < 4; ++mf)
#pragma unroll
                for (int r = 0; r < 4; ++r) {
                    float vv = acc[mf][nf][r] + bv;
                    if (RELU) vv = fmaxf(vv, 0.f);
                    Sb[wm + mf * 16 + lg * 4 + r][col] = (bf16)vv;
                }
        }
        __syncthreads();
#pragma unroll
        for (int i = 0; i < 8; ++i) {
            int o = i * 256 + t;
            int row = o >> 4, cg = (o & 15) * 8;
            *(bf16x8*)(outB + (size_t)(bm + row) * 128 + cg) = *(const bf16x8*)&Sb[row][cg];
        }
    } else {
        for (int half = 0; half < 2; ++half) {
            __syncthreads();
            if ((wid >> 1) == half) {
#pragma unroll
                for (int nf = 0; nf < 4; ++nf) {
                    int col = wn + nf * 16 + lr;
                    float bv = bias ? bias[col] : 0.f;
#pragma unroll
                    for (int mf = 0; mf < 4; ++mf)
#pragma unroll
                        for (int r = 0; r < 4; ++r)
                            Sf[mf * 16 + lg * 4 + r][col] = acc[mf][nf][r] + bv;
                }
            }
            __syncthreads();
#pragma unroll
            for (int i = 0; i < 8; ++i) {
                int o = i * 256 + t;
                int row = o >> 5, cq = (o & 31) * 4;
                int grow = bm + half * 64 + row;
                float4 v = *(const float4*)&Sf[row][cq];
                if (POS) {
                    int hw = grow % cNPIX;
                    int h = hw / cW, w = hw - (hw / cW) * cW;
                    float4 p = (cq < 64) ? *(const float4*)(ytab + (h << 6) + cq)
                                         : *(const float4*)(xtab + (w << 6) + cq - 64);
                    v.x += p.x; v.y += p.y; v.z += p.z; v.w += p.w;
                }
                if (RES) {
                    float4 rr = *(const float4*)(res + (size_t)grow * 128 + cq);
                    v.x += rr.x; v.y += rr.y; v.z += rr.z; v.w += rr.w;
                }
                if (LNOUT) {
                    float s  = v.x + v.y + v.z + v.w;
                    float sq = v.x*v.x + v.y*v.y + v.z*v.z + v.w*v.w;
#pragma unroll
                    for (int mk = 1; mk < 32; mk <<= 1) {
                        s  += __shfl_xor(s,  mk);
                        sq += __shfl_xor(sq, mk);
                    }
                    float mu = s * (1.f / 128.f);
                    float rs = rsqrtf(sq * (1.f / 128.f) - mu * mu + 1e-5f);
                    float4 g4 = *(const float4*)(lng + cq);
                    float4 b4 = *(const float4*)(lnb + cq);
                    bf16x4 xo;
                    xo[0] = (bf16)((v.x - mu) * rs * g4.x + b4.x);
                    xo[1] = (bf16)((v.y - mu) * rs * g4.y + b4.y);
                    xo[2] = (bf16)((v.z - mu) * rs * g4.z + b4.z);
                    xo[3] = (bf16)((v.w - mu) * rs * g4.w + b4.w);
                    *(bf16x4*)(xnbO + (size_t)grow * 128 + cq) = xo;
                }
                *(float4*)(outF + (size_t)grow * 128 + cq) = v;
            }
        }
    }
}

// ---------------------------------------------------------------------------
// Outlook fused gather (bf16 logits, stride 84).
// ---------------------------------------------------------------------------
__global__ __launch_bounds__(256) void k_olk_gather(const bf16* __restrict__ v,
                                                    const bf16* __restrict__ attn,
                                                    bf16* __restrict__ y)
{
    __shared__ float pr[16][84];
    __shared__ float coef[16][26];

    const int t  = threadIdx.x;
    const int px = t >> 4;
    const int j  = t & 15;
    const int pix = blockIdx.x * 16 + px;
    const int b  = pix / cNPIX;
    const int hw = pix % cNPIX;
    const int h = hw / cW, w = hw % cW;

    if (j < 9) {
        const int p  = j;
        const int pi = p / 3, pj = p - pi * 3;
        const int hh = h + 1 - pi, ww = w + 1 - pj;
        float prv[9];
        if ((unsigned)hh < (unsigned)cH && (unsigned)ww < (unsigned)cW) {
            const size_t row = (size_t)(b * cNPIX + hh * cW + ww);
            const bf16* arow = attn + row * cAS + p * 9;
            float lg[9];
            float m = 0.f;
#pragma unroll
            for (int q = 0; q < 9; ++q) { lg[q] = (float)arow[q]; m = fmaxf(m, lg[q]); }
            float se = 0.f;
#pragma unroll
            for (int q = 0; q < 9; ++q) { prv[q] = __expf(lg[q] - m); se += prv[q]; }
            float inv = 1.f / (se + __expf(-m));
#pragma unroll
            for (int q = 0; q < 9; ++q) prv[q] *= inv;
        } else {
#pragma unroll
            for (int q = 0; q < 9; ++q) prv[q] = 0.f;
        }
#pragma unroll
        for (int q = 0; q < 9; ++q) pr[px][p * 9 + q] = prv[q];
    }
    __syncthreads();

    for (int d = j; d < 25; d += 16) {
        const int a  = d / 5, bb = d - a * 5;
        float s = 0.f;
#pragma unroll
        for (int pi = 0; pi < 3; ++pi) {
            const int qi = pi + a - 2;
            if ((unsigned)qi >= 3u) continue;
#pragma unroll
            for (int pj = 0; pj < 3; ++pj) {
                const int qj = pj + bb - 2;
                if ((unsigned)qj >= 3u) continue;
                s += pr[px][(pi * 3 + pj) * 9 + qi * 3 + qj];
            }
        }
        coef[px][d] = s;
    }
    __syncthreads();

    float acc[8] = {};
    const size_t bbase = (size_t)b * cNPIX;
#pragma unroll
    for (int a = 0; a < 5; ++a) {
        const int sh = h + a - 2;
        if ((unsigned)sh >= (unsigned)cH) continue;
#pragma unroll
        for (int bb = 0; bb < 5; ++bb) {
            const int sw = w + bb - 2;
            if ((unsigned)sw >= (unsigned)cW) continue;
            const float cf = coef[px][a * 5 + bb];
            const bf16x8 v8 = *(const bf16x8*)(v + ((bbase + (size_t)sh * cW + sw) * 128 + j * 8));
#pragma unroll
            for (int e = 0; e < 8; ++e) acc[e] = fmaf(cf, (float)v8[e], acc[e]);
        }
    }
    bf16x8 o8;
#pragma unroll
    for (int e = 0; e < 8; ++e) o8[e] = (bf16)acc[e];
    *(bf16x8*)(y + (size_t)pix * 128 + j * 8) = o8;
}

// ---------------------------------------------------------------------------
// Depthwise 3x3 + bias + exact GELU, row-sliding, NHWC 512 ch.
// ---------------------------------------------------------------------------
__global__ __launch_bounds__(256) void k_dwconv_gelu(const bf16* __restrict__ h1,
                                                     const float* __restrict__ dwt,
                                                     const float* __restrict__ bdw,
                                                     bf16* __restrict__ h2)
{
    const int t   = threadIdx.x;
    const int c2  = t * 2;
    const int blk = blockIdx.x;
    const int row = blk >> 3;
    const int seg = blk & 7;
    const int bb  = row / cH, h = row % cH;
    const int w0  = seg * 40;

    float2 wgt[9];
#pragma unroll
    for (int k = 0; k < 9; ++k)
        wgt[k] = *(const float2*)(dwt + k * 512 + c2);
    const float2 bias = *(const float2*)(bdw + c2);

    const size_t base = (size_t)bb * cNPIX;

    auto ld = [&](int hh, int ww) -> float2 {
        float2 r; r.x = 0.f; r.y = 0.f;
        if ((unsigned)hh < (unsigned)cH && (unsigned)ww < (unsigned)cW) {
            unsigned u = *(const unsigned*)(h1 + ((base + (size_t)hh * cW + ww) * 512 + c2));
            r.x = __uint_as_float(u << 16);
            r.y = __uint_as_float(u & 0xffff0000u);
        }
        return r;
    };

    float2 cm[3], c0[3], cp[3];
#pragma unroll
    for (int r = 0; r < 3; ++r) {
        cm[r] = ld(h + r - 1, w0 - 1);
        c0[r] = ld(h + r - 1, w0);
    }

    for (int j = 0; j < 40; ++j) {
#pragma unroll
        for (int r = 0; r < 3; ++r) cp[r] = ld(h + r - 1, w0 + j + 1);
        float a0 = bias.x, a1 = bias.y;
#pragma unroll
        for (int r = 0; r < 3; ++r) {
            a0 = fmaf(cm[r].x, wgt[r * 3 + 0].x, a0);
            a1 = fmaf(cm[r].y, wgt[r * 3 + 0].y, a1);
            a0 = fmaf(c0[r].x, wgt[r * 3 + 1].x, a0);
            a1 = fmaf(c0[r].y, wgt[r * 3 + 1].y, a1);
            a0 = fmaf(cp[r].x, wgt[r * 3 + 2].x, a0);
            a1 = fmaf(cp[r].y, wgt[r * 3 + 2].y, a1);
        }
        a0 = 0.5f * a0 * (1.f + erff(a0 * 0.70710678118654752f));
        a1 = 0.5f * a1 * (1.f + erff(a1 * 0.70710678118654752f));
        union { bf16 hh[2]; unsigned int u; } o2;
        o2.hh[0] = (bf16)a0;
        o2.hh[1] = (bf16)a1;
        *(unsigned int*)(h2 + (base + (size_t)h * cW + w0 + j) * 512 + c2) = o2.u;
#pragma unroll
        for (int r = 0; r < 3; ++r) { cm[r] = c0[r]; c0[r] = cp[r]; }
    }
}

// ---------------------------------------------------------------------------
// Window attention. q: [tok][128]; ks: [wb*480+key][128] window-ordered;
// vt: [(wb*128+ch)*480+key]. Division-free K-loop; incremental SHIFT labels.
// ---------------------------------------------------------------------------
template<bool SHIFT>
__global__ __launch_bounds__(256) void k_win_attn(const bf16* __restrict__ q,
                                                  const bf16* __restrict__ ks,
                                                  const bf16* __restrict__ vt,
                                                  bf16* __restrict__ out)
{
    __shared__ bf16 Ks[2][32][136];
    __shared__ bf16 Vs[2][128][40];
    __shared__ bf16 Ps[4][16][40];

    const int t = threadIdx.x, lane = t & 63, wid = t >> 6;
    const int lr = lane & 15, lg = lane >> 4;
    const int wb = blockIdx.x;
    const int b  = wb >> 6, win = wb & 63;
    const int nh = win >> 3, nw = win & 7;
    const int qbase = blockIdx.y * 64 + wid * 16;

    const float SCALE   = 0.088388347648318447f;
    const float MASKRAW = 100.f / 0.088388347648318447f;

    auto tokOf = [&](int p) {
        int ph = nh * 12 + p / 40;
        int pw = nw * 40 + (p % 40);
        if (SHIFT) {
            ph += 6;  if (ph >= cH) ph -= cH;
            pw += 20; if (pw >= cW) pw -= cW;
        }
        return b * cNPIX + ph * cW + pw;
    };

    int qp = min(qbase + lr, 479);
    const bf16* qptr = q + (size_t)tokOf(qp) * 128;
    bf16x8 qf[4];
#pragma unroll
    for (int c = 0; c < 4; ++c)
        qf[c] = *(const bf16x8*)(qptr + c * 32 + lg * 8);

    int labq[4];
    if (SHIFT) {
#pragma unroll
        for (int r = 0; r < 4; ++r) {
            int qrow = min(qbase + lg * 4 + r, 479);
            int qr = qrow / 40, qc = qrow - qr * 40;
            int rh = (nh == 7) ? (qr < 6 ? 1 : 2) : 0;
            int rc = (nw == 7) ? (qc < 20 ? 1 : 2) : 0;
            labq[r] = rh * 3 + rc;
        }
    }

    const bf16* kbase = ks + (size_t)wb * 480 * 128;
    const bf16* vbase = vt + (size_t)wb * 128 * 480;
    auto loadK = [&](int kt, int i) {
        int idx = t + i * 256;
        int key = idx >> 4, cg = (idx & 15) * 8;
        return *(const bf16x8*)(kbase + (size_t)(kt * 32 + key) * 128 + cg);
    };
    auto loadV = [&](int kt, int i) {
        int idx = t + i * 256;
        int ch = idx >> 2, kq = (idx & 3) * 8;
        return *(const bf16x8*)(vbase + (size_t)ch * 480 + kt * 32 + kq);
    };

    bf16x8 kreg0 = loadK(0, 0), kreg1 = loadK(0, 1);
    bf16x8 vreg0 = loadV(0, 0), vreg1 = loadV(0, 1);

    // incremental in-window (row,col) for this thread's two key slots
    int kc0 = lr, kr0 = 0;
    int kc1 = 16 + lr, kr1 = 0;

    const f32x4 zero4 = {0.f, 0.f, 0.f, 0.f};
    float m_run[4] = {0.f, 0.f, 0.f, 0.f};
    float mguard = 8.f;
    f32x4 l4 = zero4;
    f32x4 o[8];
#pragma unroll
    for (int nf = 0; nf < 8; ++nf) o[nf] = zero4;

    bf16x8 ones8;
#pragma unroll
    for (int j = 0; j < 8; ++j) ones8[j] = (bf16)1.f;

    int buf = 0;
    for (int kt = 0; kt < 15; ++kt) {
        {
            int i0 = t, i1 = t + 256;
            *(bf16x8*)&Ks[buf][i0 >> 4][(i0 & 15) * 8] = kreg0;
            *(bf16x8*)&Ks[buf][i1 >> 4][(i1 & 15) * 8] = kreg1;
            *(bf16x8*)&Vs[buf][i0 >> 2][(i0 & 3) * 8] = vreg0;
            *(bf16x8*)&Vs[buf][i1 >> 2][(i1 & 3) * 8] = vreg1;
        }
        if (kt + 1 < 15) {
            kreg0 = loadK(kt + 1, 0); kreg1 = loadK(kt + 1, 1);
            vreg0 = loadV(kt + 1, 0); vreg1 = loadV(kt + 1, 1);
        }
        __syncthreads();

        f32x4 s0 = zero4, s1 = zero4;
        __builtin_amdgcn_s_setprio(1);
#pragma unroll
        for (int c = 0; c < 4; ++c) {
            bf16x8 kf0 = *(const bf16x8*)&Ks[buf][lr][c * 32 + lg * 8];
            bf16x8 kf1 = *(const bf16x8*)&Ks[buf][16 + lr][c * 32 + lg * 8];
            s0 = MFMA_BF16(qf[c], kf0, s0);
            s1 = MFMA_BF16(qf[c], kf1, s1);
        }
        __builtin_amdgcn_s_setprio(0);

        if (SHIFT) {
            int rh0 = (nh == 7) ? (kr0 < 6 ? 1 : 2) : 0;
            int rc0 = (nw == 7) ? (kc0 < 20 ? 1 : 2) : 0;
            int rh1 = (nh == 7) ? (kr1 < 6 ? 1 : 2) : 0;
            int rc1 = (nw == 7) ? (kc1 < 20 ? 1 : 2) : 0;
            int lab0 = rh0 * 3 + rc0;
            int lab1 = rh1 * 3 + rc1;
#pragma unroll
            for (int r = 0; r < 4; ++r) {
                if (labq[r] != lab0) s0[r] -= MASKRAW;
                if (labq[r] != lab1) s1[r] -= MASKRAW;
            }
        }
        // advance key trackers
        kc0 += 32; if (kc0 >= 40) { kc0 -= 40; ++kr0; }
        kc1 += 32; if (kc1 >= 40) { kc1 -= 40; ++kr1; }

        float tm = fmaxf(fmaxf(fmaxf(s0[0], s0[1]), fmaxf(s0[2], s0[3])),
                         fmaxf(fmaxf(s1[0], s1[1]), fmaxf(s1[2], s1[3])));
#pragma unroll
        for (int off = 1; off < 16; off <<= 1) tm = fmaxf(tm, __shfl_xor(tm, off));
        if (tm * SCALE > mguard) {
#pragma unroll
            for (int r = 0; r < 4; ++r) {
                float mx = fmaxf(s0[r], s1[r]);
#pragma unroll
                for (int off = 1; off < 16; off <<= 1) mx = fmaxf(mx, __shfl_xor(mx, off));
                float nm = fmaxf(m_run[r], mx * SCALE);
                float sc = __expf(m_run[r] - nm);
#pragma unroll
                for (int nf = 0; nf < 8; ++nf) o[nf][r] *= sc;
                l4[r] *= sc;
                m_run[r] = nm;
            }
            mguard = fminf(fminf(m_run[0], m_run[1]), fminf(m_run[2], m_run[3])) + 8.f;
        }

#pragma unroll
        for (int r = 0; r < 4; ++r) {
            float p0 = __expf(fmaf(s0[r], SCALE, -m_run[r]));
            float p1 = __expf(fmaf(s1[r], SCALE, -m_run[r]));
            Ps[wid][lg * 4 + r][lr]      = (bf16)p0;
            Ps[wid][lg * 4 + r][16 + lr] = (bf16)p1;
        }

        bf16x8 pa = *(const bf16x8*)&Ps[wid][lr][lg * 8];
        __builtin_amdgcn_s_setprio(1);
        l4 = MFMA_BF16(pa, ones8, l4);
#pragma unroll
        for (int nf = 0; nf < 8; ++nf) {
            bf16x8 bv = *(const bf16x8*)&Vs[buf][nf * 16 + lr][lg * 8];
            o[nf] = MFMA_BF16(pa, bv, o[nf]);
        }
        __builtin_amdgcn_s_setprio(0);
        __syncthreads();
        buf ^= 1;
    }

#pragma unroll
    for (int r = 0; r < 4; ++r) {
        int qrow = qbase + lg * 4 + r;
        if (qrow >= 480) continue;
        float inv = 1.f / (l4[r] + __expf(-m_run[r]));
        size_t ooff = (size_t)tokOf(qrow) * 128;
#pragma unroll
        for (int nf = 0; nf < 8; ++nf)
            out[ooff + nf * 16 + lr] = (bf16)(o[nf][r] * inv);
    }
}

// ---------------------------------------------------------------------------
// Host launcher
// ---------------------------------------------------------------------------
extern "C" void kernel_launch(void* const* d_in, const int* in_sizes, int n_in,
                              void* d_out, int out_size, void* d_ws, size_t ws_size,
                              hipStream_t stream)
{
    (void)in_sizes; (void)n_in; (void)out_size; (void)ws_size;

    const float* X = (const float*)d_in[0];

    char* ws = (char*)d_ws;
    float* f    = (float*)ws;                                 ws += (size_t)cNTOK * 128 * 4;
    bf16*  xnb  = (bf16*)ws;                                  ws += (size_t)cNTOK * 128 * 2;
    bf16*  bufA = (bf16*)ws;                                  ws += (size_t)cNTOK * 512 * 2;
    bf16*  bufB = (bf16*)ws;                                  ws += (size_t)cNTOK * 512 * 2;
    bf16*  wts  = (bf16*)ws;

    size_t wo_off = 0;
    auto nextw = [&](int K, int M) { bf16* p = wts + wo_off; wo_off += (size_t)K * M; return p; };
    bf16* agg_w1t = nextw(256, 128);
    bf16* agg_w2t = nextw(128, 128);
    bf16* ol_wvt  = nextw(128, 128);
    bf16* ol_wat  = nextw(128, 81);
    bf16* ol_wot  = nextw(128, 128);
    bf16* f1_w1t  = nextw(128, 512);
    bf16* f1_w2t  = nextw(512, 128);
    bf16* w_qkvt  = nextw(128, 384);
    bf16* w_wot   = nextw(128, 128);
    bf16* f2_w1t  = nextw(128, 512);
    bf16* f2_w2t  = nextw(512, 128);
    bf16* s_qkvt  = nextw(128, 384);
    bf16* s_wot   = nextw(128, 128);
    bf16* f3_w1t  = nextw(128, 512);
    bf16* f3_w2t  = nextw(512, 128);
    float* dwt1 = (float*)(wts + wo_off);
    float* dwt2 = dwt1 + 512 * 9;
    float* dwt3 = dwt2 + 512 * 9;
    float* ytab = dwt3 + 512 * 9;
    float* xtab = ytab + 96 * 64;

    WJobs jobs;
    int ji = 0;
    auto addj = [&](int src_idx, bf16* dst, int K, int M) {
        jobs.j[ji++] = WJob{(const float*)d_in[src_idx], dst, K, M};
    };
    addj(1,  agg_w1t, 256, 128);
    addj(3,  agg_w2t, 128, 128);
    addj(7,  ol_wvt,  128, 128);
    addj(8,  ol_wat,  128, 81);
    addj(10, ol_wot,  128, 128);
    addj(14, f1_w1t,  128, 512);
    addj(18, f1_w2t,  512, 128);
    addj(22, w_qkvt,           128, 128);
    addj(23, w_qkvt + 128*128, 128, 128);
    addj(24, w_qkvt + 256*128, 128, 128);
    addj(25, w_wot,   128, 128);
    addj(29, f2_w1t,  128, 512);
    addj(33, f2_w2t,  512, 128);
    addj(37, s_qkvt,           128, 128);
    addj(38, s_qkvt + 128*128, 128, 128);
    addj(39, s_qkvt + 256*128, 128, 128);
    addj(40, s_wot,   128, 128);
    addj(44, f3_w1t,  128, 512);
    addj(48, f3_w2t,  512, 128);
    k_wt<<<dim3(16, 16, 19), dim3(32, 8), 0, stream>>>(jobs);
    k_dwt<<<3, 256, 0, stream>>>((const float*)d_in[16], (const float*)d_in[31],
                                 (const float*)d_in[46], dwt1, dwt2, dwt3);
    k_postab<<<80, 256, 0, stream>>>(ytab, xtab);

    const int nTT = cNTOK / 128;   // 480 token tiles

    // ---- input transpose + aggregation MLP (agg_w2 epilogue emits ol-LN) ----
    k_chw2hwc<<<dim3(cNPIX / 32, 256 / 32, cB), dim3(32, 8), 0, stream>>>(X, bufA);
    k_gemm_res<true, true, false, false, false><<<nTT, 256, 0, stream>>>(
        bufA, agg_w1t, (const float*)d_in[2], nullptr, nullptr, bufB, 256,
        nullptr, nullptr, nullptr, nullptr, nullptr);
    k_gemm_res<false, false, false, false, true><<<nTT, 256, 0, stream>>>(
        bufB, agg_w2t, (const float*)d_in[4], nullptr, f, nullptr, 128,
        nullptr, nullptr, (const float*)d_in[5], (const float*)d_in[6], xnb);

    // ---- outlook attention (ol_wo epilogue emits f1-LN) ----
    {
        bf16*  vb   = bufA;
        bf16*  gout = bufA + (size_t)cNTOK * 128;
        bf16*  atn  = bufB;
        k_gemm128<-1><<<nTT, 256, 0, stream>>>(xnb, ol_wvt, nullptr, vb, 128, nullptr, nullptr);
        k_gemm128_wa<<<nTT, 256, 0, stream>>>(xnb, ol_wat, (const float*)d_in[9], atn);
        k_olk_gather<<<cNTOK / 16, 256, 0, stream>>>(vb, atn, gout);
        k_gemm_res<false, false, true, false, true><<<nTT, 256, 0, stream>>>(
            gout, ol_wot, (const float*)d_in[11], f, f, nullptr, 128,
            nullptr, nullptr, (const float*)d_in[12], (const float*)d_in[13], xnb);
    }

    // ---- conv FFN; w2 epilogue emits next block's LN (if lnG) ----
    auto run_ffn = [&](int base, bf16* w1t, bf16* w2t, float* dwt, bool pos,
                       const float* lnG, const float* lnB) {
        k_gemm128<-1><<<nTT * 4, 256, 0, stream>>>(
            xnb, w1t, (const float*)d_in[base + 3], bufA, 512, nullptr, nullptr);
        k_dwconv_gelu<<<cB * cH * 8, 256, 0, stream>>>(
            bufA, dwt, (const float*)d_in[base + 5], bufB);
        if (pos) {
            k_gemm_res<false, false, true, true, true><<<nTT, 256, 0, stream>>>(
                bufB, w2t, (const float*)d_in[base + 7], f, f, nullptr, 512,
                ytab, xtab, lnG, lnB, xnb);
        } else if (lnG) {
            k_gemm_res<false, false, true, false, true><<<nTT, 256, 0, stream>>>(
                bufB, w2t, (const float*)d_in[base + 7], f, f, nullptr, 512,
                nullptr, nullptr, lnG, lnB, xnb);
        } else {
            k_gemm_res<false, false, true, false, false><<<nTT, 256, 0, stream>>>(
                bufB, w2t, (const float*)d_in[base + 7], f, f, nullptr, 512,
                nullptr, nullptr, nullptr, nullptr, nullptr);
        }
    };

    // ---- window attention; wo epilogue emits next block's LN ----
    auto run_win = [&](int base, bf16* qkvt, bf16* wot, bool shift,
                       const float* lnG, const float* lnB) {
        bf16* qb  = bufA;
        bf16* ksb = bufA + (size_t)cNTOK * 128;
        bf16* vtb = bufA + (size_t)cNTOK * 256;
        bf16* ao  = bufB;
        if (shift)
            k_gemm128<1><<<nTT * 3, 256, 0, stream>>>(xnb, qkvt, nullptr, qb, 384, vtb, ksb);
        else
            k_gemm128<0><<<nTT * 3, 256, 0, stream>>>(xnb, qkvt, nullptr, qb, 384, vtb, ksb);
        if (shift) k_win_attn<true ><<<dim3(128, 8), 256, 0, stream>>>(qb, ksb, vtb, ao);
        else       k_win_attn<false><<<dim3(128, 8), 256, 0, stream>>>(qb, ksb, vtb, ao);
        k_gemm_res<false, false, true, false, true><<<nTT, 256, 0, stream>>>(
            ao, wot, (const float*)d_in[base + 6], f, f, nullptr, 128,
            nullptr, nullptr, lnG, lnB, xnb);
    };

    run_ffn(12, f1_w1t, f1_w2t, dwt1, true,
            (const float*)d_in[20], (const float*)d_in[21]);       // f1 (+pos, emits w-LN)
    run_win(20, w_qkvt, w_wot, false,
            (const float*)d_in[27], (const float*)d_in[28]);       // w (emits f2-LN)
    run_ffn(27, f2_w1t, f2_w2t, dwt2, false,
            (const float*)d_in[35], (const float*)d_in[36]);       // f2 (emits s-LN)
    run_win(35, s_qkvt, s_wot, true,
            (const float*)d_in[42], (const float*)d_in[43]);       // s (emits f3-LN)
    run_ffn(42, f3_w1t, f3_w2t, dwt3, false, nullptr, nullptr);    // f3 (no LN out)

    k_hwc2chw<<<dim3(cNPIX / 32, cC / 32, cB), dim3(32, 8), 0, stream>>>(f, (float*)d_out);
}

// Round 10
// 571.549 us; speedup vs baseline: 6.8206x; 1.0972x over previous
//
#include <hip/hip_runtime.h>

typedef __bf16 bf16;
typedef __bf16 bf16x8 __attribute__((ext_vector_type(8)));
typedef __bf16 bf16x4 __attribute__((ext_vector_type(4)));
typedef float  f32x4  __attribute__((ext_vector_type(4)));

#define MFMA_BF16(a, b, c) __builtin_amdgcn_mfma_f32_16x16x32_bf16(a, b, c, 0, 0, 0)

constexpr int cB    = 2;
constexpr int cH    = 96;
constexpr int cW    = 320;
constexpr int cC    = 128;
constexpr int cNPIX = cH * cW;          // 30720
constexpr int cNTOK = cB * cNPIX;       // 61440
constexpr int cAS   = 84;               // padded attn-logit stride (81 -> 84)

// ---------------------------------------------------------------------------
// Weight transpose+convert: fp32 W (K x M) -> bf16 Wt (M x K)
// ---------------------------------------------------------------------------
struct WJob  { const float* src; bf16* dst; int K; int M; };
struct WJobs { WJob j[19]; };

__global__ __launch_bounds__(256) void k_wt(WJobs jobs)
{
    __shared__ float tile[32][33];
    const WJob jb = jobs.j[blockIdx.z];
    int k0 = blockIdx.y * 32, m0 = blockIdx.x * 32;
    if (k0 >= jb.K || m0 >= jb.M) return;
    int tx = threadIdx.x, ty = threadIdx.y;
#pragma unroll
    for (int i = 0; i < 32; i += 8) {
        int kk = k0 + ty + i, mm = m0 + tx;
        tile[ty + i][tx] = (kk < jb.K && mm < jb.M) ? jb.src[(size_t)kk * jb.M + mm] : 0.f;
    }
    __syncthreads();
#pragma unroll
    for (int i = 0; i < 32; i += 8) {
        int mm = m0 + ty + i, kk = k0 + tx;
        if (mm < jb.M && kk < jb.K)
            jb.dst[(size_t)mm * jb.K + kk] = (bf16)tile[tx][ty + i];
    }
}

__global__ __launch_bounds__(256) void k_dwt(const float* s0, const float* s1, const float* s2,
                                             float* d0, float* d1, float* d2)
{
    const float* s = blockIdx.x == 0 ? s0 : (blockIdx.x == 1 ? s1 : s2);
    float*       d = blockIdx.x == 0 ? d0 : (blockIdx.x == 1 ? d1 : d2);
    for (int i = threadIdx.x; i < 512 * 9; i += 256) {
        int c = i / 9, tap = i - c * 9;
        d[tap * 512 + c] = s[i];
    }
}

__global__ __launch_bounds__(256) void k_postab(float* __restrict__ yt, float* __restrict__ xt)
{
    int i = blockIdx.x * 256 + threadIdx.x;
    const float TWO_PI = 6.283185307179586f;
    const float KSC = -9.210340371976184f / 32.f;
    if (i < 96 * 64) {
        int h = i >> 6, c = i & 63;
        float p = (float)(h + 1) * (TWO_PI / (96.f + 1e-6f));
        float val = p * expf((float)(c >> 1) * KSC);
        yt[i] = (c & 1) ? cosf(val) : sinf(val);
    }
    if (i < 320 * 64) {
        int w = i >> 6, c = i & 63;
        float p = (float)(w + 1) * (TWO_PI / (320.f + 1e-6f));
        float val = p * expf((float)(c >> 1) * KSC);
        xt[i] = (c & 1) ? cosf(val) : sinf(val);
    }
}

// ---------------------------------------------------------------------------
// Transposes
// ---------------------------------------------------------------------------
__global__ __launch_bounds__(256) void k_chw2hwc(const float* __restrict__ in,
                                                 bf16* __restrict__ out)
{
    __shared__ float tile[32][33];
    const int Cc = 256;
    int s0 = blockIdx.x * 32;
    int c0 = blockIdx.y * 32;
    int b  = blockIdx.z;
    const float* ip = in  + (size_t)b * Cc * cNPIX;
    bf16*        op = out + (size_t)b * cNPIX * Cc;
    int tx = threadIdx.x, ty = threadIdx.y;
#pragma unroll
    for (int i = 0; i < 32; i += 8)
        tile[ty + i][tx] = ip[(size_t)(c0 + ty + i) * cNPIX + s0 + tx];
    __syncthreads();
#pragma unroll
    for (int i = 0; i < 32; i += 8)
        op[(size_t)(s0 + ty + i) * Cc + c0 + tx] = (bf16)tile[tx][ty + i];
}

__global__ __launch_bounds__(256) void k_hwc2chw(const float* __restrict__ in,
                                                 float* __restrict__ out)
{
    __shared__ float tile[32][33];
    int s0 = blockIdx.x * 32;
    int c0 = blockIdx.y * 32;
    int b  = blockIdx.z;
    const float* ip = in  + (size_t)b * cNPIX * cC;
    float*       op = out + (size_t)b * cC * cNPIX;
    int tx = threadIdx.x, ty = threadIdx.y;
#pragma unroll
    for (int i = 0; i < 32; i += 8)
        tile[ty + i][tx] = ip[(size_t)(s0 + ty + i) * cC + c0 + tx];
    __syncthreads();
#pragma unroll
    for (int i = 0; i < 32; i += 8)
        op[(size_t)(c0 + ty + i) * cNPIX + s0 + tx] = tile[tx][ty + i];
}

// ---------------------------------------------------------------------------
// K=128 single-shot GEMM (unchanged from R9).
// ---------------------------------------------------------------------------
template<int QKVS>
__global__ __launch_bounds__(256) void k_gemm128(const bf16* __restrict__ A,
                                                 const bf16* __restrict__ Wt,
                                                 const float* __restrict__ bias,
                                                 bf16* __restrict__ outB, int M,
                                                 bf16* __restrict__ vtb,
                                                 bf16* __restrict__ ksb)
{
    __shared__ bf16 As[128][136];
    __shared__ bf16 Sb[64][136];

    const int NS = M >> 7;
    const int l  = blockIdx.x;
    const int r8 = l % (8 * NS);
    const int qq = l / (8 * NS);
    const int bm = (qq * 8 + (r8 & 7)) * 128;
    const int bn = (r8 >> 3) * 128;

    const int t = threadIdx.x;
    const int lane = t & 63, wid = t >> 6;
    const int wm = (wid >> 1) * 64, wn = (wid & 1) * 64;
    const int lr = lane & 15, lg = lane >> 4;

    const bf16* wp = Wt + (size_t)(bn + wn + lr) * 128 + lg * 8;
    bf16x8 bwA[4], bwB[4];
#pragma unroll
    for (int nf = 0; nf < 4; ++nf)
        bwA[nf] = *(const bf16x8*)(wp + (size_t)(nf * 16) * 128);

#pragma unroll
    for (int i = 0; i < 8; ++i) {
        int o = i * 256 + t;
        int row = o >> 4, cg = (o & 15) * 8;
        *(bf16x8*)&As[row][cg] = *(const bf16x8*)(A + (size_t)(bm + row) * 128 + cg);
    }
    __syncthreads();

    const f32x4 zero4 = {0.f, 0.f, 0.f, 0.f};
    f32x4 acc[4][4];
#pragma unroll
    for (int i = 0; i < 4; ++i)
#pragma unroll
        for (int j = 0; j < 4; ++j) acc[i][j] = zero4;

#pragma unroll
    for (int ks = 0; ks < 4; ++ks) {
        const bf16x8* cur = (ks & 1) ? bwB : bwA;
        bf16x8*       nxt = (ks & 1) ? bwA : bwB;
        if (ks < 3) {
#pragma unroll
            for (int nf = 0; nf < 4; ++nf)
                nxt[nf] = *(const bf16x8*)(wp + (size_t)(nf * 16) * 128 + (ks + 1) * 32);
        }
        bf16x8 af[4];
#pragma unroll
        for (int mf = 0; mf < 4; ++mf)
            af[mf] = *(const bf16x8*)&As[wm + mf*16 + lr][ks*32 + lg*8];
        __builtin_amdgcn_s_setprio(1);
#pragma unroll
        for (int mf = 0; mf < 4; ++mf)
#pragma unroll
            for (int nf = 0; nf < 4; ++nf)
                acc[mf][nf] = MFMA_BF16(af[mf], cur[nf], acc[mf][nf]);
        __builtin_amdgcn_s_setprio(0);
    }

    const bool vpart = (QKVS >= 0) && (bn == 256);
    const bool kpart = (QKVS >= 0) && (bn == 128);
    if (!vpart) {
#pragma unroll
        for (int half = 0; half < 2; ++half) {
            __syncthreads();
            if ((wid >> 1) == half) {
#pragma unroll
                for (int nf = 0; nf < 4; ++nf) {
                    int col = wn + nf * 16 + lr;
                    float bv = bias ? bias[bn + col] : 0.f;
#pragma unroll
                    for (int mf = 0; mf < 4; ++mf)
#pragma unroll
                        for (int r = 0; r < 4; ++r)
                            Sb[mf * 16 + lg * 4 + r][col] = (bf16)(acc[mf][nf][r] + bv);
                }
            }
            __syncthreads();
            if (!kpart) {
                const int ldo = (QKVS >= 0) ? 128 : M;
#pragma unroll
                for (int i = 0; i < 4; ++i) {
                    int o = i * 256 + t;
                    int row = o >> 4, cg = (o & 15) * 8;
                    *(bf16x8*)(outB + (size_t)(bm + half * 64 + row) * ldo + bn + cg) =
                        *(const bf16x8*)&Sb[row][cg];
                }
            } else {
#pragma unroll
                for (int i = 0; i < 4; ++i) {
                    int o = i * 256 + t;
                    int row = o >> 4, cg = (o & 15) * 8;
                    int gt = bm + half * 64 + row;
                    int b_ = gt / cNPIX, hw = gt - b_ * cNPIX;
                    int h = hw / cW, w = hw - (hw / cW) * cW;
                    int h0 = (QKVS == 1) ? ((h + 90) % 96)  : h;
                    int w0 = (QKVS == 1) ? ((w + 300) % 320) : w;
                    int nh = h0 / 12, kh = h0 - nh * 12;
                    int nw = w0 / 40, kw = w0 - nw * 40;
                    size_t krow = (size_t)((b_ * 64 + nh * 8 + nw) * 480 + kh * 40 + kw);
                    *(bf16x8*)(ksb + krow * 128 + cg) = *(const bf16x8*)&Sb[row][cg];
                }
            }
        }
    } else {
        const int lr_ = t & 15, cg_ = t >> 4;
        const int gt = bm + lr_ * 8;
        const int b_ = gt / cNPIX, hw = gt % cNPIX;
        const int h = hw / cW, w = hw % cW;
        const int h0 = (QKVS == 1) ? ((h + 90) % 96) : h;
        const int nh = h0 / 12, kh = h0 - nh * 12;
#pragma unroll
        for (int cp = 0; cp < 2; ++cp) {
            __syncthreads();
            if ((wid & 1) == cp) {
#pragma unroll
                for (int nf = 0; nf < 4; ++nf) {
                    int cl = nf * 16 + lr;
#pragma unroll
                    for (int mf = 0; mf < 4; ++mf)
#pragma unroll
                        for (int r = 0; r < 4; ++r)
                            Sb[cl][wm + mf * 16 + lg * 4 + r] = (bf16)acc[mf][nf][r];
                }
            }
            __syncthreads();
#pragma unroll
            for (int i = 0; i < 4; ++i) {
                int chl = cg_ + 16 * i;
                int ch  = cp * 64 + chl;
                bf16x8 e = *(const bf16x8*)&Sb[chl][lr_ * 8];
#pragma unroll
                for (int hi = 0; hi < 2; ++hi) {
                    int wv = (QKVS == 1) ? ((w + hi * 4 + 300) % 320) : (w + hi * 4);
                    int nw = wv / 40, kw = wv - nw * 40;
                    bf16* dst = vtb + ((size_t)((b_ * 64 + nh * 8 + nw) * 128 + ch)) * 480 + kh * 40 + kw;
                    bf16x4 hv;
#pragma unroll
                    for (int j = 0; j < 4; ++j) hv[j] = e[hi * 4 + j];
                    *(bf16x4*)dst = hv;
                }
            }
        }
    }
}

// ---------------------------------------------------------------------------
// K=128 GEMM for outlook attn logits (unchanged from R9).
// ---------------------------------------------------------------------------
__global__ __launch_bounds__(256) void k_gemm128_wa(const bf16* __restrict__ A,
                                                    const bf16* __restrict__ Wt,
                                                    const float* __restrict__ bias,
                                                    bf16* __restrict__ outA)
{
    __shared__ bf16 As[128][136];
    __shared__ bf16 Sb[64][88];

    const int bm = blockIdx.x * 128;
    const int t = threadIdx.x;
    const int lane = t & 63, wid = t >> 6;
    const int wm = (wid >> 1) * 64, wn = (wid & 1) * 64;
    const int lr = lane & 15, lg = lane >> 4;

    bf16x8 zrow;
#pragma unroll
    for (int j = 0; j < 8; ++j) zrow[j] = (bf16)0.f;

    bool okc[4];
    const bf16* wp = Wt + (size_t)(wn + lr) * 128 + lg * 8;
#pragma unroll
    for (int nf = 0; nf < 4; ++nf) okc[nf] = (wn + nf * 16 + lr) < 81;

    bf16x8 bwA[4], bwB[4];
#pragma unroll
    for (int nf = 0; nf < 4; ++nf)
        bwA[nf] = okc[nf] ? *(const bf16x8*)(wp + (size_t)(nf * 16) * 128) : zrow;

#pragma unroll
    for (int i = 0; i < 8; ++i) {
        int o = i * 256 + t;
        int row = o >> 4, cg = (o & 15) * 8;
        *(bf16x8*)&As[row][cg] = *(const bf16x8*)(A + (size_t)(bm + row) * 128 + cg);
    }
    __syncthreads();

    const f32x4 zero4 = {0.f, 0.f, 0.f, 0.f};
    f32x4 acc[4][4];
#pragma unroll
    for (int i = 0; i < 4; ++i)
#pragma unroll
        for (int j = 0; j < 4; ++j) acc[i][j] = zero4;

#pragma unroll
    for (int ks = 0; ks < 4; ++ks) {
        const bf16x8* cur = (ks & 1) ? bwB : bwA;
        bf16x8*       nxt = (ks & 1) ? bwA : bwB;
        if (ks < 3) {
#pragma unroll
            for (int nf = 0; nf < 4; ++nf)
                nxt[nf] = okc[nf] ? *(const bf16x8*)(wp + (size_t)(nf * 16) * 128 + (ks + 1) * 32) : zrow;
        }
        bf16x8 af[4];
#pragma unroll
        for (int mf = 0; mf < 4; ++mf)
            af[mf] = *(const bf16x8*)&As[wm + mf*16 + lr][ks*32 + lg*8];
        __builtin_amdgcn_s_setprio(1);
#pragma unroll
        for (int mf = 0; mf < 4; ++mf)
#pragma unroll
            for (int nf = 0; nf < 4; ++nf)
                acc[mf][nf] = MFMA_BF16(af[mf], cur[nf], acc[mf][nf]);
        __builtin_amdgcn_s_setprio(0);
    }

#pragma unroll
    for (int half = 0; half < 2; ++half) {
        __syncthreads();
        if ((wid >> 1) == half) {
#pragma unroll
            for (int nf = 0; nf < 4; ++nf) {
                int col = wn + nf * 16 + lr;
                if (col >= 84) continue;
                float bv = (col < 81) ? bias[col] : 0.f;
#pragma unroll
                for (int mf = 0; mf < 4; ++mf)
#pragma unroll
                    for (int r = 0; r < 4; ++r) {
                        float vv = (col < 81) ? (acc[mf][nf][r] + bv) : 0.f;
                        Sb[mf * 16 + lg * 4 + r][col] = (bf16)vv;
                    }
            }
        }
        __syncthreads();
#pragma unroll
        for (int i = 0; i < 6; ++i) {
            int o = i * 256 + t;
            if (o < 64 * 21) {
                int row = o / 21, cq = (o - row * 21) * 4;
                *(bf16x4*)(outA + (size_t)(bm + half * 64 + row) * cAS + cq) =
                    *(const bf16x4*)&Sb[row][cq];
            }
        }
    }
}

// ---------------------------------------------------------------------------
// Generic k-loop GEMM, M=128, optional fused next-LN epilogue (unchanged).
// ---------------------------------------------------------------------------
template<bool OUTBF, bool RELU, bool RES, bool POS, bool LNOUT>
__global__ __launch_bounds__(256) void k_gemm_res(const bf16* __restrict__ A,
                                                  const bf16* __restrict__ Wt,
                                                  const float* __restrict__ bias,
                                                  const float* __restrict__ res,
                                                  float* __restrict__ outF,
                                                  bf16* __restrict__ outB,
                                                  int K,
                                                  const float* __restrict__ ytab,
                                                  const float* __restrict__ xtab,
                                                  const float* __restrict__ lng,
                                                  const float* __restrict__ lnb,
                                                  bf16* __restrict__ xnbO)
{
    __shared__ bf16 As[128][40];
    __shared__ bf16 Bs[128][40];
    __shared__ float Sf[64][136];

    const int bm = blockIdx.x * 128;
    const int t = threadIdx.x;
    const int lane = t & 63, wid = t >> 6;
    const int wm = (wid >> 1) * 64, wn = (wid & 1) * 64;
    const int lr = lane & 15, lg = lane >> 4;

    const f32x4 zero4 = {0.f, 0.f, 0.f, 0.f};
    f32x4 acc[4][4];
#pragma unroll
    for (int i = 0; i < 4; ++i)
#pragma unroll
        for (int j = 0; j < 4; ++j) acc[i][j] = zero4;

    for (int k0 = 0; k0 < K; k0 += 32) {
#pragma unroll
        for (int i = 0; i < 2; ++i) {
            int idx = t + i * 256;
            int row = idx >> 2, kg = (idx & 3) * 8;
            *(bf16x8*)&As[row][kg] = *(const bf16x8*)(A + (size_t)(bm + row) * K + k0 + kg);
            *(bf16x8*)&Bs[row][kg] = *(const bf16x8*)(Wt + (size_t)row * K + k0 + kg);
        }
        __syncthreads();
        bf16x8 af[4], bf[4];
#pragma unroll
        for (int mf = 0; mf < 4; ++mf)
            af[mf] = *(const bf16x8*)&As[wm + mf*16 + lr][lg * 8];
#pragma unroll
        for (int nf = 0; nf < 4; ++nf)
            bf[nf] = *(const bf16x8*)&Bs[wn + nf*16 + lr][lg * 8];
        __builtin_amdgcn_s_setprio(1);
#pragma unroll
        for (int mf = 0; mf < 4; ++mf)
#pragma unroll
            for (int nf = 0; nf < 4; ++nf)
                acc[mf][nf] = MFMA_BF16(af[mf], bf[nf], acc[mf][nf]);
        __builtin_amdgcn_s_setprio(0);
        __syncthreads();
    }

    if (OUTBF) {
        bf16 (*Sb)[136] = (bf16(*)[136])Sf;
#pragma unroll
        for (int nf = 0; nf < 4; ++nf) {
            int col = wn + nf * 16 + lr;
            float bv = bias ? bias[col] : 0.f;
#pragma unroll
            for (int mf = 0; mf < 4; ++mf)
#pragma unroll
                for (int r = 0; r < 4; ++r) {
                    float vv = acc[mf][nf][r] + bv;
                    if (RELU) vv = fmaxf(vv, 0.f);
                    Sb[wm + mf * 16 + lg * 4 + r][col] = (bf16)vv;
                }
        }
        __syncthreads();
#pragma unroll
        for (int i = 0; i < 8; ++i) {
            int o = i * 256 + t;
            int row = o >> 4, cg = (o & 15) * 8;
            *(bf16x8*)(outB + (size_t)(bm + row) * 128 + cg) = *(const bf16x8*)&Sb[row][cg];
        }
    } else {
        for (int half = 0; half < 2; ++half) {
            __syncthreads();
            if ((wid >> 1) == half) {
#pragma unroll
                for (int nf = 0; nf < 4; ++nf) {
                    int col = wn + nf * 16 + lr;
                    float bv = bias ? bias[col] : 0.f;
#pragma unroll
                    for (int mf = 0; mf < 4; ++mf)
#pragma unroll
                        for (int r = 0; r < 4; ++r)
                            Sf[mf * 16 + lg * 4 + r][col] = acc[mf][nf][r] + bv;
                }
            }
            __syncthreads();
#pragma unroll
            for (int i = 0; i < 8; ++i) {
                int o = i * 256 + t;
                int row = o >> 5, cq = (o & 31) * 4;
                int grow = bm + half * 64 + row;
                float4 v = *(const float4*)&Sf[row][cq];
                if (POS) {
                    int hw = grow % cNPIX;
                    int h = hw / cW, w = hw - (hw / cW) * cW;
                    float4 p = (cq < 64) ? *(const float4*)(ytab + (h << 6) + cq)
                                         : *(const float4*)(xtab + (w << 6) + cq - 64);
                    v.x += p.x; v.y += p.y; v.z += p.z; v.w += p.w;
                }
                if (RES) {
                    float4 rr = *(const float4*)(res + (size_t)grow * 128 + cq);
                    v.x += rr.x; v.y += rr.y; v.z += rr.z; v.w += rr.w;
                }
                if (LNOUT) {
                    float s  = v.x + v.y + v.z + v.w;
                    float sq = v.x*v.x + v.y*v.y + v.z*v.z + v.w*v.w;
#pragma unroll
                    for (int mk = 1; mk < 32; mk <<= 1) {
                        s  += __shfl_xor(s,  mk);
                        sq += __shfl_xor(sq, mk);
                    }
                    float mu = s * (1.f / 128.f);
                    float rs = rsqrtf(sq * (1.f / 128.f) - mu * mu + 1e-5f);
                    float4 g4 = *(const float4*)(lng + cq);
                    float4 b4 = *(const float4*)(lnb + cq);
                    bf16x4 xo;
                    xo[0] = (bf16)((v.x - mu) * rs * g4.x + b4.x);
                    xo[1] = (bf16)((v.y - mu) * rs * g4.y + b4.y);
                    xo[2] = (bf16)((v.z - mu) * rs * g4.z + b4.z);
                    xo[3] = (bf16)((v.w - mu) * rs * g4.w + b4.w);
                    *(bf16x4*)(xnbO + (size_t)grow * 128 + cq) = xo;
                }
                *(float4*)(outF + (size_t)grow * 128 + cq) = v;
            }
        }
    }
}

// ---------------------------------------------------------------------------
// Outlook fused gather (unchanged).
// ---------------------------------------------------------------------------
__global__ __launch_bounds__(256) void k_olk_gather(const bf16* __restrict__ v,
                                                    const bf16* __restrict__ attn,
                                                    bf16* __restrict__ y)
{
    __shared__ float pr[16][84];
    __shared__ float coef[16][26];

    const int t  = threadIdx.x;
    const int px = t >> 4;
    const int j  = t & 15;
    const int pix = blockIdx.x * 16 + px;
    const int b  = pix / cNPIX;
    const int hw = pix % cNPIX;
    const int h = hw / cW, w = hw % cW;

    if (j < 9) {
        const int p  = j;
        const int pi = p / 3, pj = p - pi * 3;
        const int hh = h + 1 - pi, ww = w + 1 - pj;
        float prv[9];
        if ((unsigned)hh < (unsigned)cH && (unsigned)ww < (unsigned)cW) {
            const size_t row = (size_t)(b * cNPIX + hh * cW + ww);
            const bf16* arow = attn + row * cAS + p * 9;
            float lg[9];
            float m = 0.f;
#pragma unroll
            for (int q = 0; q < 9; ++q) { lg[q] = (float)arow[q]; m = fmaxf(m, lg[q]); }
            float se = 0.f;
#pragma unroll
            for (int q = 0; q < 9; ++q) { prv[q] = __expf(lg[q] - m); se += prv[q]; }
            float inv = 1.f / (se + __expf(-m));
#pragma unroll
            for (int q = 0; q < 9; ++q) prv[q] *= inv;
        } else {
#pragma unroll
            for (int q = 0; q < 9; ++q) prv[q] = 0.f;
        }
#pragma unroll
        for (int q = 0; q < 9; ++q) pr[px][p * 9 + q] = prv[q];
    }
    __syncthreads();

    for (int d = j; d < 25; d += 16) {
        const int a  = d / 5, bb = d - a * 5;
        float s = 0.f;
#pragma unroll
        for (int pi = 0; pi < 3; ++pi) {
            const int qi = pi + a - 2;
            if ((unsigned)qi >= 3u) continue;
#pragma unroll
            for (int pj = 0; pj < 3; ++pj) {
                const int qj = pj + bb - 2;
                if ((unsigned)qj >= 3u) continue;
                s += pr[px][(pi * 3 + pj) * 9 + qi * 3 + qj];
            }
        }
        coef[px][d] = s;
    }
    __syncthreads();

    float acc[8] = {};
    const size_t bbase = (size_t)b * cNPIX;
#pragma unroll
    for (int a = 0; a < 5; ++a) {
        const int sh = h + a - 2;
        if ((unsigned)sh >= (unsigned)cH) continue;
#pragma unroll
        for (int bb = 0; bb < 5; ++bb) {
            const int sw = w + bb - 2;
            if ((unsigned)sw >= (unsigned)cW) continue;
            const float cf = coef[px][a * 5 + bb];
            const bf16x8 v8 = *(const bf16x8*)(v + ((bbase + (size_t)sh * cW + sw) * 128 + j * 8));
#pragma unroll
            for (int e = 0; e < 8; ++e) acc[e] = fmaf(cf, (float)v8[e], acc[e]);
        }
    }
    bf16x8 o8;
#pragma unroll
    for (int e = 0; e < 8; ++e) o8[e] = (bf16)acc[e];
    *(bf16x8*)(y + (size_t)pix * 128 + j * 8) = o8;
}

// ---------------------------------------------------------------------------
// Depthwise 3x3 + bias + fast GELU (sigmoid form, 1 v_exp), row-sliding.
// 20-px segments (grid 2*96*16); row validity folded into weights; no
// per-iteration bounds checks (uniform branch only on segment edges).
// ---------------------------------------------------------------------------
__global__ __launch_bounds__(256) void k_dwconv_gelu(const bf16* __restrict__ h1,
                                                     const float* __restrict__ dwt,
                                                     const float* __restrict__ bdw,
                                                     bf16* __restrict__ h2)
{
    const int t   = threadIdx.x;
    const int c2  = t * 2;
    const int blk = blockIdx.x;
    const int row = blk >> 4;          // b*96 + h
    const int seg = blk & 15;
    const int bb  = row / cH, h = row % cH;
    const int w0  = seg * 20;

    float2 wgt[9];
#pragma unroll
    for (int k = 0; k < 9; ++k)
        wgt[k] = *(const float2*)(dwt + k * 512 + c2);
    if (h == 0) {
        wgt[0].x = wgt[0].y = wgt[1].x = wgt[1].y = wgt[2].x = wgt[2].y = 0.f;
    }
    if (h == cH - 1) {
        wgt[6].x = wgt[6].y = wgt[7].x = wgt[7].y = wgt[8].x = wgt[8].y = 0.f;
    }
    const float2 bias = *(const float2*)(bdw + c2);

    const size_t base = (size_t)bb * cNPIX;
    const int hm = (h == 0) ? 0 : h - 1;
    const int hp = (h == cH - 1) ? h : h + 1;
    const bf16* rp0 = h1 + (base + (size_t)hm * cW + w0) * 512 + c2;
    const bf16* rp1 = h1 + (base + (size_t)h  * cW + w0) * 512 + c2;
    const bf16* rp2 = h1 + (base + (size_t)hp * cW + w0) * 512 + c2;

    auto ldc = [&](const bf16* rp, int wofs) -> float2 {
        unsigned u = *(const unsigned*)(rp + (size_t)wofs * 512);
        float2 r;
        r.x = __uint_as_float(u << 16);
        r.y = __uint_as_float(u & 0xffff0000u);
        return r;
    };
    auto gelu = [](float x) -> float {
        float x2 = x * x;
        float z2 = fmaf(x2 * x, 0.0713548162726f, 1.5957691216057308f * x);
        float t1 = 1.f / (1.f + __expf(-z2));   // sigmoid(2z)
        return x * t1;
    };

    float2 cm[3], c0[3], cp[3];
    if (seg == 0) {
#pragma unroll
        for (int r = 0; r < 3; ++r) { cm[r].x = 0.f; cm[r].y = 0.f; }
    } else {
        cm[0] = ldc(rp0, -1); cm[1] = ldc(rp1, -1); cm[2] = ldc(rp2, -1);
    }
    c0[0] = ldc(rp0, 0); c0[1] = ldc(rp1, 0); c0[2] = ldc(rp2, 0);

    bf16* op = h2 + (base + (size_t)h * cW + w0) * 512 + c2;

    for (int j = 0; j < 20; ++j) {
        if (j == 19 && seg == 15) {
#pragma unroll
            for (int r = 0; r < 3; ++r) { cp[r].x = 0.f; cp[r].y = 0.f; }
        } else {
            cp[0] = ldc(rp0, j + 1); cp[1] = ldc(rp1, j + 1); cp[2] = ldc(rp2, j + 1);
        }
        float a0 = bias.x, a1 = bias.y;
#pragma unroll
        for (int r = 0; r < 3; ++r) {
            a0 = fmaf(cm[r].x, wgt[r * 3 + 0].x, a0);
            a1 = fmaf(cm[r].y, wgt[r * 3 + 0].y, a1);
            a0 = fmaf(c0[r].x, wgt[r * 3 + 1].x, a0);
            a1 = fmaf(c0[r].y, wgt[r * 3 + 1].y, a1);
            a0 = fmaf(cp[r].x, wgt[r * 3 + 2].x, a0);
            a1 = fmaf(cp[r].y, wgt[r * 3 + 2].y, a1);
        }
        a0 = gelu(a0);
        a1 = gelu(a1);
        union { bf16 hh[2]; unsigned int u; } o2;
        o2.hh[0] = (bf16)a0;
        o2.hh[1] = (bf16)a1;
        *(unsigned int*)(op + (size_t)j * 512) = o2.u;
#pragma unroll
        for (int r = 0; r < 3; ++r) { cm[r] = c0[r]; c0[r] = cp[r]; }
    }
}

// ---------------------------------------------------------------------------
// Window attention (unchanged from R9).
// ---------------------------------------------------------------------------
template<bool SHIFT>
__global__ __launch_bounds__(256) void k_win_attn(const bf16* __restrict__ q,
                                                  const bf16* __restrict__ ks,
                                                  const bf16* __restrict__ vt,
                                                  bf16* __restrict__ out)
{
    __shared__ bf16 Ks[2][32][136];
    __shared__ bf16 Vs[2][128][40];
    __shared__ bf16 Ps[4][16][40];

    const int t = threadIdx.x, lane = t & 63, wid = t >> 6;
    const int lr = lane & 15, lg = lane >> 4;
    const int wb = blockIdx.x;
    const int b  = wb >> 6, win = wb & 63;
    const int nh = win >> 3, nw = win & 7;
    const int qbase = blockIdx.y * 64 + wid * 16;

    const float SCALE   = 0.088388347648318447f;
    const float MASKRAW = 100.f / 0.088388347648318447f;

    auto tokOf = [&](int p) {
        int ph = nh * 12 + p / 40;
        int pw = nw * 40 + (p % 40);
        if (SHIFT) {
            ph += 6;  if (ph >= cH) ph -= cH;
            pw += 20; if (pw >= cW) pw -= cW;
        }
        return b * cNPIX + ph * cW + pw;
    };

    int qp = min(qbase + lr, 479);
    const bf16* qptr = q + (size_t)tokOf(qp) * 128;
    bf16x8 qf[4];
#pragma unroll
    for (int c = 0; c < 4; ++c)
        qf[c] = *(const bf16x8*)(qptr + c * 32 + lg * 8);

    int labq[4];
    if (SHIFT) {
#pragma unroll
        for (int r = 0; r < 4; ++r) {
            int qrow = min(qbase + lg * 4 + r, 479);
            int qr = qrow / 40, qc = qrow - qr * 40;
            int rh = (nh == 7) ? (qr < 6 ? 1 : 2) : 0;
            int rc = (nw == 7) ? (qc < 20 ? 1 : 2) : 0;
            labq[r] = rh * 3 + rc;
        }
    }

    const bf16* kbase = ks + (size_t)wb * 480 * 128;
    const bf16* vbase = vt + (size_t)wb * 128 * 480;
    auto loadK = [&](int kt, int i) {
        int idx = t + i * 256;
        int key = idx >> 4, cg = (idx & 15) * 8;
        return *(const bf16x8*)(kbase + (size_t)(kt * 32 + key) * 128 + cg);
    };
    auto loadV = [&](int kt, int i) {
        int idx = t + i * 256;
        int ch = idx >> 2, kq = (idx & 3) * 8;
        return *(const bf16x8*)(vbase + (size_t)ch * 480 + kt * 32 + kq);
    };

    bf16x8 kreg0 = loadK(0, 0), kreg1 = loadK(0, 1);
    bf16x8 vreg0 = loadV(0, 0), vreg1 = loadV(0, 1);

    int kc0 = lr, kr0 = 0;
    int kc1 = 16 + lr, kr1 = 0;

    const f32x4 zero4 = {0.f, 0.f, 0.f, 0.f};
    float m_run[4] = {0.f, 0.f, 0.f, 0.f};
    float mguard = 8.f;
    f32x4 l4 = zero4;
    f32x4 o[8];
#pragma unroll
    for (int nf = 0; nf < 8; ++nf) o[nf] = zero4;

    bf16x8 ones8;
#pragma unroll
    for (int j = 0; j < 8; ++j) ones8[j] = (bf16)1.f;

    int buf = 0;
    for (int kt = 0; kt < 15; ++kt) {
        {
            int i0 = t, i1 = t + 256;
            *(bf16x8*)&Ks[buf][i0 >> 4][(i0 & 15) * 8] = kreg0;
            *(bf16x8*)&Ks[buf][i1 >> 4][(i1 & 15) * 8] = kreg1;
            *(bf16x8*)&Vs[buf][i0 >> 2][(i0 & 3) * 8] = vreg0;
            *(bf16x8*)&Vs[buf][i1 >> 2][(i1 & 3) * 8] = vreg1;
        }
        if (kt + 1 < 15) {
            kreg0 = loadK(kt + 1, 0); kreg1 = loadK(kt + 1, 1);
            vreg0 = loadV(kt + 1, 0); vreg1 = loadV(kt + 1, 1);
        }
        __syncthreads();

        f32x4 s0 = zero4, s1 = zero4;
        __builtin_amdgcn_s_setprio(1);
#pragma unroll
        for (int c = 0; c < 4; ++c) {
            bf16x8 kf0 = *(const bf16x8*)&Ks[buf][lr][c * 32 + lg * 8];
            bf16x8 kf1 = *(const bf16x8*)&Ks[buf][16 + lr][c * 32 + lg * 8];
            s0 = MFMA_BF16(qf[c], kf0, s0);
            s1 = MFMA_BF16(qf[c], kf1, s1);
        }
        __builtin_amdgcn_s_setprio(0);

        if (SHIFT) {
            int rh0 = (nh == 7) ? (kr0 < 6 ? 1 : 2) : 0;
            int rc0 = (nw == 7) ? (kc0 < 20 ? 1 : 2) : 0;
            int rh1 = (nh == 7) ? (kr1 < 6 ? 1 : 2) : 0;
            int rc1 = (nw == 7) ? (kc1 < 20 ? 1 : 2) : 0;
            int lab0 = rh0 * 3 + rc0;
            int lab1 = rh1 * 3 + rc1;
#pragma unroll
            for (int r = 0; r < 4; ++r) {
                if (labq[r] != lab0) s0[r] -= MASKRAW;
                if (labq[r] != lab1) s1[r] -= MASKRAW;
            }
        }
        kc0 += 32; if (kc0 >= 40) { kc0 -= 40; ++kr0; }
        kc1 += 32; if (kc1 >= 40) { kc1 -= 40; ++kr1; }

        float tm = fmaxf(fmaxf(fmaxf(s0[0], s0[1]), fmaxf(s0[2], s0[3])),
                         fmaxf(fmaxf(s1[0], s1[1]), fmaxf(s1[2], s1[3])));
#pragma unroll
        for (int off = 1; off < 16; off <<= 1) tm = fmaxf(tm, __shfl_xor(tm, off));
        if (tm * SCALE > mguard) {
#pragma unroll
            for (int r = 0; r < 4; ++r) {
                float mx = fmaxf(s0[r], s1[r]);
#pragma unroll
                for (int off = 1; off < 16; off <<= 1) mx = fmaxf(mx, __shfl_xor(mx, off));
                float nm = fmaxf(m_run[r], mx * SCALE);
                float sc = __expf(m_run[r] - nm);
#pragma unroll
                for (int nf = 0; nf < 8; ++nf) o[nf][r] *= sc;
                l4[r] *= sc;
                m_run[r] = nm;
            }
            mguard = fminf(fminf(m_run[0], m_run[1]), fminf(m_run[2], m_run[3])) + 8.f;
        }

#pragma unroll
        for (int r = 0; r < 4; ++r) {
            float p0 = __expf(fmaf(s0[r], SCALE, -m_run[r]));
            float p1 = __expf(fmaf(s1[r], SCALE, -m_run[r]));
            Ps[wid][lg * 4 + r][lr]      = (bf16)p0;
            Ps[wid][lg * 4 + r][16 + lr] = (bf16)p1;
        }

        bf16x8 pa = *(const bf16x8*)&Ps[wid][lr][lg * 8];
        __builtin_amdgcn_s_setprio(1);
        l4 = MFMA_BF16(pa, ones8, l4);
#pragma unroll
        for (int nf = 0; nf < 8; ++nf) {
            bf16x8 bv = *(const bf16x8*)&Vs[buf][nf * 16 + lr][lg * 8];
            o[nf] = MFMA_BF16(pa, bv, o[nf]);
        }
        __builtin_amdgcn_s_setprio(0);
        __syncthreads();
        buf ^= 1;
    }

#pragma unroll
    for (int r = 0; r < 4; ++r) {
        int qrow = qbase + lg * 4 + r;
        if (qrow >= 480) continue;
        float inv = 1.f / (l4[r] + __expf(-m_run[r]));
        size_t ooff = (size_t)tokOf(qrow) * 128;
#pragma unroll
        for (int nf = 0; nf < 8; ++nf)
            out[ooff + nf * 16 + lr] = (bf16)(o[nf][r] * inv);
    }
}

// ---------------------------------------------------------------------------
// Host launcher
// ---------------------------------------------------------------------------
extern "C" void kernel_launch(void* const* d_in, const int* in_sizes, int n_in,
                              void* d_out, int out_size, void* d_ws, size_t ws_size,
                              hipStream_t stream)
{
    (void)in_sizes; (void)n_in; (void)out_size; (void)ws_size;

    const float* X = (const float*)d_in[0];

    char* ws = (char*)d_ws;
    float* f    = (float*)ws;                                 ws += (size_t)cNTOK * 128 * 4;
    bf16*  xnb  = (bf16*)ws;                                  ws += (size_t)cNTOK * 128 * 2;
    bf16*  bufA = (bf16*)ws;                                  ws += (size_t)cNTOK * 512 * 2;
    bf16*  bufB = (bf16*)ws;                                  ws += (size_t)cNTOK * 512 * 2;
    bf16*  wts  = (bf16*)ws;

    size_t wo_off = 0;
    auto nextw = [&](int K, int M) { bf16* p = wts + wo_off; wo_off += (size_t)K * M; return p; };
    bf16* agg_w1t = nextw(256, 128);
    bf16* agg_w2t = nextw(128, 128);
    bf16* ol_wvt  = nextw(128, 128);
    bf16* ol_wat  = nextw(128, 81);
    bf16* ol_wot  = nextw(128, 128);
    bf16* f1_w1t  = nextw(128, 512);
    bf16* f1_w2t  = nextw(512, 128);
    bf16* w_qkvt  = nextw(128, 384);
    bf16* w_wot   = nextw(128, 128);
    bf16* f2_w1t  = nextw(128, 512);
    bf16* f2_w2t  = nextw(512, 128);
    bf16* s_qkvt  = nextw(128, 384);
    bf16* s_wot   = nextw(128, 128);
    bf16* f3_w1t  = nextw(128, 512);
    bf16* f3_w2t  = nextw(512, 128);
    float* dwt1 = (float*)(wts + wo_off);
    float* dwt2 = dwt1 + 512 * 9;
    float* dwt3 = dwt2 + 512 * 9;
    float* ytab = dwt3 + 512 * 9;
    float* xtab = ytab + 96 * 64;

    WJobs jobs;
    int ji = 0;
    auto addj = [&](int src_idx, bf16* dst, int K, int M) {
        jobs.j[ji++] = WJob{(const float*)d_in[src_idx], dst, K, M};
    };
    addj(1,  agg_w1t, 256, 128);
    addj(3,  agg_w2t, 128, 128);
    addj(7,  ol_wvt,  128, 128);
    addj(8,  ol_wat,  128, 81);
    addj(10, ol_wot,  128, 128);
    addj(14, f1_w1t,  128, 512);
    addj(18, f1_w2t,  512, 128);
    addj(22, w_qkvt,           128, 128);
    addj(23, w_qkvt + 128*128, 128, 128);
    addj(24, w_qkvt + 256*128, 128, 128);
    addj(25, w_wot,   128, 128);
    addj(29, f2_w1t,  128, 512);
    addj(33, f2_w2t,  512, 128);
    addj(37, s_qkvt,           128, 128);
    addj(38, s_qkvt + 128*128, 128, 128);
    addj(39, s_qkvt + 256*128, 128, 128);
    addj(40, s_wot,   128, 128);
    addj(44, f3_w1t,  128, 512);
    addj(48, f3_w2t,  512, 128);
    k_wt<<<dim3(16, 16, 19), dim3(32, 8), 0, stream>>>(jobs);
    k_dwt<<<3, 256, 0, stream>>>((const float*)d_in[16], (const float*)d_in[31],
                                 (const float*)d_in[46], dwt1, dwt2, dwt3);
    k_postab<<<80, 256, 0, stream>>>(ytab, xtab);

    const int nTT = cNTOK / 128;   // 480 token tiles

    // ---- input transpose + aggregation MLP (agg_w2 epilogue emits ol-LN) ----
    k_chw2hwc<<<dim3(cNPIX / 32, 256 / 32, cB), dim3(32, 8), 0, stream>>>(X, bufA);
    k_gemm_res<true, true, false, false, false><<<nTT, 256, 0, stream>>>(
        bufA, agg_w1t, (const float*)d_in[2], nullptr, nullptr, bufB, 256,
        nullptr, nullptr, nullptr, nullptr, nullptr);
    k_gemm_res<false, false, false, false, true><<<nTT, 256, 0, stream>>>(
        bufB, agg_w2t, (const float*)d_in[4], nullptr, f, nullptr, 128,
        nullptr, nullptr, (const float*)d_in[5], (const float*)d_in[6], xnb);

    // ---- outlook attention (ol_wo epilogue emits f1-LN) ----
    {
        bf16*  vb   = bufA;
        bf16*  gout = bufA + (size_t)cNTOK * 128;
        bf16*  atn  = bufB;
        k_gemm128<-1><<<nTT, 256, 0, stream>>>(xnb, ol_wvt, nullptr, vb, 128, nullptr, nullptr);
        k_gemm128_wa<<<nTT, 256, 0, stream>>>(xnb, ol_wat, (const float*)d_in[9], atn);
        k_olk_gather<<<cNTOK / 16, 256, 0, stream>>>(vb, atn, gout);
        k_gemm_res<false, false, true, false, true><<<nTT, 256, 0, stream>>>(
            gout, ol_wot, (const float*)d_in[11], f, f, nullptr, 128,
            nullptr, nullptr, (const float*)d_in[12], (const float*)d_in[13], xnb);
    }

    // ---- conv FFN; w2 epilogue emits next block's LN (if lnG) ----
    auto run_ffn = [&](int base, bf16* w1t, bf16* w2t, float* dwt, bool pos,
                       const float* lnG, const float* lnB) {
        k_gemm128<-1><<<nTT * 4, 256, 0, stream>>>(
            xnb, w1t, (const float*)d_in[base + 3], bufA, 512, nullptr, nullptr);
        k_dwconv_gelu<<<cB * cH * 16, 256, 0, stream>>>(
            bufA, dwt, (const float*)d_in[base + 5], bufB);
        if (pos) {
            k_gemm_res<false, false, true, true, true><<<nTT, 256, 0, stream>>>(
                bufB, w2t, (const float*)d_in[base + 7], f, f, nullptr, 512,
                ytab, xtab, lnG, lnB, xnb);
        } else if (lnG) {
            k_gemm_res<false, false, true, false, true><<<nTT, 256, 0, stream>>>(
                bufB, w2t, (const float*)d_in[base + 7], f, f, nullptr, 512,
                nullptr, nullptr, lnG, lnB, xnb);
        } else {
            k_gemm_res<false, false, true, false, false><<<nTT, 256, 0, stream>>>(
                bufB, w2t, (const float*)d_in[base + 7], f, f, nullptr, 512,
                nullptr, nullptr, nullptr, nullptr, nullptr);
        }
    };

    // ---- window attention; wo epilogue emits next block's LN ----
    auto run_win = [&](int base, bf16* qkvt, bf16* wot, bool shift,
                       const float* lnG, const float* lnB) {
        bf16* qb  = bufA;
        bf16* ksb = bufA + (size_t)cNTOK * 128;
        bf16* vtb = bufA + (size_t)cNTOK * 256;
        bf16* ao  = bufB;
        if (shift)
            k_gemm128<1><<<nTT * 3, 256, 0, stream>>>(xnb, qkvt, nullptr, qb, 384, vtb, ksb);
        else
            k_gemm128<0><<<nTT * 3, 256, 0, stream>>>(xnb, qkvt, nullptr, qb, 384, vtb, ksb);
        if (shift) k_win_attn<true ><<<dim3(128, 8), 256, 0, stream>>>(qb, ksb, vtb, ao);
        else       k_win_attn<false><<<dim3(128, 8), 256, 0, stream>>>(qb, ksb, vtb, ao);
        k_gemm_res<false, false, true, false, true><<<nTT, 256, 0, stream>>>(
            ao, wot, (const float*)d_in[base + 6], f, f, nullptr, 128,
            nullptr, nullptr, lnG, lnB, xnb);
    };

    run_ffn(12, f1_w1t, f1_w2t, dwt1, true,
            (const float*)d_in[20], (const float*)d_in[21]);       // f1 (+pos, emits w-LN)
    run_win(20, w_qkvt, w_wot, false,
            (const float*)d_in[27], (const float*)d_in[28]);       // w (emits f2-LN)
    run_ffn(27, f2_w1t, f2_w2t, dwt2, false,
            (const float*)d_in[35], (const float*)d_in[36]);       // f2 (emits s-LN)
    run_win(35, s_qkvt, s_wot, true,
            (const float*)d_in[42], (const float*)d_in[43]);       // s (emits f3-LN)
    run_ffn(42, f3_w1t, f3_w2t, dwt3, false, nullptr, nullptr);    // f3 (no LN out)

    k_hwc2chw<<<dim3(cNPIX / 32, cC / 32, cB), dim3(32, 8), 0, stream>>>(f, (float*)d_out);
}